// Round 1
// baseline (882.077 us; speedup 1.0000x reference)
//
#include <hip/hip_runtime.h>
#include <math.h>

#define EPS 1e-5f

// ---------------- Linear: (1,512) @ (768,512)^T + b -> 768 ----------------
__global__ __launch_bounds__(256) void linear_kernel(
    const float* __restrict__ z, const float* __restrict__ w,
    const float* __restrict__ b, float* __restrict__ out) {
  int j = blockIdx.x * blockDim.x + threadIdx.x;
  if (j >= 768) return;
  const float* wr = w + j * 512;
  float acc = b[j];
  for (int k = 0; k < 512; ++k) acc += z[k] * wr[k];
  out[j] = acc;
}

// ------------- Fused: conv5(valid, both weight sets) + nearest-upsample -------------
// out pixel (n,c,oy,ox) at res r; src conv pos sy=(oy*hc)/r, sx=(ox*wc)/r
__global__ __launch_bounds__(256) void conv_up_kernel(
    const float* __restrict__ in, float* __restrict__ y, float* __restrict__ u2,
    const float* __restrict__ w1, const float* __restrict__ b1,
    const float* __restrict__ w2, const float* __restrict__ b2,
    int N, int Hin, int Win, int hc, int wc, int r) {
  __shared__ float w1s[225], w2s[225], b1s[3], b2s[3];
  for (int t = threadIdx.x; t < 225; t += blockDim.x) { w1s[t] = w1[t]; w2s[t] = w2[t]; }
  if (threadIdx.x < 3) { b1s[threadIdx.x] = b1[threadIdx.x]; b2s[threadIdx.x] = b2[threadIdx.x]; }
  __syncthreads();
  int idx = blockIdx.x * blockDim.x + threadIdx.x;
  int total = N * 3 * r * r;
  if (idx >= total) return;
  int ox = idx % r; int t = idx / r;
  int oy = t % r;   t /= r;
  int c  = t % 3;   int n = t / 3;
  int sy = (oy * hc) / r, sx = (ox * wc) / r;
  float a1 = b1s[c], a2 = b2s[c];
  const float* wp1 = w1s + c * 75;
  const float* wp2 = w2s + c * 75;
  for (int ci = 0; ci < 3; ++ci) {
    const float* ip = in + ((size_t)(n * 3 + ci) * Hin + sy) * Win + sx;
    #pragma unroll
    for (int ky = 0; ky < 5; ++ky) {
      const float* row = ip + ky * Win;
      #pragma unroll
      for (int kx = 0; kx < 5; ++kx) {
        float v = row[kx];
        a1 += v * wp1[(ci * 5 + ky) * 5 + kx];
        a2 += v * wp2[(ci * 5 + ky) * 5 + kx];
      }
    }
  }
  y[idx] = a1;
  u2[idx] = a2;
}

// ------------- per-(n,c) sum / sumsq over hw elements -------------
__global__ __launch_bounds__(256) void stats_kernel(
    const float* __restrict__ y, float* __restrict__ sums, int hw) {
  int nc = blockIdx.x;
  const float* p = y + (size_t)nc * hw;
  float s = 0.f, s2 = 0.f;
  for (int i = threadIdx.x; i < hw; i += blockDim.x) { float v = p[i]; s += v; s2 += v * v; }
  __shared__ float sh[256], sh2[256];
  sh[threadIdx.x] = s; sh2[threadIdx.x] = s2;
  __syncthreads();
  for (int off = 128; off > 0; off >>= 1) {
    if (threadIdx.x < off) { sh[threadIdx.x] += sh[threadIdx.x + off]; sh2[threadIdx.x] += sh2[threadIdx.x + off]; }
    __syncthreads();
  }
  if (threadIdx.x == 0) { sums[2 * nc] = sh[0]; sums[2 * nc + 1] = sh2[0]; }
}

// ------------- fold instance-norm + batch-norm + p1 into per-(n,c) affine -------------
__global__ __launch_bounds__(128) void finalize_kernel(
    const float* __restrict__ sums, float* __restrict__ alpha, float* __restrict__ beta,
    int N, int hw,
    const float* __restrict__ inp, const float* __restrict__ lnp, const float* __restrict__ bnp,
    const float* __restrict__ bnw, const float* __restrict__ bnb, const float* __restrict__ p1p) {
  int j = threadIdx.x;
  if (j >= N * 3) return;
  int c = j % 3;
  float si = inp[0] + inp[1] + inp[2] + lnp[0] + lnp[1] + lnp[2];
  float sb = bnp[0] + bnp[1] + bnp[2];
  float inv = 1.0f / (float)hw;
  float mi = sums[2 * j] * inv;
  float vi = sums[2 * j + 1] * inv - mi * mi;
  float ri = rsqrtf(vi + EPS);
  float bs = 0.f, bs2 = 0.f;
  for (int n = 0; n < N; ++n) { bs += sums[2 * (n * 3 + c)]; bs2 += sums[2 * (n * 3 + c) + 1]; }
  float invb = 1.0f / ((float)N * (float)hw);
  float mb = bs * invb;
  float vb = bs2 * invb - mb * mb;
  float rb = rsqrtf(vb + EPS);
  float w = bnw[c];
  float A = 1.0f + si * ri + sb * rb * w;
  float B = -(si * ri * mi + sb * rb * w * mb) + sb * bnb[c];
  float p1 = p1p[0];
  alpha[j] = A * p1;
  beta[j]  = B * p1;
}

// ------------- elementwise: out = alpha[nc]*y + beta[nc] + p2*u2 (+noise) (tanh) -------------
__global__ __launch_bounds__(256) void elemD_kernel(
    const float* __restrict__ y, const float* __restrict__ u2,
    const float* __restrict__ alpha, const float* __restrict__ beta,
    const float* __restrict__ p2p, const float* __restrict__ noise,
    float* __restrict__ out, int total, int hw, int hw3, int do_tanh) {
  int idx = blockIdx.x * blockDim.x + threadIdx.x;
  if (idx >= total) return;
  int nc = idx / hw;
  float p2 = p2p[0];
  float v = alpha[nc] * y[idx] + beta[nc] + p2 * u2[idx];
  if (noise) v += noise[idx % hw3];
  if (do_tanh) v = tanhf(v);
  out[idx] = v;
}

// ------------- QKV 1x1 "conv" (3x3 channel mix) -------------
__global__ __launch_bounds__(256) void qkv_kernel(
    const float* __restrict__ x, float* __restrict__ q, float* __restrict__ k, float* __restrict__ v,
    const float* __restrict__ qwp, const float* __restrict__ qbp,
    const float* __restrict__ kwp, const float* __restrict__ kbp,
    const float* __restrict__ vwp, const float* __restrict__ vbp,
    int N, int HW) {
  int idx = blockIdx.x * blockDim.x + threadIdx.x;
  if (idx >= N * HW) return;
  int p = idx % HW;
  int b = idx / HW;
  const float* xb = x + (size_t)b * 3 * HW + p;
  float x0 = xb[0], x1 = xb[HW], x2 = xb[2 * HW];
  size_t base = (size_t)b * 3 * HW + p;
  #pragma unroll
  for (int o = 0; o < 3; ++o) {
    q[base + (size_t)o * HW] = qwp[o * 3] * x0 + qwp[o * 3 + 1] * x1 + qwp[o * 3 + 2] * x2 + qbp[o];
    k[base + (size_t)o * HW] = kwp[o * 3] * x0 + kwp[o * 3 + 1] * x1 + kwp[o * 3 + 2] * x2 + kbp[o];
    v[base + (size_t)o * HW] = vwp[o * 3] * x0 + vwp[o * 3 + 1] * x1 + vwp[o * 3 + 2] * x2 + vbp[o];
  }
}

// ------------- attention pass 1: per-row max / sumexp (softmax over n for fixed m) -------------
__global__ __launch_bounds__(256) void attn_rows_kernel(
    const float* __restrict__ qg, const float* __restrict__ kg,
    float* __restrict__ M, float* __restrict__ L, int HW) {
  __shared__ float qs[3 * 1024];
  int chunks = HW / 256;
  int b  = blockIdx.x / chunks;
  int m0 = (blockIdx.x % chunks) * 256;
  const float* qb = qg + (size_t)b * 3 * HW;
  for (int t = threadIdx.x; t < 3 * HW; t += 256) qs[t] = qb[t];
  __syncthreads();
  int m = m0 + threadIdx.x;
  const float* kb = kg + (size_t)b * 3 * HW;
  float kx = kb[m], ky = kb[HW + m], kz = kb[2 * HW + m];
  float mr = -1e30f, l = 0.f;
  for (int n = 0; n < HW; ++n) {
    float s = kx * qs[n] + ky * qs[HW + n] + kz * qs[2 * HW + n];
    float nm = fmaxf(mr, s);
    l = l * __expf(mr - nm) + __expf(s - nm);
    mr = nm;
  }
  M[(size_t)b * HW + m] = mr;
  L[(size_t)b * HW + m] = 1.0f / l;
}

// ------------- attention pass 2: out[c,n] = sum_m v[c,m]*softmax + x -------------
__global__ __launch_bounds__(256) void attn_out_kernel(
    const float* __restrict__ qg, const float* __restrict__ kg, const float* __restrict__ vg,
    const float* __restrict__ M, const float* __restrict__ L,
    const float* __restrict__ x, float* __restrict__ out, int HW) {
  __shared__ float ks[3 * 1024], vs[3 * 1024], Ms[1024], Ls[1024];
  int chunks = HW / 256;
  int b  = blockIdx.x / chunks;
  int n0 = (blockIdx.x % chunks) * 256;
  const float* kb = kg + (size_t)b * 3 * HW;
  const float* vb = vg + (size_t)b * 3 * HW;
  for (int t = threadIdx.x; t < 3 * HW; t += 256) { ks[t] = kb[t]; vs[t] = vb[t]; }
  for (int t = threadIdx.x; t < HW; t += 256) {
    Ms[t] = M[(size_t)b * HW + t];
    Ls[t] = L[(size_t)b * HW + t];
  }
  __syncthreads();
  int n = n0 + threadIdx.x;
  const float* qb = qg + (size_t)b * 3 * HW;
  float q0 = qb[n], q1 = qb[HW + n], q2 = qb[2 * HW + n];
  float a0 = 0.f, a1 = 0.f, a2 = 0.f;
  for (int m = 0; m < HW; ++m) {
    float s = ks[m] * q0 + ks[HW + m] * q1 + ks[2 * HW + m] * q2;
    float w = __expf(s - Ms[m]) * Ls[m];
    a0 += vs[m] * w;
    a1 += vs[HW + m] * w;
    a2 += vs[2 * HW + m] * w;
  }
  size_t o0 = (size_t)b * 3 * HW + n;
  out[o0]          = a0 + x[o0];
  out[o0 + HW]     = a1 + x[o0 + HW];
  out[o0 + 2 * HW] = a2 + x[o0 + 2 * HW];
}

extern "C" void kernel_launch(void* const* d_in, const int* in_sizes, int n_in,
                              void* d_out, int out_size, void* d_ws, size_t ws_size,
                              hipStream_t stream) {
  const float* x       = (const float*)d_in[0];
  const float* noise_z = (const float*)d_in[1];
  const float* lin_w   = (const float*)d_in[2];
  const float* lin_b   = (const float*)d_in[3];
  const float* conv_w  = (const float*)d_in[4];
  const float* conv_b  = (const float*)d_in[5];
  const float* conv2_w = (const float*)d_in[6];
  const float* conv2_b = (const float*)d_in[7];
  const float* q_w     = (const float*)d_in[8];
  const float* q_b     = (const float*)d_in[9];
  const float* k_w     = (const float*)d_in[10];
  const float* k_b     = (const float*)d_in[11];
  const float* v_w     = (const float*)d_in[12];
  const float* v_b     = (const float*)d_in[13];
  const float* in_p    = (const float*)d_in[14];
  const float* ln_p    = (const float*)d_in[15];
  const float* bn_p    = (const float*)d_in[16];
  const float* bn_w    = (const float*)d_in[17];
  const float* bn_b    = (const float*)d_in[18];
  const float* p1      = (const float*)d_in[19];
  const float* p2      = (const float*)d_in[20];
  float* out = (float*)d_out;

  float* ws = (float*)d_ws;
  const size_t BIG = (size_t)32 * 3 * 256 * 256;  // 6,291,456
  float* B0  = ws;
  float* B1  = B0 + BIG;
  float* B2  = B1 + BIG;
  float* NB0 = B2 + BIG;            // noise buffers (1,3,64,64) max
  float* NB1 = NB0 + 12288;
  float* NB2 = NB1 + 12288;
  float* SUMS  = NB2 + 12288;       // 192
  float* ALPHA = SUMS + 192;        // 96
  float* BETA  = ALPHA + 96;        // 96
  float* Qb = BETA + 96;            // 32*3*1024 each
  float* Kb = Qb + 98304;
  float* Vb = Kb + 98304;
  float* Mb = Vb + 98304;           // 32*1024
  float* Lb = Mb + 32768;

  auto run_block = [&](int i, int N, int Hin, int r, const float* cur,
                       float* ybuf, float* u2buf, const float* noise, float* final_out) {
    int hc = Hin - 4, wc = Hin - 4;
    int hw = r * r;
    int total = N * 3 * hw;
    conv_up_kernel<<<(total + 255) / 256, 256, 0, stream>>>(
        cur, ybuf, u2buf, conv_w + i * 225, conv_b + i * 3,
        conv2_w + i * 225, conv2_b + i * 3, N, Hin, Hin, hc, wc, r);
    stats_kernel<<<N * 3, 256, 0, stream>>>(ybuf, SUMS, hw);
    finalize_kernel<<<1, 128, 0, stream>>>(SUMS, ALPHA, BETA, N, hw,
        in_p + 3 * i, ln_p + 3 * i, bn_p + 3 * i, bn_w + 3 * i, bn_b + 3 * i, p1 + i);
    float* dtgt = final_out ? final_out : ybuf;
    elemD_kernel<<<(total + 255) / 256, 256, 0, stream>>>(
        ybuf, u2buf, ALPHA, BETA, p2 + i, noise, dtgt, total, hw, 3 * hw,
        final_out ? 1 : 0);
  };

  // ---- noise path: Linear -> (1,3,16,16) -> block0 (r=32) -> block1 (r=64) ----
  linear_kernel<<<3, 256, 0, stream>>>(noise_z, lin_w, lin_b, NB0);
  run_block(0, 1, 16, 32, NB0, NB1, NB2, nullptr, nullptr);  // result in NB1
  run_block(1, 1, 32, 64, NB1, NB0, NB2, nullptr, nullptr);  // result in NB0

  // ---- main path ----
  struct Blk { int i, Hin, r, attn, noise; };
  const Blk blocks[10] = {
      {2, 256, 256, 0, 0}, {3, 256, 128, 0, 0}, {4, 128, 64, 0, 1},
      {5, 64, 32, 1, 0},   {6, 32, 16, 1, 0},   {7, 16, 16, 1, 0},
      {8, 16, 32, 1, 0},   {9, 32, 64, 0, 0},   {10, 64, 128, 0, 0},
      {11, 128, 256, 0, 0}};

  const float* curp = x;
  float* fa = B0;  // y target
  float* fb = B1;  // u2 target
  float* fc = B2;  // replacement slot while cur==x
  bool x_live = true;

  for (int t = 0; t < 10; ++t) {
    int i = blocks[t].i, Hin = blocks[t].Hin, r = blocks[t].r;
    bool last = (i == 11);
    float* y  = fa;
    float* u2 = fb;
    run_block(i, 32, Hin, r, curp, y, u2,
              blocks[t].noise ? NB0 : nullptr, last ? out : nullptr);
    const float* oldcur = curp;
    if (blocks[t].attn) {
      int HW = r * r;
      int tot = 32 * HW;
      qkv_kernel<<<(tot + 255) / 256, 256, 0, stream>>>(
          y, Qb, Kb, Vb, q_w + 9 * i, q_b + 3 * i, k_w + 9 * i, k_b + 3 * i,
          v_w + 9 * i, v_b + 3 * i, 32, HW);
      int chunks = HW / 256;
      attn_rows_kernel<<<32 * chunks, 256, 0, stream>>>(Qb, Kb, Mb, Lb, HW);
      attn_out_kernel<<<32 * chunks, 256, 0, stream>>>(Qb, Kb, Vb, Mb, Lb, y, u2, HW);
      curp = u2;                      // attention output
      fa = y;                         // y now free
      fb = x_live ? fc : (float*)oldcur;
    } else {
      curp = y;                       // elemD was in-place into y
      fa = x_live ? fc : (float*)oldcur;
      // fb (u2) stays as the other free buffer
    }
    x_live = false;
  }
}

// Round 2
// 643.375 us; speedup vs baseline: 1.3710x; 1.3710x over previous
//
#include <hip/hip_runtime.h>
#include <math.h>

#define EPS 1e-5f
#define LOG2E 1.44269504088896340736f

// ---------------- Linear: (1,512) @ (768,512)^T + b -> 768 ----------------
__global__ __launch_bounds__(256) void linear_kernel(
    const float* __restrict__ z, const float* __restrict__ w,
    const float* __restrict__ b, float* __restrict__ out) {
  int j = blockIdx.x * blockDim.x + threadIdx.x;
  if (j >= 768) return;
  const float* wr = w + j * 512;
  float acc = b[j];
  for (int k = 0; k < 512; ++k) acc = fmaf(z[k], wr[k], acc);
  out[j] = acc;
}

// ---- conv5 (both weight sets, 3 out channels, TX pixels/thread) at distinct
// ---- source grid S x S, fused per-(n,c) sum/sumsq stats via atomics. ----
// upsample (r>hc): stored grid = src grid (S=hc), stats weighted by multiplicity.
// downsample (r<=hc): stored grid = output grid (S=r), src pos = (p*hc)/r.
template <int TX>
__global__ __launch_bounds__(256) void conv_src_kernel(
    const float* __restrict__ in, float* __restrict__ ys, float* __restrict__ u2s,
    const float* __restrict__ w1, const float* __restrict__ b1,
    const float* __restrict__ w2, const float* __restrict__ b2,
    float* __restrict__ sums, int N, int Hin, int S, int hc, int r,
    int upsample, int bpi) {
  int n = blockIdx.x / bpi;
  int t = (blockIdx.x % bpi) * 256 + threadIdx.x;
  int SX = S / TX;
  int py = t / SX;
  int pxg = t - py * SX;
  int px0 = pxg * TX;
  bool valid = (py < S);
  float a1[3][TX], a2[3][TX];
  #pragma unroll
  for (int c = 0; c < 3; ++c) {
    float bb1 = b1[c], bb2 = b2[c];
    #pragma unroll
    for (int x = 0; x < TX; ++x) { a1[c][x] = bb1; a2[c][x] = bb2; }
  }
  float sc[3] = {0.f, 0.f, 0.f}, sq[3] = {0.f, 0.f, 0.f};
  if (valid) {
    int sy, sx0;
    if (upsample) { sy = py; sx0 = px0; }
    else { sy = (py * hc) / r; sx0 = (px0 * hc) / r; }
    const float* ip0 = in + ((size_t)(n * 3) * Hin + sy) * Hin + sx0;
    #pragma unroll
    for (int ci = 0; ci < 3; ++ci) {
      const float* ip = ip0 + (size_t)ci * Hin * Hin;
      #pragma unroll
      for (int ky = 0; ky < 5; ++ky) {
        const float* row = ip + ky * Hin;
        float v[4 + TX];
        #pragma unroll
        for (int kx = 0; kx < 4 + TX; ++kx) v[kx] = row[kx];
        #pragma unroll
        for (int c = 0; c < 3; ++c) {
          const float* wp1 = w1 + c * 75 + ci * 25 + ky * 5;
          const float* wp2 = w2 + c * 75 + ci * 25 + ky * 5;
          #pragma unroll
          for (int kx = 0; kx < 5; ++kx) {
            float wv1 = wp1[kx], wv2 = wp2[kx];
            #pragma unroll
            for (int x = 0; x < TX; ++x) {
              a1[c][x] = fmaf(v[kx + x], wv1, a1[c][x]);
              a2[c][x] = fmaf(v[kx + x], wv2, a2[c][x]);
            }
          }
        }
      }
    }
    float wy = 1.f, wx[TX];
    if (upsample) {
      wy = (float)(((py + 1) * r + hc - 1) / hc - (py * r + hc - 1) / hc);
      #pragma unroll
      for (int x = 0; x < TX; ++x) {
        int px = px0 + x;
        wx[x] = (float)(((px + 1) * r + hc - 1) / hc - (px * r + hc - 1) / hc);
      }
    } else {
      #pragma unroll
      for (int x = 0; x < TX; ++x) wx[x] = 1.f;
    }
    int base = (n * 3) * S * S + py * S + px0;
    #pragma unroll
    for (int c = 0; c < 3; ++c) {
      #pragma unroll
      for (int x = 0; x < TX; ++x) {
        ys[base + c * S * S + x] = a1[c][x];
        u2s[base + c * S * S + x] = a2[c][x];
        float wgt = wy * wx[x];
        sc[c] += a1[c][x] * wgt;
        sq[c] += a1[c][x] * a1[c][x] * wgt;
      }
    }
  }
  #pragma unroll
  for (int off = 32; off; off >>= 1) {
    #pragma unroll
    for (int c = 0; c < 3; ++c) {
      sc[c] += __shfl_down(sc[c], off);
      sq[c] += __shfl_down(sq[c], off);
    }
  }
  __shared__ float redS[4][3], redQ[4][3];
  int wid = threadIdx.x >> 6, lane = threadIdx.x & 63;
  if (lane == 0) {
    #pragma unroll
    for (int c = 0; c < 3; ++c) { redS[wid][c] = sc[c]; redQ[wid][c] = sq[c]; }
  }
  __syncthreads();
  if (threadIdx.x < 3) {
    int c = threadIdx.x;
    atomicAdd(&sums[2 * (n * 3 + c)],     redS[0][c] + redS[1][c] + redS[2][c] + redS[3][c]);
    atomicAdd(&sums[2 * (n * 3 + c) + 1], redQ[0][c] + redQ[1][c] + redQ[2][c] + redQ[3][c]);
  }
}

// ---- elemD: inline finalize (alpha/beta from SUMS), gather upsample,
// ---- y2 = alpha*y + beta + p2*u2 (+noise)(tanh), optional fused QKV ----
__global__ __launch_bounds__(256) void elemD_kernel(
    const float* __restrict__ ys, const float* __restrict__ u2s,
    const float* __restrict__ sums,
    const float* __restrict__ inp, const float* __restrict__ lnp,
    const float* __restrict__ bnp, const float* __restrict__ bnw,
    const float* __restrict__ bnb, const float* __restrict__ p1p,
    const float* __restrict__ p2p,
    const float* __restrict__ noise, float* __restrict__ out,
    float* __restrict__ qo, float* __restrict__ ko, float* __restrict__ vo,
    const float* __restrict__ qwp, const float* __restrict__ qbp,
    const float* __restrict__ kwp, const float* __restrict__ kbp,
    const float* __restrict__ vwp, const float* __restrict__ vbp,
    int N, int S, int hc, int r, int upsample, int do_tanh) {
  int hw = r * r;
  int bpi = hw >> 8;
  int n = blockIdx.x / bpi;
  int p = (blockIdx.x % bpi) * 256 + threadIdx.x;
  __shared__ float Ab[3], Bb[3];
  if (threadIdx.x < 3) {
    int c = threadIdx.x;
    float si_ = inp[0] + inp[1] + inp[2] + lnp[0] + lnp[1] + lnp[2];
    float sb = bnp[0] + bnp[1] + bnp[2];
    float inv = 1.0f / (float)hw;
    float s1 = sums[2 * (n * 3 + c)], s2 = sums[2 * (n * 3 + c) + 1];
    float mi = s1 * inv;
    float vi = s2 * inv - mi * mi;
    float ri = rsqrtf(vi + EPS);
    float bs = 0.f, bs2 = 0.f;
    for (int nn = 0; nn < N; ++nn) {
      bs += sums[2 * (nn * 3 + c)];
      bs2 += sums[2 * (nn * 3 + c) + 1];
    }
    float invb = 1.0f / ((float)N * (float)hw);
    float mb = bs * invb;
    float vbv = bs2 * invb - mb * mb;
    float rb = rsqrtf(vbv + EPS);
    float w = bnw[c];
    float A = 1.0f + si_ * ri + sb * rb * w;
    float B = -(si_ * ri * mi + sb * rb * w * mb) + sb * bnb[c];
    float p1 = p1p[0];
    Ab[c] = A * p1;
    Bb[c] = B * p1;
  }
  __syncthreads();
  int oy = p / r, ox = p - oy * r;
  int si = upsample ? ((oy * hc) / r) * S + (ox * hc) / r : p;
  float p2 = p2p[0];
  float v[3];
  #pragma unroll
  for (int c = 0; c < 3; ++c) {
    int ibase = (n * 3 + c) * S * S + si;
    float val = Ab[c] * ys[ibase] + Bb[c] + p2 * u2s[ibase];
    if (noise) val += noise[c * hw + p];
    if (do_tanh) val = tanhf(val);
    v[c] = val;
    out[(n * 3 + c) * hw + p] = val;
  }
  if (qo) {
    int b3 = n * 3;
    #pragma unroll
    for (int o = 0; o < 3; ++o) {
      float qv = qbp[o], kv = kbp[o], vv = vbp[o];
      #pragma unroll
      for (int c = 0; c < 3; ++c) {
        qv = fmaf(qwp[o * 3 + c], v[c], qv);
        kv = fmaf(kwp[o * 3 + c], v[c], kv);
        vv = fmaf(vwp[o * 3 + c], v[c], vv);
      }
      qo[(b3 + o) * hw + p] = qv;
      ko[(b3 + o) * hw + p] = kv * LOG2E;   // pre-scale k into log2 domain
      vo[(b3 + o) * hw + p] = vv;
    }
  }
}

// ---- attention pass 1 (4-way n-partitioned): partial row max / sumexp ----
__global__ __launch_bounds__(256) void attn_rows_kernel(
    const float* __restrict__ qg, const float* __restrict__ kg,
    float* __restrict__ Mp, float* __restrict__ Lp, int HW, int mchunks) {
  int plen = HW >> 2;
  __shared__ float qs[768];
  int bid = blockIdx.x;
  int np = bid & 3; bid >>= 2;
  int mc = bid % mchunks;
  int b = bid / mchunks;
  const float* qb_ = qg + (size_t)b * 3 * HW + np * plen;
  for (int t = threadIdx.x; t < 3 * plen; t += 256) {
    int c = t / plen, j = t - c * plen;
    qs[t] = qb_[c * HW + j];
  }
  __syncthreads();
  int m = mc * 256 + threadIdx.x;
  const float* kb_ = kg + (size_t)b * 3 * HW;
  float kx = kb_[m], ky = kb_[HW + m], kz = kb_[2 * HW + m];
  float mr = -1e30f;
  for (int j = 0; j < plen; ++j) {
    float s = kx * qs[j] + ky * qs[plen + j] + kz * qs[2 * plen + j];
    mr = fmaxf(mr, s);
  }
  float l = 0.f;
  for (int j = 0; j < plen; ++j) {
    float s = kx * qs[j] + ky * qs[plen + j] + kz * qs[2 * plen + j];
    l += exp2f(s - mr);
  }
  int idx = (b * 4 + np) * HW + m;
  Mp[idx] = mr;
  Lp[idx] = l;
}

// ---- attention pass 2 (4-way m-partitioned): merge partials, atomic out ----
__global__ __launch_bounds__(256) void attn_out_kernel(
    const float* __restrict__ qg, const float* __restrict__ kg,
    const float* __restrict__ vg,
    const float* __restrict__ Mp, const float* __restrict__ Lp,
    const float* __restrict__ y2, float* __restrict__ aout, int HW, int nchunks) {
  int plen = HW >> 2;
  __shared__ float ks[768], vs[768], Ms[256], Ls[256];
  int bid = blockIdx.x;
  int mp = bid & 3; bid >>= 2;
  int nc = bid % nchunks;
  int b = bid / nchunks;
  int m0 = mp * plen;
  const float* kb_ = kg + (size_t)b * 3 * HW + m0;
  const float* vb_ = vg + (size_t)b * 3 * HW + m0;
  for (int t = threadIdx.x; t < 3 * plen; t += 256) {
    int c = t / plen, j = t - c * plen;
    ks[t] = kb_[c * HW + j];
    vs[t] = vb_[c * HW + j];
  }
  for (int t = threadIdx.x; t < plen; t += 256) {
    int m = m0 + t;
    float M0 = Mp[(b * 4 + 0) * HW + m], M1 = Mp[(b * 4 + 1) * HW + m];
    float M2 = Mp[(b * 4 + 2) * HW + m], M3 = Mp[(b * 4 + 3) * HW + m];
    float L0 = Lp[(b * 4 + 0) * HW + m], L1 = Lp[(b * 4 + 1) * HW + m];
    float L2 = Lp[(b * 4 + 2) * HW + m], L3 = Lp[(b * 4 + 3) * HW + m];
    float MM = fmaxf(fmaxf(M0, M1), fmaxf(M2, M3));
    float LL = L0 * exp2f(M0 - MM) + L1 * exp2f(M1 - MM) +
               L2 * exp2f(M2 - MM) + L3 * exp2f(M3 - MM);
    Ms[t] = MM;
    Ls[t] = 1.0f / LL;
  }
  __syncthreads();
  int nn = nc * 256 + threadIdx.x;
  const float* qb_ = qg + (size_t)b * 3 * HW;
  float q0 = qb_[nn], q1 = qb_[HW + nn], q2 = qb_[2 * HW + nn];
  float a0 = 0.f, a1 = 0.f, a2 = 0.f;
  for (int j = 0; j < plen; ++j) {
    float s = ks[j] * q0 + ks[plen + j] * q1 + ks[2 * plen + j] * q2;
    float w = exp2f(s - Ms[j]) * Ls[j];
    a0 = fmaf(vs[j], w, a0);
    a1 = fmaf(vs[plen + j], w, a1);
    a2 = fmaf(vs[2 * plen + j], w, a2);
  }
  size_t o0 = (size_t)b * 3 * HW + nn;
  if (mp == 0) { a0 += y2[o0]; a1 += y2[o0 + HW]; a2 += y2[o0 + 2 * HW]; }
  atomicAdd(&aout[o0], a0);
  atomicAdd(&aout[o0 + HW], a1);
  atomicAdd(&aout[o0 + 2 * HW], a2);
}

extern "C" void kernel_launch(void* const* d_in, const int* in_sizes, int n_in,
                              void* d_out, int out_size, void* d_ws, size_t ws_size,
                              hipStream_t stream) {
  const float* x       = (const float*)d_in[0];
  const float* noise_z = (const float*)d_in[1];
  const float* lin_w   = (const float*)d_in[2];
  const float* lin_b   = (const float*)d_in[3];
  const float* conv_w  = (const float*)d_in[4];
  const float* conv_b  = (const float*)d_in[5];
  const float* conv2_w = (const float*)d_in[6];
  const float* conv2_b = (const float*)d_in[7];
  const float* q_w     = (const float*)d_in[8];
  const float* q_b     = (const float*)d_in[9];
  const float* k_w     = (const float*)d_in[10];
  const float* k_b     = (const float*)d_in[11];
  const float* v_w     = (const float*)d_in[12];
  const float* v_b     = (const float*)d_in[13];
  const float* in_p    = (const float*)d_in[14];
  const float* ln_p    = (const float*)d_in[15];
  const float* bn_p    = (const float*)d_in[16];
  const float* bn_w    = (const float*)d_in[17];
  const float* bn_b    = (const float*)d_in[18];
  const float* p1      = (const float*)d_in[19];
  const float* p2      = (const float*)d_in[20];
  float* out = (float*)d_out;

  float* ws = (float*)d_ws;
  const size_t BIG = (size_t)32 * 3 * 256 * 256;  // 6,291,456 floats
  float* P0  = ws;
  float* P1  = P0 + BIG;
  float* P2  = P1 + BIG;
  float* NB0 = P2 + BIG;
  float* NB1 = NB0 + 12288;
  float* NB2 = NB1 + 12288;
  float* NB3 = NB2 + 12288;
  float* ZRO  = NB3 + 12288;          // zeroed region start
  float* SUMS = ZRO;                  // 12 * 192
  float* A5 = ZRO + 2304;             // attn outputs (zero-init for atomics)
  float* A6 = A5 + 98304;
  float* A7 = A6 + 24576;
  float* A8 = A7 + 24576;
  size_t zro_floats = 2304 + 98304 + 24576 + 24576 + 98304;  // 248064
  float* Qb = A8 + 98304;
  float* Kb = Qb + 98304;
  float* Vb = Kb + 98304;
  float* Mp = Vb + 98304;             // 4*32*1024
  float* Lp = Mp + 131072;

  hipMemsetAsync(ZRO, 0, zro_floats * sizeof(float), stream);

  const float* nul = nullptr;

  // ---- noise path ----
  linear_kernel<<<3, 256, 0, stream>>>(noise_z, lin_w, lin_b, NB0);
  // block 0: Hin=16, hc=12, r=32, upsample, S=12, TX=2, bpi=1
  conv_src_kernel<2><<<1, 256, 0, stream>>>(NB0, NB1, NB2, conv_w, conv_b,
      conv2_w, conv2_b, SUMS, 1, 16, 12, 12, 32, 1, 1);
  elemD_kernel<<<4, 256, 0, stream>>>(NB1, NB2, SUMS, in_p, ln_p, bn_p, bn_w,
      bn_b, p1, p2, nul, NB3, nullptr, nullptr, nullptr, nul, nul, nul, nul,
      nul, nul, 1, 12, 12, 32, 1, 0);
  // block 1: Hin=32, hc=28, r=64, upsample, S=28, TX=2, bpi=2
  conv_src_kernel<2><<<2, 256, 0, stream>>>(NB3, NB1, NB2, conv_w + 225,
      conv_b + 3, conv2_w + 225, conv2_b + 3, SUMS + 192, 1, 32, 28, 28, 64, 1, 2);
  elemD_kernel<<<16, 256, 0, stream>>>(NB1, NB2, SUMS + 192, in_p + 3, ln_p + 3,
      bn_p + 3, bn_w + 3, bn_b + 3, p1 + 1, p2 + 1, nul, NB0, nullptr, nullptr,
      nullptr, nul, nul, nul, nul, nul, nul, 1, 28, 28, 64, 1, 0);
  // final noise activation: NB0 (1,3,64,64)

  // ---- main path ----
  struct Blk { int i, Hin, r, S, up, tx, attn, noise; };
  const Blk blocks[10] = {
      {2, 256, 256, 252, 1, 2, 0, 0}, {3, 256, 128, 128, 0, 1, 0, 0},
      {4, 128, 64, 64, 0, 1, 0, 1},   {5, 64, 32, 32, 0, 1, 1, 0},
      {6, 32, 16, 16, 0, 1, 1, 0},    {7, 16, 16, 12, 1, 2, 1, 0},
      {8, 16, 32, 12, 1, 2, 1, 0},    {9, 32, 64, 28, 1, 2, 0, 0},
      {10, 64, 128, 60, 1, 2, 0, 0},  {11, 128, 256, 124, 1, 2, 0, 0}};
  float* aouts[4] = {A5, A6, A7, A8};
  int ai = 0;

  const float* cur = x;
  float* slots[3] = {P0, P1, P2};

  for (int t = 0; t < 10; ++t) {
    const Blk& bk = blocks[t];
    int i = bk.i, Hin = bk.Hin, r = bk.r, S = bk.S, up = bk.up;
    int hc = Hin - 4;
    bool last = (i == 11);
    float* fr[3]; int nf = 0;
    for (int s = 0; s < 3; ++s) if (slots[s] != cur) fr[nf++] = slots[s];
    float* ysb = fr[0];
    float* u2b = fr[1];
    float* y2d = last ? out : (nf == 3 ? fr[2] : (float*)cur);

    int SX = S / bk.tx;
    int bpi = (S * SX + 255) / 256;
    if (bk.tx == 2)
      conv_src_kernel<2><<<32 * bpi, 256, 0, stream>>>(cur, ysb, u2b,
          conv_w + 225 * i, conv_b + 3 * i, conv2_w + 225 * i, conv2_b + 3 * i,
          SUMS + 192 * i, 32, Hin, S, hc, r, up, bpi);
    else
      conv_src_kernel<1><<<32 * bpi, 256, 0, stream>>>(cur, ysb, u2b,
          conv_w + 225 * i, conv_b + 3 * i, conv2_w + 225 * i, conv2_b + 3 * i,
          SUMS + 192 * i, 32, Hin, S, hc, r, up, bpi);

    int hw = r * r;
    if (bk.attn)
      elemD_kernel<<<32 * (hw >> 8), 256, 0, stream>>>(ysb, u2b, SUMS + 192 * i,
          in_p + 3 * i, ln_p + 3 * i, bn_p + 3 * i, bn_w + 3 * i, bn_b + 3 * i,
          p1 + i, p2 + i, bk.noise ? NB0 : nul, y2d, Qb, Kb, Vb,
          q_w + 9 * i, q_b + 3 * i, k_w + 9 * i, k_b + 3 * i,
          v_w + 9 * i, v_b + 3 * i, 32, S, hc, r, up, 0);
    else
      elemD_kernel<<<32 * (hw >> 8), 256, 0, stream>>>(ysb, u2b, SUMS + 192 * i,
          in_p + 3 * i, ln_p + 3 * i, bn_p + 3 * i, bn_w + 3 * i, bn_b + 3 * i,
          p1 + i, p2 + i, bk.noise ? NB0 : nul, y2d, nullptr, nullptr, nullptr,
          nul, nul, nul, nul, nul, nul, 32, S, hc, r, up, last ? 1 : 0);

    if (bk.attn) {
      int HW = hw;
      int mch = HW >> 8;            // 4 at HW=1024, 1 at HW=256
      attn_rows_kernel<<<32 * mch * 4, 256, 0, stream>>>(Qb, Kb, Mp, Lp, HW, mch);
      attn_out_kernel<<<32 * mch * 4, 256, 0, stream>>>(Qb, Kb, Vb, Mp, Lp, y2d,
          aouts[ai], HW, mch);
      cur = aouts[ai];
      ++ai;
    } else {
      cur = y2d;
    }
  }
}

// Round 3
// 607.691 us; speedup vs baseline: 1.4515x; 1.0587x over previous
//
#include <hip/hip_runtime.h>
#include <math.h>

#define EPS 1e-5f
#define LOG2E 1.44269504088896340736f

// ---------------- Linear: (1,512) @ (768,512)^T + b -> 768 ----------------
__global__ __launch_bounds__(256) void linear_kernel(
    const float* __restrict__ z, const float* __restrict__ w,
    const float* __restrict__ b, float* __restrict__ out) {
  int j = blockIdx.x * blockDim.x + threadIdx.x;
  if (j >= 768) return;
  const float* wr = w + j * 512;
  float acc = b[j];
  for (int k = 0; k < 512; ++k) acc = fmaf(z[k], wr[k], acc);
  out[j] = acc;
}

// ---- small-upsample conv (S<=12 blocks): R2 path, global loads ----
template <int TX>
__global__ __launch_bounds__(256) void conv_src_kernel(
    const float* __restrict__ in, float* __restrict__ ys, float* __restrict__ u2s,
    const float* __restrict__ w1, const float* __restrict__ b1,
    const float* __restrict__ w2, const float* __restrict__ b2,
    float* __restrict__ sums, int N, int Hin, int S, int hc, int r,
    int upsample, int bpi) {
  int n = blockIdx.x / bpi;
  int t = (blockIdx.x % bpi) * 256 + threadIdx.x;
  int SX = S / TX;
  int py = t / SX;
  int pxg = t - py * SX;
  int px0 = pxg * TX;
  bool valid = (py < S);
  float a1[3][TX], a2[3][TX];
  #pragma unroll
  for (int c = 0; c < 3; ++c) {
    float bb1 = b1[c], bb2 = b2[c];
    #pragma unroll
    for (int x = 0; x < TX; ++x) { a1[c][x] = bb1; a2[c][x] = bb2; }
  }
  float sc[3] = {0.f, 0.f, 0.f}, sq[3] = {0.f, 0.f, 0.f};
  if (valid) {
    int sy, sx0;
    if (upsample) { sy = py; sx0 = px0; }
    else { sy = (py * hc) / r; sx0 = (px0 * hc) / r; }
    const float* ip0 = in + ((size_t)(n * 3) * Hin + sy) * Hin + sx0;
    #pragma unroll
    for (int ci = 0; ci < 3; ++ci) {
      const float* ip = ip0 + (size_t)ci * Hin * Hin;
      #pragma unroll
      for (int ky = 0; ky < 5; ++ky) {
        const float* row = ip + ky * Hin;
        float v[4 + TX];
        #pragma unroll
        for (int kx = 0; kx < 4 + TX; ++kx) v[kx] = row[kx];
        #pragma unroll
        for (int c = 0; c < 3; ++c) {
          const float* wp1 = w1 + c * 75 + ci * 25 + ky * 5;
          const float* wp2 = w2 + c * 75 + ci * 25 + ky * 5;
          #pragma unroll
          for (int kx = 0; kx < 5; ++kx) {
            float wv1 = wp1[kx], wv2 = wp2[kx];
            #pragma unroll
            for (int x = 0; x < TX; ++x) {
              a1[c][x] = fmaf(v[kx + x], wv1, a1[c][x]);
              a2[c][x] = fmaf(v[kx + x], wv2, a2[c][x]);
            }
          }
        }
      }
    }
    float wy = 1.f, wx[TX];
    if (upsample) {
      wy = (float)(((py + 1) * r + hc - 1) / hc - (py * r + hc - 1) / hc);
      #pragma unroll
      for (int x = 0; x < TX; ++x) {
        int px = px0 + x;
        wx[x] = (float)(((px + 1) * r + hc - 1) / hc - (px * r + hc - 1) / hc);
      }
    } else {
      #pragma unroll
      for (int x = 0; x < TX; ++x) wx[x] = 1.f;
    }
    int base = (n * 3) * S * S + py * S + px0;
    #pragma unroll
    for (int c = 0; c < 3; ++c) {
      #pragma unroll
      for (int x = 0; x < TX; ++x) {
        ys[base + c * S * S + x] = a1[c][x];
        u2s[base + c * S * S + x] = a2[c][x];
        float wgt = wy * wx[x];
        sc[c] += a1[c][x] * wgt;
        sq[c] += a1[c][x] * a1[c][x] * wgt;
      }
    }
  }
  #pragma unroll
  for (int off = 32; off; off >>= 1) {
    #pragma unroll
    for (int c = 0; c < 3; ++c) {
      sc[c] += __shfl_down(sc[c], off);
      sq[c] += __shfl_down(sq[c], off);
    }
  }
  __shared__ float redS[4][3], redQ[4][3];
  int wid = threadIdx.x >> 6, lane = threadIdx.x & 63;
  if (lane == 0) {
    #pragma unroll
    for (int c = 0; c < 3; ++c) { redS[wid][c] = sc[c]; redQ[wid][c] = sq[c]; }
  }
  __syncthreads();
  if (threadIdx.x < 3) {
    int c = threadIdx.x;
    atomicAdd(&sums[2 * (n * 3 + c)],     redS[0][c] + redS[1][c] + redS[2][c] + redS[3][c]);
    atomicAdd(&sums[2 * (n * 3 + c) + 1], redQ[0][c] + redQ[1][c] + redQ[2][c] + redQ[3][c]);
  }
}

// ---- LDS-tiled upsample conv: S==hc, 64x16 tile, TX=4, 3ch x 2conv ----
__global__ __launch_bounds__(256) void conv_up_tiled(
    const float* __restrict__ in, float* __restrict__ ys, float* __restrict__ u2s,
    const float* __restrict__ w1, const float* __restrict__ b1,
    const float* __restrict__ w2, const float* __restrict__ b2,
    float* __restrict__ sums, int Hin, int S, int r, int tilesX, int tilesY) {
  const int TW = 64, TH = 16, IW = 68, IH = 20;
  __shared__ float lin[3 * IH * IW];  // 16320 B, rows 16B-aligned (68*4=272)
  int tpi = tilesX * tilesY;
  int n = blockIdx.x / tpi;
  int trem = blockIdx.x - n * tpi;
  int tyB = trem / tilesX, txB = trem - tyB * tilesX;
  int px0 = txB * TW, py0 = tyB * TH;
  const float* inb = in + (size_t)n * 3 * Hin * Hin;
  for (int t = threadIdx.x; t < 3 * IH * IW; t += 256) {
    int cc = t / (IH * IW);
    int rem = t - cc * IH * IW;
    int rr = rem / IW, col = rem - rr * IW;
    int gy = py0 + rr; gy = gy < Hin ? gy : Hin - 1;
    int gx = px0 + col; gx = gx < Hin ? gx : Hin - 1;
    lin[t] = inb[((size_t)cc * Hin + gy) * Hin + gx];
  }
  __syncthreads();
  int tx = threadIdx.x & 15, ty = threadIdx.x >> 4;
  int lx0 = tx * 4;
  int px = px0 + lx0, py = py0 + ty;
  float a1[3][4], a2[3][4];
  #pragma unroll
  for (int c = 0; c < 3; ++c) {
    float bb1 = b1[c], bb2 = b2[c];
    #pragma unroll
    for (int x = 0; x < 4; ++x) { a1[c][x] = bb1; a2[c][x] = bb2; }
  }
  #pragma unroll 1
  for (int ci = 0; ci < 3; ++ci) {
    const float* lrow = lin + ci * IH * IW + ty * IW + lx0;
    const float* wp1 = w1 + ci * 25;
    const float* wp2 = w2 + ci * 25;
    #pragma unroll
    for (int ky = 0; ky < 5; ++ky) {
      float v[8];
      #pragma unroll
      for (int j = 0; j < 8; ++j) v[j] = lrow[ky * IW + j];
      #pragma unroll
      for (int c = 0; c < 3; ++c) {
        #pragma unroll
        for (int kx = 0; kx < 5; ++kx) {
          float wa = wp1[c * 75 + ky * 5 + kx];
          float wb = wp2[c * 75 + ky * 5 + kx];
          #pragma unroll
          for (int x = 0; x < 4; ++x) {
            a1[c][x] = fmaf(v[kx + x], wa, a1[c][x]);
            a2[c][x] = fmaf(v[kx + x], wb, a2[c][x]);
          }
        }
      }
    }
  }
  float sc[3] = {0.f, 0.f, 0.f}, sq[3] = {0.f, 0.f, 0.f};
  bool valid = (py < S) && (px < S);  // S%4==0 and px%4==0 -> whole quad valid
  if (valid) {
    int hc = S;
    float wy = (float)(((py + 1) * r + hc - 1) / hc - (py * r + hc - 1) / hc);
    float wx[4];
    #pragma unroll
    for (int x = 0; x < 4; ++x) {
      int pxx = px + x;
      wx[x] = (float)(((pxx + 1) * r + hc - 1) / hc - (pxx * r + hc - 1) / hc);
    }
    #pragma unroll
    for (int c = 0; c < 3; ++c) {
      size_t idx = ((size_t)(n * 3 + c) * S + py) * S + px;
      *reinterpret_cast<float4*>(ys + idx) =
          make_float4(a1[c][0], a1[c][1], a1[c][2], a1[c][3]);
      *reinterpret_cast<float4*>(u2s + idx) =
          make_float4(a2[c][0], a2[c][1], a2[c][2], a2[c][3]);
      #pragma unroll
      for (int x = 0; x < 4; ++x) {
        float wgt = wy * wx[x];
        sc[c] += a1[c][x] * wgt;
        sq[c] += a1[c][x] * a1[c][x] * wgt;
      }
    }
  }
  #pragma unroll
  for (int off = 32; off; off >>= 1) {
    #pragma unroll
    for (int c = 0; c < 3; ++c) {
      sc[c] += __shfl_down(sc[c], off);
      sq[c] += __shfl_down(sq[c], off);
    }
  }
  __shared__ float redS[4][3], redQ[4][3];
  int wid = threadIdx.x >> 6, lane = threadIdx.x & 63;
  if (lane == 0) {
    #pragma unroll
    for (int c = 0; c < 3; ++c) { redS[wid][c] = sc[c]; redQ[wid][c] = sq[c]; }
  }
  __syncthreads();
  if (threadIdx.x < 3) {
    int c = threadIdx.x;
    atomicAdd(&sums[2 * (n * 3 + c)],     redS[0][c] + redS[1][c] + redS[2][c] + redS[3][c]);
    atomicAdd(&sums[2 * (n * 3 + c) + 1], redQ[0][c] + redQ[1][c] + redQ[2][c] + redQ[3][c]);
  }
}

// ---- LDS-tiled downsample conv: ratio<2.05, 32x8 tile, 1 px/thread ----
__global__ __launch_bounds__(256) void conv_dn_tiled(
    const float* __restrict__ in, float* __restrict__ ys, float* __restrict__ u2s,
    const float* __restrict__ w1, const float* __restrict__ b1,
    const float* __restrict__ w2, const float* __restrict__ b2,
    float* __restrict__ sums, int Hin, int S, int hc, int logr,
    int tilesX, int tilesY) {
  const int TW = 32, TH = 8, IW = 68, IH = 20;
  __shared__ float lin[3 * IH * IW];
  int tpi = tilesX * tilesY;
  int n = blockIdx.x / tpi;
  int trem = blockIdx.x - n * tpi;
  int tyB = trem / tilesX, txB = trem - tyB * tilesX;
  int px0 = txB * TW, py0 = tyB * TH;
  int sy0 = (py0 * hc) >> logr, sx0 = (px0 * hc) >> logr;
  const float* inb = in + (size_t)n * 3 * Hin * Hin;
  for (int t = threadIdx.x; t < 3 * IH * IW; t += 256) {
    int cc = t / (IH * IW);
    int rem = t - cc * IH * IW;
    int rr = rem / IW, col = rem - rr * IW;
    int gy = sy0 + rr; gy = gy < Hin ? gy : Hin - 1;
    int gx = sx0 + col; gx = gx < Hin ? gx : Hin - 1;
    lin[t] = inb[((size_t)cc * Hin + gy) * Hin + gx];
  }
  __syncthreads();
  int tx = threadIdx.x & 31, ty = threadIdx.x >> 5;
  int px = px0 + tx, py = py0 + ty;
  int sxl = ((px * hc) >> logr) - sx0;
  int syl = ((py * hc) >> logr) - sy0;
  float a1[3], a2[3];
  #pragma unroll
  for (int c = 0; c < 3; ++c) { a1[c] = b1[c]; a2[c] = b2[c]; }
  #pragma unroll 1
  for (int ci = 0; ci < 3; ++ci) {
    const float* lrow = lin + ci * IH * IW + syl * IW + sxl;
    const float* wp1 = w1 + ci * 25;
    const float* wp2 = w2 + ci * 25;
    #pragma unroll
    for (int ky = 0; ky < 5; ++ky) {
      float v[5];
      #pragma unroll
      for (int j = 0; j < 5; ++j) v[j] = lrow[ky * IW + j];
      #pragma unroll
      for (int c = 0; c < 3; ++c) {
        #pragma unroll
        for (int kx = 0; kx < 5; ++kx) {
          a1[c] = fmaf(v[kx], wp1[c * 75 + ky * 5 + kx], a1[c]);
          a2[c] = fmaf(v[kx], wp2[c * 75 + ky * 5 + kx], a2[c]);
        }
      }
    }
  }
  float sc[3] = {0.f, 0.f, 0.f}, sq[3] = {0.f, 0.f, 0.f};
  bool valid = (py < S) && (px < S);
  if (valid) {
    #pragma unroll
    for (int c = 0; c < 3; ++c) {
      size_t idx = ((size_t)(n * 3 + c) * S + py) * S + px;
      ys[idx] = a1[c];
      u2s[idx] = a2[c];
      sc[c] += a1[c];
      sq[c] += a1[c] * a1[c];
    }
  }
  #pragma unroll
  for (int off = 32; off; off >>= 1) {
    #pragma unroll
    for (int c = 0; c < 3; ++c) {
      sc[c] += __shfl_down(sc[c], off);
      sq[c] += __shfl_down(sq[c], off);
    }
  }
  __shared__ float redS[4][3], redQ[4][3];
  int wid = threadIdx.x >> 6, lane = threadIdx.x & 63;
  if (lane == 0) {
    #pragma unroll
    for (int c = 0; c < 3; ++c) { redS[wid][c] = sc[c]; redQ[wid][c] = sq[c]; }
  }
  __syncthreads();
  if (threadIdx.x < 3) {
    int c = threadIdx.x;
    atomicAdd(&sums[2 * (n * 3 + c)],     redS[0][c] + redS[1][c] + redS[2][c] + redS[3][c]);
    atomicAdd(&sums[2 * (n * 3 + c) + 1], redQ[0][c] + redQ[1][c] + redQ[2][c] + redQ[3][c]);
  }
}

// ---- elemD: inline finalize, gather upsample, affine+p2*u2 (+noise)(tanh), fused QKV ----
__global__ __launch_bounds__(256) void elemD_kernel(
    const float* __restrict__ ys, const float* __restrict__ u2s,
    const float* __restrict__ sums,
    const float* __restrict__ inp, const float* __restrict__ lnp,
    const float* __restrict__ bnp, const float* __restrict__ bnw,
    const float* __restrict__ bnb, const float* __restrict__ p1p,
    const float* __restrict__ p2p,
    const float* __restrict__ noise, float* __restrict__ out,
    float* __restrict__ qo, float* __restrict__ ko, float* __restrict__ vo,
    const float* __restrict__ qwp, const float* __restrict__ qbp,
    const float* __restrict__ kwp, const float* __restrict__ kbp,
    const float* __restrict__ vwp, const float* __restrict__ vbp,
    int N, int S, int hc, int r, int upsample, int do_tanh) {
  int hw = r * r;
  int bpi = hw >> 8;
  int n = blockIdx.x / bpi;
  int p = (blockIdx.x % bpi) * 256 + threadIdx.x;
  __shared__ float Ab[3], Bb[3];
  if (threadIdx.x < 3) {
    int c = threadIdx.x;
    float si_ = inp[0] + inp[1] + inp[2] + lnp[0] + lnp[1] + lnp[2];
    float sb = bnp[0] + bnp[1] + bnp[2];
    float inv = 1.0f / (float)hw;
    float s1 = sums[2 * (n * 3 + c)], s2 = sums[2 * (n * 3 + c) + 1];
    float mi = s1 * inv;
    float vi = s2 * inv - mi * mi;
    float ri = rsqrtf(vi + EPS);
    float bs = 0.f, bs2 = 0.f;
    for (int nn = 0; nn < N; ++nn) {
      bs += sums[2 * (nn * 3 + c)];
      bs2 += sums[2 * (nn * 3 + c) + 1];
    }
    float invb = 1.0f / ((float)N * (float)hw);
    float mb = bs * invb;
    float vbv = bs2 * invb - mb * mb;
    float rb = rsqrtf(vbv + EPS);
    float w = bnw[c];
    float A = 1.0f + si_ * ri + sb * rb * w;
    float B = -(si_ * ri * mi + sb * rb * w * mb) + sb * bnb[c];
    float p1 = p1p[0];
    Ab[c] = A * p1;
    Bb[c] = B * p1;
  }
  __syncthreads();
  int oy = p / r, ox = p - oy * r;
  int si = upsample ? ((oy * hc) / r) * S + (ox * hc) / r : p;
  float p2 = p2p[0];
  float v[3];
  #pragma unroll
  for (int c = 0; c < 3; ++c) {
    int ibase = (n * 3 + c) * S * S + si;
    float val = Ab[c] * ys[ibase] + Bb[c] + p2 * u2s[ibase];
    if (noise) val += noise[c * hw + p];
    if (do_tanh) val = tanhf(val);
    v[c] = val;
    out[(n * 3 + c) * hw + p] = val;
  }
  if (qo) {
    int b3 = n * 3;
    #pragma unroll
    for (int o = 0; o < 3; ++o) {
      float qv = qbp[o], kv = kbp[o], vv = vbp[o];
      #pragma unroll
      for (int c = 0; c < 3; ++c) {
        qv = fmaf(qwp[o * 3 + c], v[c], qv);
        kv = fmaf(kwp[o * 3 + c], v[c], kv);
        vv = fmaf(vwp[o * 3 + c], v[c], vv);
      }
      qo[(b3 + o) * hw + p] = qv;
      ko[(b3 + o) * hw + p] = kv * LOG2E;   // pre-scale k into log2 domain
      vo[(b3 + o) * hw + p] = vv;
    }
  }
}

// ---- attention pass 1 (HW=1024, 4-way n-partitioned): partial row max/sumexp ----
__global__ __launch_bounds__(256) void attn_rows_kernel(
    const float* __restrict__ qg, const float* __restrict__ kg,
    float* __restrict__ Mp, float* __restrict__ Lp, int HW, int mchunks) {
  int plen = HW >> 2;
  __shared__ float qs[768];
  int bid = blockIdx.x;
  int np = bid & 3; bid >>= 2;
  int mc = bid % mchunks;
  int b = bid / mchunks;
  const float* qb_ = qg + (size_t)b * 3 * HW + np * plen;
  for (int t = threadIdx.x; t < 3 * plen; t += 256) {
    int c = t / plen, j = t - c * plen;
    qs[t] = qb_[c * HW + j];
  }
  __syncthreads();
  int m = mc * 256 + threadIdx.x;
  const float* kb_ = kg + (size_t)b * 3 * HW;
  float kx = kb_[m], ky = kb_[HW + m], kz = kb_[2 * HW + m];
  float mr = -1e30f;
  for (int j = 0; j < plen; ++j) {
    float s = kx * qs[j] + ky * qs[plen + j] + kz * qs[2 * plen + j];
    mr = fmaxf(mr, s);
  }
  float l = 0.f;
  for (int j = 0; j < plen; ++j) {
    float s = kx * qs[j] + ky * qs[plen + j] + kz * qs[2 * plen + j];
    l += exp2f(s - mr);
  }
  int idx = (b * 4 + np) * HW + m;
  Mp[idx] = mr;
  Lp[idx] = l;
}

// ---- attention pass 2 (HW=1024, 4-way m-partitioned): merge, atomic out ----
__global__ __launch_bounds__(256) void attn_out_kernel(
    const float* __restrict__ qg, const float* __restrict__ kg,
    const float* __restrict__ vg,
    const float* __restrict__ Mp, const float* __restrict__ Lp,
    const float* __restrict__ y2, float* __restrict__ aout, int HW, int nchunks) {
  int plen = HW >> 2;
  __shared__ float ks[768], vs[768], Ms[256], Ls[256];
  int bid = blockIdx.x;
  int mp = bid & 3; bid >>= 2;
  int nc = bid % nchunks;
  int b = bid / nchunks;
  int m0 = mp * plen;
  const float* kb_ = kg + (size_t)b * 3 * HW + m0;
  const float* vb_ = vg + (size_t)b * 3 * HW + m0;
  for (int t = threadIdx.x; t < 3 * plen; t += 256) {
    int c = t / plen, j = t - c * plen;
    ks[t] = kb_[c * HW + j];
    vs[t] = vb_[c * HW + j];
  }
  for (int t = threadIdx.x; t < plen; t += 256) {
    int m = m0 + t;
    float M0 = Mp[(b * 4 + 0) * HW + m], M1 = Mp[(b * 4 + 1) * HW + m];
    float M2 = Mp[(b * 4 + 2) * HW + m], M3 = Mp[(b * 4 + 3) * HW + m];
    float L0 = Lp[(b * 4 + 0) * HW + m], L1 = Lp[(b * 4 + 1) * HW + m];
    float L2 = Lp[(b * 4 + 2) * HW + m], L3 = Lp[(b * 4 + 3) * HW + m];
    float MM = fmaxf(fmaxf(M0, M1), fmaxf(M2, M3));
    float LL = L0 * exp2f(M0 - MM) + L1 * exp2f(M1 - MM) +
               L2 * exp2f(M2 - MM) + L3 * exp2f(M3 - MM);
    Ms[t] = MM;
    Ls[t] = 1.0f / LL;
  }
  __syncthreads();
  int nn = nc * 256 + threadIdx.x;
  const float* qb_ = qg + (size_t)b * 3 * HW;
  float q0 = qb_[nn], q1 = qb_[HW + nn], q2 = qb_[2 * HW + nn];
  float a0 = 0.f, a1 = 0.f, a2 = 0.f;
  for (int j = 0; j < plen; ++j) {
    float s = ks[j] * q0 + ks[plen + j] * q1 + ks[2 * plen + j] * q2;
    float w = exp2f(s - Ms[j]) * Ls[j];
    a0 = fmaf(vs[j], w, a0);
    a1 = fmaf(vs[plen + j], w, a1);
    a2 = fmaf(vs[2 * plen + j], w, a2);
  }
  size_t o0 = (size_t)b * 3 * HW + nn;
  if (mp == 0) { a0 += y2[o0]; a1 += y2[o0 + HW]; a2 += y2[o0 + 2 * HW]; }
  atomicAdd(&aout[o0], a0);
  atomicAdd(&aout[o0 + HW], a1);
  atomicAdd(&aout[o0 + 2 * HW], a2);
}

// ---- fused attention for HW=256: one block per batch image ----
__global__ __launch_bounds__(256) void attn256_kernel(
    const float* __restrict__ qg, const float* __restrict__ kg,
    const float* __restrict__ vg, const float* __restrict__ y2,
    float* __restrict__ aout) {
  __shared__ float qs[768], ks[768], vs[768], Ms[256], Ls[256];
  int b = blockIdx.x;
  size_t base = (size_t)b * 768;
  for (int t = threadIdx.x; t < 768; t += 256) {
    qs[t] = qg[base + t];
    ks[t] = kg[base + t];
    vs[t] = vg[base + t];
  }
  __syncthreads();
  {
    int m = threadIdx.x;
    float kx = ks[m], ky = ks[256 + m], kz = ks[512 + m];
    float mr = -1e30f;
    for (int j = 0; j < 256; ++j) {
      float s = kx * qs[j] + ky * qs[256 + j] + kz * qs[512 + j];
      mr = fmaxf(mr, s);
    }
    float l = 0.f;
    for (int j = 0; j < 256; ++j) {
      float s = kx * qs[j] + ky * qs[256 + j] + kz * qs[512 + j];
      l += exp2f(s - mr);
    }
    Ms[m] = mr;
    Ls[m] = 1.0f / l;
  }
  __syncthreads();
  int nn = threadIdx.x;
  float q0 = qs[nn], q1 = qs[256 + nn], q2 = qs[512 + nn];
  float a0 = 0.f, a1 = 0.f, a2 = 0.f;
  for (int j = 0; j < 256; ++j) {
    float s = ks[j] * q0 + ks[256 + j] * q1 + ks[512 + j] * q2;
    float w = exp2f(s - Ms[j]) * Ls[j];
    a0 = fmaf(vs[j], w, a0);
    a1 = fmaf(vs[256 + j], w, a1);
    a2 = fmaf(vs[512 + j], w, a2);
  }
  aout[base + nn]       = a0 + y2[base + nn];
  aout[base + 256 + nn] = a1 + y2[base + 256 + nn];
  aout[base + 512 + nn] = a2 + y2[base + 512 + nn];
}

extern "C" void kernel_launch(void* const* d_in, const int* in_sizes, int n_in,
                              void* d_out, int out_size, void* d_ws, size_t ws_size,
                              hipStream_t stream) {
  const float* x       = (const float*)d_in[0];
  const float* noise_z = (const float*)d_in[1];
  const float* lin_w   = (const float*)d_in[2];
  const float* lin_b   = (const float*)d_in[3];
  const float* conv_w  = (const float*)d_in[4];
  const float* conv_b  = (const float*)d_in[5];
  const float* conv2_w = (const float*)d_in[6];
  const float* conv2_b = (const float*)d_in[7];
  const float* q_w     = (const float*)d_in[8];
  const float* q_b     = (const float*)d_in[9];
  const float* k_w     = (const float*)d_in[10];
  const float* k_b     = (const float*)d_in[11];
  const float* v_w     = (const float*)d_in[12];
  const float* v_b     = (const float*)d_in[13];
  const float* in_p    = (const float*)d_in[14];
  const float* ln_p    = (const float*)d_in[15];
  const float* bn_p    = (const float*)d_in[16];
  const float* bn_w    = (const float*)d_in[17];
  const float* bn_b    = (const float*)d_in[18];
  const float* p1      = (const float*)d_in[19];
  const float* p2      = (const float*)d_in[20];
  float* out = (float*)d_out;

  float* ws = (float*)d_ws;
  const size_t BIG = (size_t)32 * 3 * 256 * 256;  // 6,291,456 floats
  float* P0  = ws;
  float* P1  = P0 + BIG;
  float* P2  = P1 + BIG;
  float* NB0 = P2 + BIG;
  float* NB1 = NB0 + 12288;
  float* NB2 = NB1 + 12288;
  float* NB3 = NB2 + 12288;
  float* ZRO  = NB3 + 12288;          // zeroed region start
  float* SUMS = ZRO;                  // 12 * 192
  float* A5 = ZRO + 2304;             // attn outputs needing zero (atomics)
  float* A8 = A5 + 98304;
  size_t zro_floats = 2304 + 98304 + 98304;  // 198912
  float* A6 = A8 + 98304;             // fused-attn outputs (no zero needed)
  float* A7 = A6 + 24576;
  float* Qb = A7 + 24576;
  float* Kb = Qb + 98304;
  float* Vb = Kb + 98304;
  float* Mp = Vb + 98304;             // 4*32*1024
  float* Lp = Mp + 131072;

  hipMemsetAsync(ZRO, 0, zro_floats * sizeof(float), stream);

  const float* nul = nullptr;

  // ---- noise path ----
  linear_kernel<<<3, 256, 0, stream>>>(noise_z, lin_w, lin_b, NB0);
  conv_src_kernel<2><<<1, 256, 0, stream>>>(NB0, NB1, NB2, conv_w, conv_b,
      conv2_w, conv2_b, SUMS, 1, 16, 12, 12, 32, 1, 1);
  elemD_kernel<<<4, 256, 0, stream>>>(NB1, NB2, SUMS, in_p, ln_p, bn_p, bn_w,
      bn_b, p1, p2, nul, NB3, nullptr, nullptr, nullptr, nul, nul, nul, nul,
      nul, nul, 1, 12, 12, 32, 1, 0);
  conv_up_tiled<<<2, 256, 0, stream>>>(NB3, NB1, NB2, conv_w + 225,
      conv_b + 3, conv2_w + 225, conv2_b + 3, SUMS + 192, 32, 28, 64, 1, 2);
  elemD_kernel<<<16, 256, 0, stream>>>(NB1, NB2, SUMS + 192, in_p + 3, ln_p + 3,
      bn_p + 3, bn_w + 3, bn_b + 3, p1 + 1, p2 + 1, nul, NB0, nullptr, nullptr,
      nullptr, nul, nul, nul, nul, nul, nul, 1, 28, 28, 64, 1, 0);
  // noise activation now in NB0 (1,3,64,64)

  // ---- main path ----
  // kind: 0=conv_src<2> (tiny upsample), 1=conv_up_tiled, 2=conv_dn_tiled
  struct Blk { int i, Hin, r, S, kind, tX, tY, attn, noise; };
  const Blk blocks[10] = {
      {2, 256, 256, 252, 1, 4, 16, 0, 0}, {3, 256, 128, 128, 2, 4, 16, 0, 0},
      {4, 128, 64, 64, 2, 2, 8, 0, 1},    {5, 64, 32, 32, 2, 1, 4, 1, 0},
      {6, 32, 16, 16, 2, 1, 2, 1, 0},     {7, 16, 16, 12, 0, 0, 0, 1, 0},
      {8, 16, 32, 12, 0, 0, 0, 1, 0},     {9, 32, 64, 28, 1, 1, 2, 0, 0},
      {10, 64, 128, 60, 1, 1, 4, 0, 0},   {11, 128, 256, 124, 1, 2, 8, 0, 0}};
  float* aouts[4] = {A5, A6, A7, A8};
  int ai = 0;

  const float* cur = x;
  float* slots[3] = {P0, P1, P2};

  for (int t = 0; t < 10; ++t) {
    const Blk& bk = blocks[t];
    int i = bk.i, Hin = bk.Hin, r = bk.r, S = bk.S;
    int hc = Hin - 4;
    int up = (bk.kind != 2) ? 1 : 0;
    bool last = (i == 11);
    float* fr[3]; int nf = 0;
    for (int s = 0; s < 3; ++s) if (slots[s] != cur) fr[nf++] = slots[s];
    float* ysb = fr[0];
    float* u2b = fr[1];
    float* y2d = last ? out : (nf == 3 ? fr[2] : (float*)cur);

    if (bk.kind == 1) {
      int tpi = bk.tX * bk.tY;
      conv_up_tiled<<<32 * tpi, 256, 0, stream>>>(cur, ysb, u2b,
          conv_w + 225 * i, conv_b + 3 * i, conv2_w + 225 * i, conv2_b + 3 * i,
          SUMS + 192 * i, Hin, S, r, bk.tX, bk.tY);
    } else if (bk.kind == 2) {
      int tpi = bk.tX * bk.tY;
      conv_dn_tiled<<<32 * tpi, 256, 0, stream>>>(cur, ysb, u2b,
          conv_w + 225 * i, conv_b + 3 * i, conv2_w + 225 * i, conv2_b + 3 * i,
          SUMS + 192 * i, Hin, S, hc, __builtin_ctz(r), bk.tX, bk.tY);
    } else {
      int SX = S / 2;
      int bpi = (S * SX + 255) / 256;
      conv_src_kernel<2><<<32 * bpi, 256, 0, stream>>>(cur, ysb, u2b,
          conv_w + 225 * i, conv_b + 3 * i, conv2_w + 225 * i, conv2_b + 3 * i,
          SUMS + 192 * i, 32, Hin, S, hc, r, 1, bpi);
    }

    int hw = r * r;
    if (bk.attn)
      elemD_kernel<<<32 * (hw >> 8), 256, 0, stream>>>(ysb, u2b, SUMS + 192 * i,
          in_p + 3 * i, ln_p + 3 * i, bn_p + 3 * i, bn_w + 3 * i, bn_b + 3 * i,
          p1 + i, p2 + i, bk.noise ? NB0 : nul, y2d, Qb, Kb, Vb,
          q_w + 9 * i, q_b + 3 * i, k_w + 9 * i, k_b + 3 * i,
          v_w + 9 * i, v_b + 3 * i, 32, S, hc, r, up, 0);
    else
      elemD_kernel<<<32 * (hw >> 8), 256, 0, stream>>>(ysb, u2b, SUMS + 192 * i,
          in_p + 3 * i, ln_p + 3 * i, bn_p + 3 * i, bn_w + 3 * i, bn_b + 3 * i,
          p1 + i, p2 + i, bk.noise ? NB0 : nul, y2d, nullptr, nullptr, nullptr,
          nul, nul, nul, nul, nul, nul, 32, S, hc, r, up, last ? 1 : 0);

    if (bk.attn) {
      int HW = hw;
      if (HW == 1024) {
        attn_rows_kernel<<<32 * 4 * 4, 256, 0, stream>>>(Qb, Kb, Mp, Lp, HW, 4);
        attn_out_kernel<<<32 * 4 * 4, 256, 0, stream>>>(Qb, Kb, Vb, Mp, Lp, y2d,
            aouts[ai], HW, 4);
      } else {
        attn256_kernel<<<32, 256, 0, stream>>>(Qb, Kb, Vb, y2d, aouts[ai]);
      }
      cur = aouts[ai];
      ++ai;
    } else {
      cur = y2d;
    }
  }
}

// Round 4
// 597.632 us; speedup vs baseline: 1.4760x; 1.0168x over previous
//
#include <hip/hip_runtime.h>
#include <math.h>

#define EPS 1e-5f
#define LOG2E 1.44269504088896340736f

// ---------------- Linear: (1,512) @ (768,512)^T + b -> 768 ----------------
__global__ __launch_bounds__(256) void linear_kernel(
    const float* __restrict__ z, const float* __restrict__ w,
    const float* __restrict__ b, float* __restrict__ out) {
  int j = blockIdx.x * blockDim.x + threadIdx.x;
  if (j >= 768) return;
  const float* wr = w + j * 512;
  float acc = b[j];
  for (int k = 0; k < 512; ++k) acc = fmaf(z[k], wr[k], acc);
  out[j] = acc;
}

// ---- small-upsample conv (S<=12): direct global loads ----
template <int TX>
__global__ __launch_bounds__(256) void conv_src_kernel(
    const float* __restrict__ in, float* __restrict__ ys, float* __restrict__ u2s,
    const float* __restrict__ w1, const float* __restrict__ b1,
    const float* __restrict__ w2, const float* __restrict__ b2,
    float* __restrict__ sums, int N, int Hin, int S, int hc, int r,
    int upsample, int bpi) {
  int n = blockIdx.x / bpi;
  int t = (blockIdx.x % bpi) * 256 + threadIdx.x;
  int SX = S / TX;
  int py = t / SX;
  int pxg = t - py * SX;
  int px0 = pxg * TX;
  bool valid = (py < S);
  float a1[3][TX], a2[3][TX];
  #pragma unroll
  for (int c = 0; c < 3; ++c) {
    float bb1 = b1[c], bb2 = b2[c];
    #pragma unroll
    for (int x = 0; x < TX; ++x) { a1[c][x] = bb1; a2[c][x] = bb2; }
  }
  float sc[3] = {0.f, 0.f, 0.f}, sq[3] = {0.f, 0.f, 0.f};
  if (valid) {
    int sy, sx0;
    if (upsample) { sy = py; sx0 = px0; }
    else { sy = (py * hc) / r; sx0 = (px0 * hc) / r; }
    const float* ip0 = in + ((size_t)(n * 3) * Hin + sy) * Hin + sx0;
    #pragma unroll
    for (int ci = 0; ci < 3; ++ci) {
      const float* ip = ip0 + (size_t)ci * Hin * Hin;
      #pragma unroll
      for (int ky = 0; ky < 5; ++ky) {
        const float* row = ip + ky * Hin;
        float v[4 + TX];
        #pragma unroll
        for (int kx = 0; kx < 4 + TX; ++kx) v[kx] = row[kx];
        #pragma unroll
        for (int c = 0; c < 3; ++c) {
          const float* wp1 = w1 + c * 75 + ci * 25 + ky * 5;
          const float* wp2 = w2 + c * 75 + ci * 25 + ky * 5;
          #pragma unroll
          for (int kx = 0; kx < 5; ++kx) {
            float wv1 = wp1[kx], wv2 = wp2[kx];
            #pragma unroll
            for (int x = 0; x < TX; ++x) {
              a1[c][x] = fmaf(v[kx + x], wv1, a1[c][x]);
              a2[c][x] = fmaf(v[kx + x], wv2, a2[c][x]);
            }
          }
        }
      }
    }
    float wy = 1.f, wx[TX];
    if (upsample) {
      wy = (float)(((py + 1) * r + hc - 1) / hc - (py * r + hc - 1) / hc);
      #pragma unroll
      for (int x = 0; x < TX; ++x) {
        int px = px0 + x;
        wx[x] = (float)(((px + 1) * r + hc - 1) / hc - (px * r + hc - 1) / hc);
      }
    } else {
      #pragma unroll
      for (int x = 0; x < TX; ++x) wx[x] = 1.f;
    }
    int base = (n * 3) * S * S + py * S + px0;
    #pragma unroll
    for (int c = 0; c < 3; ++c) {
      #pragma unroll
      for (int x = 0; x < TX; ++x) {
        ys[base + c * S * S + x] = a1[c][x];
        u2s[base + c * S * S + x] = a2[c][x];
        float wgt = wy * wx[x];
        sc[c] += a1[c][x] * wgt;
        sq[c] += a1[c][x] * a1[c][x] * wgt;
      }
    }
  }
  #pragma unroll
  for (int off = 32; off; off >>= 1) {
    #pragma unroll
    for (int c = 0; c < 3; ++c) {
      sc[c] += __shfl_down(sc[c], off);
      sq[c] += __shfl_down(sq[c], off);
    }
  }
  __shared__ float redS[4][3], redQ[4][3];
  int wid = threadIdx.x >> 6, lane = threadIdx.x & 63;
  if (lane == 0) {
    #pragma unroll
    for (int c = 0; c < 3; ++c) { redS[wid][c] = sc[c]; redQ[wid][c] = sq[c]; }
  }
  __syncthreads();
  if (threadIdx.x < 3) {
    int c = threadIdx.x;
    atomicAdd(&sums[2 * (n * 3 + c)],     redS[0][c] + redS[1][c] + redS[2][c] + redS[3][c]);
    atomicAdd(&sums[2 * (n * 3 + c) + 1], redQ[0][c] + redQ[1][c] + redQ[2][c] + redQ[3][c]);
  }
}

// Shared fused-staging helpers (alpha/beta from prev SUMS, gather, affine).
// psums==nullptr => direct staging from `inb`. logrp>=0 => prev was upsample
// (src grid Sp==hc_prev, shift by logrp); logrp<0 => identity (Sp==Hin).
#define FUSED_AB_PROLOGUE(nvar)                                             \
  __shared__ float pA[3], pB[3]; __shared__ float pP2s;                     \
  if (psums) {                                                              \
    if (threadIdx.x == 0) pP2s = pp2[0];                                    \
    if (threadIdx.x < 3) {                                                  \
      int c = threadIdx.x;                                                  \
      float si_ = pinp[0]+pinp[1]+pinp[2]+plnp[0]+plnp[1]+plnp[2];          \
      float sb = pbnp[0]+pbnp[1]+pbnp[2];                                   \
      float hwp = (float)(Hin*Hin);                                         \
      float inv = 1.0f / hwp;                                               \
      float s1 = psums[2*((nvar)*3+c)], s2 = psums[2*((nvar)*3+c)+1];       \
      float mi = s1*inv, vi = s2*inv - mi*mi;                               \
      float ri = rsqrtf(vi+EPS);                                            \
      float bs=0.f, bs2=0.f;                                                \
      for (int nn=0; nn<pN; ++nn){ bs+=psums[2*(nn*3+c)];                   \
                                   bs2+=psums[2*(nn*3+c)+1]; }              \
      float invb = 1.0f/((float)pN*hwp);                                    \
      float mb=bs*invb, vbv=bs2*invb-mb*mb;                                 \
      float rb=rsqrtf(vbv+EPS);                                             \
      float wv=pbnw[c];                                                     \
      float A=1.0f+si_*ri+sb*rb*wv;                                         \
      float B=-(si_*ri*mi+sb*rb*wv*mb)+sb*pbnb[c];                          \
      float p1v=pp1[0];                                                     \
      pA[c]=A*p1v; pB[c]=B*p1v;                                             \
    }                                                                       \
    __syncthreads();                                                        \
  }

#define STAGE_VAL(nvar, cc, gy, gx, dst)                                    \
  {                                                                         \
    float val_;                                                             \
    if (psums) {                                                            \
      int si_ = (logrp >= 0)                                                \
        ? (((gy)*Sp)>>logrp)*Sp + (((gx)*Sp)>>logrp)                        \
        : (gy)*Sp + (gx);                                                   \
      size_t ib_ = (size_t)((nvar)*3+(cc))*(Sp*Sp) + si_;                   \
      val_ = pA[cc]*pys[ib_] + pB[cc] + pP2s*pu2[ib_];                      \
      if (pnoise) val_ += pnoise[((size_t)(cc)*Hin+(gy))*Hin+(gx)];         \
    } else {                                                                \
      val_ = inb[((size_t)(cc)*Hin+(gy))*Hin+(gx)];                         \
    }                                                                       \
    (dst) = val_;                                                           \
  }

// ---- LDS-tiled upsample conv: S==hc, 64x16 tile, TX=4, 3ch x 2conv ----
__global__ __launch_bounds__(256) void conv_up_tiled(
    const float* __restrict__ in, float* __restrict__ ys, float* __restrict__ u2s,
    const float* __restrict__ w1, const float* __restrict__ b1,
    const float* __restrict__ w2, const float* __restrict__ b2,
    float* __restrict__ sums, int Hin, int S, int r, int tilesX, int tilesY,
    const float* __restrict__ pys, const float* __restrict__ pu2,
    const float* __restrict__ psums,
    const float* __restrict__ pinp, const float* __restrict__ plnp,
    const float* __restrict__ pbnp, const float* __restrict__ pbnw,
    const float* __restrict__ pbnb, const float* __restrict__ pp1,
    const float* __restrict__ pp2, const float* __restrict__ pnoise,
    int pN, int Sp, int logrp) {
  const int TW = 64, TH = 16, IW = 68, IH = 20;
  __shared__ float lin[3 * IH * IW];
  int tpi = tilesX * tilesY;
  int n = blockIdx.x / tpi;
  int trem = blockIdx.x - n * tpi;
  int tyB = trem / tilesX, txB = trem - tyB * tilesX;
  int px0 = txB * TW, py0 = tyB * TH;
  const float* inb = in + (size_t)n * 3 * Hin * Hin;
  FUSED_AB_PROLOGUE(n)
  for (int t = threadIdx.x; t < 3 * IH * IW; t += 256) {
    int cc = t / (IH * IW);
    int rem = t - cc * IH * IW;
    int rr = rem / IW, col = rem - rr * IW;
    int gy = py0 + rr; gy = gy < Hin ? gy : Hin - 1;
    int gx = px0 + col; gx = gx < Hin ? gx : Hin - 1;
    STAGE_VAL(n, cc, gy, gx, lin[t])
  }
  __syncthreads();
  int tx = threadIdx.x & 15, ty = threadIdx.x >> 4;
  int lx0 = tx * 4;
  int px = px0 + lx0, py = py0 + ty;
  float a1[3][4], a2[3][4];
  #pragma unroll
  for (int c = 0; c < 3; ++c) {
    float bb1 = b1[c], bb2 = b2[c];
    #pragma unroll
    for (int x = 0; x < 4; ++x) { a1[c][x] = bb1; a2[c][x] = bb2; }
  }
  #pragma unroll 1
  for (int ci = 0; ci < 3; ++ci) {
    const float* lrow = lin + ci * IH * IW + ty * IW + lx0;
    const float* wp1 = w1 + ci * 25;
    const float* wp2 = w2 + ci * 25;
    #pragma unroll
    for (int ky = 0; ky < 5; ++ky) {
      float v[8];
      #pragma unroll
      for (int j = 0; j < 8; ++j) v[j] = lrow[ky * IW + j];
      #pragma unroll
      for (int c = 0; c < 3; ++c) {
        #pragma unroll
        for (int kx = 0; kx < 5; ++kx) {
          float wa = wp1[c * 75 + ky * 5 + kx];
          float wb = wp2[c * 75 + ky * 5 + kx];
          #pragma unroll
          for (int x = 0; x < 4; ++x) {
            a1[c][x] = fmaf(v[kx + x], wa, a1[c][x]);
            a2[c][x] = fmaf(v[kx + x], wb, a2[c][x]);
          }
        }
      }
    }
  }
  float sc[3] = {0.f, 0.f, 0.f}, sq[3] = {0.f, 0.f, 0.f};
  bool valid = (py < S) && (px < S);
  if (valid) {
    int hc = S;
    float wy = (float)(((py + 1) * r + hc - 1) / hc - (py * r + hc - 1) / hc);
    float wx[4];
    #pragma unroll
    for (int x = 0; x < 4; ++x) {
      int pxx = px + x;
      wx[x] = (float)(((pxx + 1) * r + hc - 1) / hc - (pxx * r + hc - 1) / hc);
    }
    #pragma unroll
    for (int c = 0; c < 3; ++c) {
      size_t idx = ((size_t)(n * 3 + c) * S + py) * S + px;
      *reinterpret_cast<float4*>(ys + idx) =
          make_float4(a1[c][0], a1[c][1], a1[c][2], a1[c][3]);
      *reinterpret_cast<float4*>(u2s + idx) =
          make_float4(a2[c][0], a2[c][1], a2[c][2], a2[c][3]);
      #pragma unroll
      for (int x = 0; x < 4; ++x) {
        float wgt = wy * wx[x];
        sc[c] += a1[c][x] * wgt;
        sq[c] += a1[c][x] * a1[c][x] * wgt;
      }
    }
  }
  #pragma unroll
  for (int off = 32; off; off >>= 1) {
    #pragma unroll
    for (int c = 0; c < 3; ++c) {
      sc[c] += __shfl_down(sc[c], off);
      sq[c] += __shfl_down(sq[c], off);
    }
  }
  __shared__ float redS[4][3], redQ[4][3];
  int wid = threadIdx.x >> 6, lane = threadIdx.x & 63;
  if (lane == 0) {
    #pragma unroll
    for (int c = 0; c < 3; ++c) { redS[wid][c] = sc[c]; redQ[wid][c] = sq[c]; }
  }
  __syncthreads();
  if (threadIdx.x < 3) {
    int c = threadIdx.x;
    atomicAdd(&sums[2 * (n * 3 + c)],     redS[0][c] + redS[1][c] + redS[2][c] + redS[3][c]);
    atomicAdd(&sums[2 * (n * 3 + c) + 1], redQ[0][c] + redQ[1][c] + redQ[2][c] + redQ[3][c]);
  }
}

// ---- LDS-tiled downsample conv: ratio<2.05, 32x8 tile, 1 px/thread ----
__global__ __launch_bounds__(256) void conv_dn_tiled(
    const float* __restrict__ in, float* __restrict__ ys, float* __restrict__ u2s,
    const float* __restrict__ w1, const float* __restrict__ b1,
    const float* __restrict__ w2, const float* __restrict__ b2,
    float* __restrict__ sums, int Hin, int S, int hc, int logr,
    int tilesX, int tilesY,
    const float* __restrict__ pys, const float* __restrict__ pu2,
    const float* __restrict__ psums,
    const float* __restrict__ pinp, const float* __restrict__ plnp,
    const float* __restrict__ pbnp, const float* __restrict__ pbnw,
    const float* __restrict__ pbnb, const float* __restrict__ pp1,
    const float* __restrict__ pp2, const float* __restrict__ pnoise,
    int pN, int Sp, int logrp) {
  const int TW = 32, TH = 8, IW = 68, IH = 20;
  __shared__ float lin[3 * IH * IW];
  int tpi = tilesX * tilesY;
  int n = blockIdx.x / tpi;
  int trem = blockIdx.x - n * tpi;
  int tyB = trem / tilesX, txB = trem - tyB * tilesX;
  int px0 = txB * TW, py0 = tyB * TH;
  int sy0 = (py0 * hc) >> logr, sx0 = (px0 * hc) >> logr;
  const float* inb = in + (size_t)n * 3 * Hin * Hin;
  FUSED_AB_PROLOGUE(n)
  for (int t = threadIdx.x; t < 3 * IH * IW; t += 256) {
    int cc = t / (IH * IW);
    int rem = t - cc * IH * IW;
    int rr = rem / IW, col = rem - rr * IW;
    int gy = sy0 + rr; gy = gy < Hin ? gy : Hin - 1;
    int gx = sx0 + col; gx = gx < Hin ? gx : Hin - 1;
    STAGE_VAL(n, cc, gy, gx, lin[t])
  }
  __syncthreads();
  int tx = threadIdx.x & 31, ty = threadIdx.x >> 5;
  int px = px0 + tx, py = py0 + ty;
  int sxl = ((px * hc) >> logr) - sx0;
  int syl = ((py * hc) >> logr) - sy0;
  float a1[3], a2[3];
  #pragma unroll
  for (int c = 0; c < 3; ++c) { a1[c] = b1[c]; a2[c] = b2[c]; }
  #pragma unroll 1
  for (int ci = 0; ci < 3; ++ci) {
    const float* lrow = lin + ci * IH * IW + syl * IW + sxl;
    const float* wp1 = w1 + ci * 25;
    const float* wp2 = w2 + ci * 25;
    #pragma unroll
    for (int ky = 0; ky < 5; ++ky) {
      float v[5];
      #pragma unroll
      for (int j = 0; j < 5; ++j) v[j] = lrow[ky * IW + j];
      #pragma unroll
      for (int c = 0; c < 3; ++c) {
        #pragma unroll
        for (int kx = 0; kx < 5; ++kx) {
          a1[c] = fmaf(v[kx], wp1[c * 75 + ky * 5 + kx], a1[c]);
          a2[c] = fmaf(v[kx], wp2[c * 75 + ky * 5 + kx], a2[c]);
        }
      }
    }
  }
  float sc[3] = {0.f, 0.f, 0.f}, sq[3] = {0.f, 0.f, 0.f};
  bool valid = (py < S) && (px < S);
  if (valid) {
    #pragma unroll
    for (int c = 0; c < 3; ++c) {
      size_t idx = ((size_t)(n * 3 + c) * S + py) * S + px;
      ys[idx] = a1[c];
      u2s[idx] = a2[c];
      sc[c] += a1[c];
      sq[c] += a1[c] * a1[c];
    }
  }
  #pragma unroll
  for (int off = 32; off; off >>= 1) {
    #pragma unroll
    for (int c = 0; c < 3; ++c) {
      sc[c] += __shfl_down(sc[c], off);
      sq[c] += __shfl_down(sq[c], off);
    }
  }
  __shared__ float redS[4][3], redQ[4][3];
  int wid = threadIdx.x >> 6, lane = threadIdx.x & 63;
  if (lane == 0) {
    #pragma unroll
    for (int c = 0; c < 3; ++c) { redS[wid][c] = sc[c]; redQ[wid][c] = sq[c]; }
  }
  __syncthreads();
  if (threadIdx.x < 3) {
    int c = threadIdx.x;
    atomicAdd(&sums[2 * (n * 3 + c)],     redS[0][c] + redS[1][c] + redS[2][c] + redS[3][c]);
    atomicAdd(&sums[2 * (n * 3 + c) + 1], redQ[0][c] + redQ[1][c] + redQ[2][c] + redQ[3][c]);
  }
}

// ---- elemD: inline finalize, gather upsample, affine+p2*u2 (+noise)(tanh), fused QKV ----
__global__ __launch_bounds__(256) void elemD_kernel(
    const float* __restrict__ ys, const float* __restrict__ u2s,
    const float* __restrict__ sums,
    const float* __restrict__ inp, const float* __restrict__ lnp,
    const float* __restrict__ bnp, const float* __restrict__ bnw,
    const float* __restrict__ bnb, const float* __restrict__ p1p,
    const float* __restrict__ p2p,
    const float* __restrict__ noise, float* __restrict__ out,
    float* __restrict__ qo, float* __restrict__ ko, float* __restrict__ vo,
    const float* __restrict__ qwp, const float* __restrict__ qbp,
    const float* __restrict__ kwp, const float* __restrict__ kbp,
    const float* __restrict__ vwp, const float* __restrict__ vbp,
    int N, int S, int hc, int r, int upsample, int do_tanh) {
  int hw = r * r;
  int bpi = hw >> 8;
  int n = blockIdx.x / bpi;
  int p = (blockIdx.x % bpi) * 256 + threadIdx.x;
  __shared__ float Ab[3], Bb[3];
  if (threadIdx.x < 3) {
    int c = threadIdx.x;
    float si_ = inp[0] + inp[1] + inp[2] + lnp[0] + lnp[1] + lnp[2];
    float sb = bnp[0] + bnp[1] + bnp[2];
    float inv = 1.0f / (float)hw;
    float s1 = sums[2 * (n * 3 + c)], s2 = sums[2 * (n * 3 + c) + 1];
    float mi = s1 * inv;
    float vi = s2 * inv - mi * mi;
    float ri = rsqrtf(vi + EPS);
    float bs = 0.f, bs2 = 0.f;
    for (int nn = 0; nn < N; ++nn) {
      bs += sums[2 * (nn * 3 + c)];
      bs2 += sums[2 * (nn * 3 + c) + 1];
    }
    float invb = 1.0f / ((float)N * (float)hw);
    float mb = bs * invb;
    float vbv = bs2 * invb - mb * mb;
    float rb = rsqrtf(vbv + EPS);
    float w = bnw[c];
    float A = 1.0f + si_ * ri + sb * rb * w;
    float B = -(si_ * ri * mi + sb * rb * w * mb) + sb * bnb[c];
    float p1 = p1p[0];
    Ab[c] = A * p1;
    Bb[c] = B * p1;
  }
  __syncthreads();
  int oy = p / r, ox = p - oy * r;
  int si = upsample ? ((oy * hc) / r) * S + (ox * hc) / r : p;
  float p2 = p2p[0];
  float v[3];
  #pragma unroll
  for (int c = 0; c < 3; ++c) {
    int ibase = (n * 3 + c) * S * S + si;
    float val = Ab[c] * ys[ibase] + Bb[c] + p2 * u2s[ibase];
    if (noise) val += noise[c * hw + p];
    if (do_tanh) val = tanhf(val);
    v[c] = val;
    out[(n * 3 + c) * hw + p] = val;
  }
  if (qo) {
    int b3 = n * 3;
    #pragma unroll
    for (int o = 0; o < 3; ++o) {
      float qv = qbp[o], kv = kbp[o], vv = vbp[o];
      #pragma unroll
      for (int c = 0; c < 3; ++c) {
        qv = fmaf(qwp[o * 3 + c], v[c], qv);
        kv = fmaf(kwp[o * 3 + c], v[c], kv);
        vv = fmaf(vwp[o * 3 + c], v[c], vv);
      }
      qo[(b3 + o) * hw + p] = qv;
      ko[(b3 + o) * hw + p] = kv * LOG2E;
      vo[(b3 + o) * hw + p] = vv;
    }
  }
}

// ---- attention pass 1 (HW=1024, 4-way n-partitioned) ----
__global__ __launch_bounds__(256) void attn_rows_kernel(
    const float* __restrict__ qg, const float* __restrict__ kg,
    float* __restrict__ Mp, float* __restrict__ Lp, int HW, int mchunks) {
  int plen = HW >> 2;
  __shared__ float qs[768];
  int bid = blockIdx.x;
  int np = bid & 3; bid >>= 2;
  int mc = bid % mchunks;
  int b = bid / mchunks;
  const float* qb_ = qg + (size_t)b * 3 * HW + np * plen;
  for (int t = threadIdx.x; t < 3 * plen; t += 256) {
    int c = t / plen, j = t - c * plen;
    qs[t] = qb_[c * HW + j];
  }
  __syncthreads();
  int m = mc * 256 + threadIdx.x;
  const float* kb_ = kg + (size_t)b * 3 * HW;
  float kx = kb_[m], ky = kb_[HW + m], kz = kb_[2 * HW + m];
  float mr = -1e30f;
  for (int j = 0; j < plen; ++j) {
    float s = kx * qs[j] + ky * qs[plen + j] + kz * qs[2 * plen + j];
    mr = fmaxf(mr, s);
  }
  float l = 0.f;
  for (int j = 0; j < plen; ++j) {
    float s = kx * qs[j] + ky * qs[plen + j] + kz * qs[2 * plen + j];
    l += exp2f(s - mr);
  }
  int idx = (b * 4 + np) * HW + m;
  Mp[idx] = mr;
  Lp[idx] = l;
}

// ---- attention pass 2 (HW=1024, 4-way m-partitioned) ----
__global__ __launch_bounds__(256) void attn_out_kernel(
    const float* __restrict__ qg, const float* __restrict__ kg,
    const float* __restrict__ vg,
    const float* __restrict__ Mp, const float* __restrict__ Lp,
    const float* __restrict__ y2, float* __restrict__ aout, int HW, int nchunks) {
  int plen = HW >> 2;
  __shared__ float ks[768], vs[768], Ms[256], Ls[256];
  int bid = blockIdx.x;
  int mp = bid & 3; bid >>= 2;
  int nc = bid % nchunks;
  int b = bid / nchunks;
  int m0 = mp * plen;
  const float* kb_ = kg + (size_t)b * 3 * HW + m0;
  const float* vb_ = vg + (size_t)b * 3 * HW + m0;
  for (int t = threadIdx.x; t < 3 * plen; t += 256) {
    int c = t / plen, j = t - c * plen;
    ks[t] = kb_[c * HW + j];
    vs[t] = vb_[c * HW + j];
  }
  for (int t = threadIdx.x; t < plen; t += 256) {
    int m = m0 + t;
    float M0 = Mp[(b * 4 + 0) * HW + m], M1 = Mp[(b * 4 + 1) * HW + m];
    float M2 = Mp[(b * 4 + 2) * HW + m], M3 = Mp[(b * 4 + 3) * HW + m];
    float L0 = Lp[(b * 4 + 0) * HW + m], L1 = Lp[(b * 4 + 1) * HW + m];
    float L2 = Lp[(b * 4 + 2) * HW + m], L3 = Lp[(b * 4 + 3) * HW + m];
    float MM = fmaxf(fmaxf(M0, M1), fmaxf(M2, M3));
    float LL = L0 * exp2f(M0 - MM) + L1 * exp2f(M1 - MM) +
               L2 * exp2f(M2 - MM) + L3 * exp2f(M3 - MM);
    Ms[t] = MM;
    Ls[t] = 1.0f / LL;
  }
  __syncthreads();
  int nn = nc * 256 + threadIdx.x;
  const float* qb_ = qg + (size_t)b * 3 * HW;
  float q0 = qb_[nn], q1 = qb_[HW + nn], q2 = qb_[2 * HW + nn];
  float a0 = 0.f, a1 = 0.f, a2 = 0.f;
  for (int j = 0; j < plen; ++j) {
    float s = ks[j] * q0 + ks[plen + j] * q1 + ks[2 * plen + j] * q2;
    float w = exp2f(s - Ms[j]) * Ls[j];
    a0 = fmaf(vs[j], w, a0);
    a1 = fmaf(vs[plen + j], w, a1);
    a2 = fmaf(vs[2 * plen + j], w, a2);
  }
  size_t o0 = (size_t)b * 3 * HW + nn;
  if (mp == 0) { a0 += y2[o0]; a1 += y2[o0 + HW]; a2 += y2[o0 + 2 * HW]; }
  atomicAdd(&aout[o0], a0);
  atomicAdd(&aout[o0 + HW], a1);
  atomicAdd(&aout[o0 + 2 * HW], a2);
}

// ---- fused attention for HW=256 ----
__global__ __launch_bounds__(256) void attn256_kernel(
    const float* __restrict__ qg, const float* __restrict__ kg,
    const float* __restrict__ vg, const float* __restrict__ y2,
    float* __restrict__ aout) {
  __shared__ float qs[768], ks[768], vs[768], Ms[256], Ls[256];
  int b = blockIdx.x;
  size_t base = (size_t)b * 768;
  for (int t = threadIdx.x; t < 768; t += 256) {
    qs[t] = qg[base + t];
    ks[t] = kg[base + t];
    vs[t] = vg[base + t];
  }
  __syncthreads();
  {
    int m = threadIdx.x;
    float kx = ks[m], ky = ks[256 + m], kz = ks[512 + m];
    float mr = -1e30f;
    for (int j = 0; j < 256; ++j) {
      float s = kx * qs[j] + ky * qs[256 + j] + kz * qs[512 + j];
      mr = fmaxf(mr, s);
    }
    float l = 0.f;
    for (int j = 0; j < 256; ++j) {
      float s = kx * qs[j] + ky * qs[256 + j] + kz * qs[512 + j];
      l += exp2f(s - mr);
    }
    Ms[m] = mr;
    Ls[m] = 1.0f / l;
  }
  __syncthreads();
  int nn = threadIdx.x;
  float q0 = qs[nn], q1 = qs[256 + nn], q2 = qs[512 + nn];
  float a0 = 0.f, a1 = 0.f, a2 = 0.f;
  for (int j = 0; j < 256; ++j) {
    float s = ks[j] * q0 + ks[256 + j] * q1 + ks[512 + j] * q2;
    float w = exp2f(s - Ms[j]) * Ls[j];
    a0 = fmaf(vs[j], w, a0);
    a1 = fmaf(vs[256 + j], w, a1);
    a2 = fmaf(vs[512 + j], w, a2);
  }
  aout[base + nn]       = a0 + y2[base + nn];
  aout[base + 256 + nn] = a1 + y2[base + 256 + nn];
  aout[base + 512 + nn] = a2 + y2[base + 512 + nn];
}

#define NOPREV nullptr, nullptr, nullptr, nullptr, nullptr, nullptr, nullptr, \
               nullptr, nullptr, nullptr, nullptr, 0, 0, 0

extern "C" void kernel_launch(void* const* d_in, const int* in_sizes, int n_in,
                              void* d_out, int out_size, void* d_ws, size_t ws_size,
                              hipStream_t stream) {
  const float* x       = (const float*)d_in[0];
  const float* noise_z = (const float*)d_in[1];
  const float* lin_w   = (const float*)d_in[2];
  const float* lin_b   = (const float*)d_in[3];
  const float* conv_w  = (const float*)d_in[4];
  const float* conv_b  = (const float*)d_in[5];
  const float* conv2_w = (const float*)d_in[6];
  const float* conv2_b = (const float*)d_in[7];
  const float* q_w     = (const float*)d_in[8];
  const float* q_b     = (const float*)d_in[9];
  const float* k_w     = (const float*)d_in[10];
  const float* k_b     = (const float*)d_in[11];
  const float* v_w     = (const float*)d_in[12];
  const float* v_b     = (const float*)d_in[13];
  const float* in_p    = (const float*)d_in[14];
  const float* ln_p    = (const float*)d_in[15];
  const float* bn_p    = (const float*)d_in[16];
  const float* bn_w    = (const float*)d_in[17];
  const float* bn_b    = (const float*)d_in[18];
  const float* p1      = (const float*)d_in[19];
  const float* p2      = (const float*)d_in[20];
  float* out = (float*)d_out;

  float* ws = (float*)d_ws;
  size_t off = 0;
  auto alloc = [&](size_t nf) { float* p = ws + off; off += nf; return p; };
  float* YS2  = alloc(6096384);   // 252^2 * 96
  float* U2S2 = alloc(6096384);
  float* PAy  = alloc(1572864);   // up to 128^2 * 96
  float* PAu  = alloc(1572864);
  float* PBy  = alloc(1572864);
  float* PBu  = alloc(1572864);
  float* SUMS = alloc(2304);      // 12 * 192 (zeroed)
  float* A5   = alloc(98304);     // attn out, atomics (zeroed)
  float* A8   = alloc(98304);     // attn out, atomics (zeroed)
  float* A6   = alloc(24576);
  float* A7   = alloc(24576);
  float* Y5   = alloc(98304);
  float* Y6   = alloc(24576);
  float* Y7   = alloc(24576);
  float* Y8   = alloc(98304);
  float* Qb   = alloc(98304);
  float* Kb   = alloc(98304);
  float* Vb   = alloc(98304);
  float* Mp   = alloc(131072);
  float* Lp   = alloc(131072);
  float* NB0  = alloc(12288);
  float* LIN  = alloc(768);
  float* NYS0 = alloc(512);
  float* NU20 = alloc(512);
  float* NYS1 = alloc(2560);
  float* NU21 = alloc(2560);

  hipMemsetAsync(SUMS, 0, (2304 + 98304 + 98304) * sizeof(float), stream);

  const float* nul = nullptr;

  // ---- noise path ----
  linear_kernel<<<3, 256, 0, stream>>>(noise_z, lin_w, lin_b, LIN);
  conv_src_kernel<2><<<1, 256, 0, stream>>>(LIN, NYS0, NU20, conv_w, conv_b,
      conv2_w, conv2_b, SUMS, 1, 16, 12, 12, 32, 1, 1);
  // block1 conv fused with elemD(block0): Hin=32, S=28, r=64
  conv_up_tiled<<<2, 256, 0, stream>>>(NYS0, NYS1, NU21, conv_w + 225,
      conv_b + 3, conv2_w + 225, conv2_b + 3, SUMS + 192, 32, 28, 64, 1, 2,
      NYS0, NU20, SUMS, in_p, ln_p, bn_p, bn_w, bn_b, p1, p2, nul, 1, 12, 5);
  // materialize noise activation NB0 (1,3,64,64)
  elemD_kernel<<<16, 256, 0, stream>>>(NYS1, NU21, SUMS + 192, in_p + 3,
      ln_p + 3, bn_p + 3, bn_w + 3, bn_b + 3, p1 + 1, p2 + 1, nul, NB0,
      nullptr, nullptr, nullptr, nul, nul, nul, nul, nul, nul, 1, 28, 28, 64, 1, 0);

  // ---- main path ----
  // conv2: direct from x
  conv_up_tiled<<<2048, 256, 0, stream>>>(x, YS2, U2S2, conv_w + 450,
      conv_b + 6, conv2_w + 450, conv2_b + 6, SUMS + 384, 256, 252, 256, 4, 16,
      NOPREV);
  // conv3: fused elemD(b2): prev up Sp=252, logrp=8
  conv_dn_tiled<<<2048, 256, 0, stream>>>(YS2, PAy, PAu, conv_w + 675,
      conv_b + 9, conv2_w + 675, conv2_b + 9, SUMS + 576, 256, 128, 252, 7, 4, 16,
      YS2, U2S2, SUMS + 384, in_p + 6, ln_p + 6, bn_p + 6, bn_w + 6, bn_b + 6,
      p1 + 2, p2 + 2, nul, 32, 252, 8);
  // conv4: fused elemD(b3): prev identity Sp=128
  conv_dn_tiled<<<512, 256, 0, stream>>>(PAy, PBy, PBu, conv_w + 900,
      conv_b + 12, conv2_w + 900, conv2_b + 12, SUMS + 768, 128, 64, 124, 6, 2, 8,
      PAy, PAu, SUMS + 576, in_p + 9, ln_p + 9, bn_p + 9, bn_w + 9, bn_b + 9,
      p1 + 3, p2 + 3, nul, 32, 128, -1);
  // conv5: fused elemD(b4)+noise: prev identity Sp=64
  conv_dn_tiled<<<128, 256, 0, stream>>>(PBy, PAy, PAu, conv_w + 1125,
      conv_b + 15, conv2_w + 1125, conv2_b + 15, SUMS + 960, 64, 32, 60, 5, 1, 4,
      PBy, PBu, SUMS + 768, in_p + 12, ln_p + 12, bn_p + 12, bn_w + 12, bn_b + 12,
      p1 + 4, p2 + 4, NB0, 32, 64, -1);
  // elemD5 + QKV -> Y5, attn1024 -> A5
  elemD_kernel<<<128, 256, 0, stream>>>(PAy, PAu, SUMS + 960, in_p + 15,
      ln_p + 15, bn_p + 15, bn_w + 15, bn_b + 15, p1 + 5, p2 + 5, nul, Y5,
      Qb, Kb, Vb, q_w + 45, q_b + 15, k_w + 45, k_b + 15, v_w + 45, v_b + 15,
      32, 32, 28, 32, 0, 0);
  attn_rows_kernel<<<512, 256, 0, stream>>>(Qb, Kb, Mp, Lp, 1024, 4);
  attn_out_kernel<<<512, 256, 0, stream>>>(Qb, Kb, Vb, Mp, Lp, Y5, A5, 1024, 4);
  // conv6: direct from A5
  conv_dn_tiled<<<64, 256, 0, stream>>>(A5, PBy, PBu, conv_w + 1350,
      conv_b + 18, conv2_w + 1350, conv2_b + 18, SUMS + 1152, 32, 16, 28, 4, 1, 2,
      NOPREV);
  elemD_kernel<<<32, 256, 0, stream>>>(PBy, PBu, SUMS + 1152, in_p + 18,
      ln_p + 18, bn_p + 18, bn_w + 18, bn_b + 18, p1 + 6, p2 + 6, nul, Y6,
      Qb, Kb, Vb, q_w + 54, q_b + 18, k_w + 54, k_b + 18, v_w + 54, v_b + 18,
      32, 16, 12, 16, 0, 0);
  attn256_kernel<<<32, 256, 0, stream>>>(Qb, Kb, Vb, Y6, A6);
  // conv7: direct from A6 (small upsample S=12)
  conv_src_kernel<2><<<32, 256, 0, stream>>>(A6, PAy, PAu, conv_w + 1575,
      conv_b + 21, conv2_w + 1575, conv2_b + 21, SUMS + 1344, 32, 16, 12, 12, 16, 1, 1);
  elemD_kernel<<<32, 256, 0, stream>>>(PAy, PAu, SUMS + 1344, in_p + 21,
      ln_p + 21, bn_p + 21, bn_w + 21, bn_b + 21, p1 + 7, p2 + 7, nul, Y7,
      Qb, Kb, Vb, q_w + 63, q_b + 21, k_w + 63, k_b + 21, v_w + 63, v_b + 21,
      32, 12, 12, 16, 1, 0);
  attn256_kernel<<<32, 256, 0, stream>>>(Qb, Kb, Vb, Y7, A7);
  // conv8: direct from A7
  conv_src_kernel<2><<<32, 256, 0, stream>>>(A7, PBy, PBu, conv_w + 1800,
      conv_b + 24, conv2_w + 1800, conv2_b + 24, SUMS + 1536, 32, 16, 12, 12, 32, 1, 1);
  elemD_kernel<<<128, 256, 0, stream>>>(PBy, PBu, SUMS + 1536, in_p + 24,
      ln_p + 24, bn_p + 24, bn_w + 24, bn_b + 24, p1 + 8, p2 + 8, nul, Y8,
      Qb, Kb, Vb, q_w + 72, q_b + 24, k_w + 72, k_b + 24, v_w + 72, v_b + 24,
      32, 12, 12, 32, 1, 0);
  attn_rows_kernel<<<512, 256, 0, stream>>>(Qb, Kb, Mp, Lp, 1024, 4);
  attn_out_kernel<<<512, 256, 0, stream>>>(Qb, Kb, Vb, Mp, Lp, Y8, A8, 1024, 4);
  // conv9: direct from A8: Hin=32, S=28, r=64
  conv_up_tiled<<<64, 256, 0, stream>>>(A8, PAy, PAu, conv_w + 2025,
      conv_b + 27, conv2_w + 2025, conv2_b + 27, SUMS + 1728, 32, 28, 64, 1, 2,
      NOPREV);
  // conv10: fused elemD(b9): prev up Sp=28, logrp=6; Hin=64, S=60, r=128
  conv_up_tiled<<<128, 256, 0, stream>>>(PAy, PBy, PBu, conv_w + 2250,
      conv_b + 30, conv2_w + 2250, conv2_b + 30, SUMS + 1920, 64, 60, 128, 1, 4,
      PAy, PAu, SUMS + 1728, in_p + 27, ln_p + 27, bn_p + 27, bn_w + 27,
      bn_b + 27, p1 + 9, p2 + 9, nul, 32, 28, 6);
  // conv11: fused elemD(b10): prev up Sp=60, logrp=7; Hin=128, S=124, r=256
  conv_up_tiled<<<512, 256, 0, stream>>>(PBy, YS2, U2S2, conv_w + 2475,
      conv_b + 33, conv2_w + 2475, conv2_b + 33, SUMS + 2112, 128, 124, 256, 2, 8,
      PBy, PBu, SUMS + 1920, in_p + 30, ln_p + 30, bn_p + 30, bn_w + 30,
      bn_b + 30, p1 + 10, p2 + 10, nul, 32, 60, 7);
  // final elemD: tanh -> out
  elemD_kernel<<<8192, 256, 0, stream>>>(YS2, U2S2, SUMS + 2112, in_p + 33,
      ln_p + 33, bn_p + 33, bn_w + 33, bn_b + 33, p1 + 11, p2 + 11, nul, out,
      nullptr, nullptr, nullptr, nul, nul, nul, nul, nul, nul,
      32, 124, 124, 256, 1, 1);
}

// Round 6
// 594.484 us; speedup vs baseline: 1.4838x; 1.0053x over previous
//
#include <hip/hip_runtime.h>
#include <math.h>

#define EPS 1e-5f
#define LOG2E 1.44269504088896340736f

// ---- shared affine-fold helper: A,B from sums (instance+batch norm + p1) ----
__device__ __forceinline__ float2 ab_from(float s1, float s2, float bs, float bs2,
    float hw, float Nf, float si_, float sb, float bnw_c, float bnb_c, float p1v) {
  float inv = 1.0f / hw;
  float mi = s1 * inv, vi = s2 * inv - mi * mi;
  float ri = rsqrtf(vi + EPS);
  float invb = 1.0f / (Nf * hw);
  float mb = bs * invb, vb = bs2 * invb - mb * mb;
  float rb = rsqrtf(vb + EPS);
  float A = 1.0f + si_ * ri + sb * rb * bnw_c;
  float B = -(si_ * ri * mi + sb * rb * bnw_c * mb) + sb * bnb_c;
  return make_float2(A * p1v, B * p1v);
}

__device__ __forceinline__ void compute_AB(
    const float* __restrict__ sums, int n, int N, float hw,
    const float* __restrict__ inp, const float* __restrict__ lnp,
    const float* __restrict__ bnp, const float* __restrict__ bnw,
    const float* __restrict__ bnb, const float* __restrict__ p1p,
    const float* __restrict__ p2p, float* pA, float* pB, float* pP2) {
  if (threadIdx.x == 0) *pP2 = p2p[0];
  if (threadIdx.x < 3) {
    int c = threadIdx.x;
    float si_ = inp[0] + inp[1] + inp[2] + lnp[0] + lnp[1] + lnp[2];
    float sb = bnp[0] + bnp[1] + bnp[2];
    float s1 = sums[2 * (n * 3 + c)], s2 = sums[2 * (n * 3 + c) + 1];
    float bs = 0.f, bs2 = 0.f;
    for (int nn = 0; nn < N; ++nn) {
      bs += sums[2 * (nn * 3 + c)];
      bs2 += sums[2 * (nn * 3 + c) + 1];
    }
    float2 ab = ab_from(s1, s2, bs, bs2, hw, (float)N, si_, sb, bnw[c], bnb[c], p1p[0]);
    pA[c] = ab.x;
    pB[c] = ab.y;
  }
  __syncthreads();
}

// stats block-reduce (all threads must participate)
#define STATS_REDUCE_ATOMIC(scv, sqv, sumsp, nvar)                            \
  {                                                                           \
    _Pragma("unroll")                                                         \
    for (int off = 32; off; off >>= 1) {                                      \
      _Pragma("unroll")                                                       \
      for (int c = 0; c < 3; ++c) {                                           \
        scv[c] += __shfl_down(scv[c], off);                                   \
        sqv[c] += __shfl_down(sqv[c], off);                                   \
      }                                                                       \
    }                                                                         \
    __shared__ float redS[4][3], redQ[4][3];                                  \
    int wid = threadIdx.x >> 6, lane = threadIdx.x & 63;                      \
    if (lane == 0) {                                                          \
      _Pragma("unroll")                                                       \
      for (int c = 0; c < 3; ++c) { redS[wid][c] = scv[c]; redQ[wid][c] = sqv[c]; } \
    }                                                                         \
    __syncthreads();                                                          \
    if (threadIdx.x < 3) {                                                    \
      int c = threadIdx.x;                                                    \
      atomicAdd(&sumsp[2 * ((nvar) * 3 + c)],                                 \
                redS[0][c] + redS[1][c] + redS[2][c] + redS[3][c]);           \
      atomicAdd(&sumsp[2 * ((nvar) * 3 + c) + 1],                             \
                redQ[0][c] + redQ[1][c] + redQ[2][c] + redQ[3][c]);           \
    }                                                                         \
  }

// ---- LDS-tiled upsample conv (S==hc): 64x16 tile, TX=4, float2 out ----
template <bool FUSED>
__global__ __launch_bounds__(256) void conv_up_t(
    const float* __restrict__ in, const float2* __restrict__ pyu,
    float2* __restrict__ yu,
    const float* __restrict__ w1, const float* __restrict__ b1,
    const float* __restrict__ w2, const float* __restrict__ b2,
    float* __restrict__ sums, int Hin, int S, int r, int tilesX, int tilesY,
    const float* __restrict__ psums,
    const float* __restrict__ pinp, const float* __restrict__ plnp,
    const float* __restrict__ pbnp, const float* __restrict__ pbnw,
    const float* __restrict__ pbnb, const float* __restrict__ pp1,
    const float* __restrict__ pp2, const float* __restrict__ pnoise,
    int pN, int Sp, int logrp) {
  const int TW = 64, TH = 16, IW = 68, IH = 20;
  __shared__ float lin[3 * IH * IW];
  __shared__ float pA[3], pB[3], pP2v;
  int tpi = tilesX * tilesY;
  int n = blockIdx.x / tpi;
  int trem = blockIdx.x - n * tpi;
  int tyB = trem / tilesX, txB = trem - tyB * tilesX;
  int px0 = txB * TW, py0 = tyB * TH;
  const float* inb = in + (size_t)n * 3 * Hin * Hin;
  if (FUSED) {
    compute_AB(psums, n, pN, (float)(Hin * Hin), pinp, plnp, pbnp, pbnw, pbnb,
               pp1, pp2, pA, pB, &pP2v);
    size_t pbase = (size_t)n * 3 * Sp * Sp;
    for (int t = threadIdx.x; t < 3 * IH * IW; t += 256) {
      int cc = t / (IH * IW);
      int rem = t - cc * IH * IW;
      int rr = rem / IW, col = rem - rr * IW;
      int gy = py0 + rr; gy = gy < Hin ? gy : Hin - 1;
      int gx = px0 + col; gx = gx < Hin ? gx : Hin - 1;
      int si = ((gy * Sp) >> logrp) * Sp + ((gx * Sp) >> logrp);
      float2 v = pyu[pbase + cc * Sp * Sp + si];
      float val = pA[cc] * v.x + pB[cc] + pP2v * v.y;
      if (pnoise) val += pnoise[((size_t)cc * Hin + gy) * Hin + gx];
      lin[t] = val;
    }
  } else {
    if (px0 + IW <= Hin && py0 + IH <= Hin) {
      for (int t = threadIdx.x; t < 3 * IH * 17; t += 256) {
        int cc = t / (IH * 17);
        int rem = t - cc * (IH * 17);
        int rr = rem / 17, j = rem - rr * 17;
        float4 v = *reinterpret_cast<const float4*>(
            inb + ((size_t)cc * Hin + py0 + rr) * Hin + px0 + 4 * j);
        *reinterpret_cast<float4*>(&lin[(cc * IH + rr) * IW + 4 * j]) = v;
      }
    } else {
      for (int t = threadIdx.x; t < 3 * IH * IW; t += 256) {
        int cc = t / (IH * IW);
        int rem = t - cc * IH * IW;
        int rr = rem / IW, col = rem - rr * IW;
        int gy = py0 + rr; gy = gy < Hin ? gy : Hin - 1;
        int gx = px0 + col; gx = gx < Hin ? gx : Hin - 1;
        lin[t] = inb[((size_t)cc * Hin + gy) * Hin + gx];
      }
    }
  }
  __syncthreads();
  int tx = threadIdx.x & 15, ty = threadIdx.x >> 4;
  int lx0 = tx * 4;
  int px = px0 + lx0, py = py0 + ty;
  float a1[3][4], a2[3][4];
  #pragma unroll
  for (int c = 0; c < 3; ++c) {
    float bb1 = b1[c], bb2 = b2[c];
    #pragma unroll
    for (int x = 0; x < 4; ++x) { a1[c][x] = bb1; a2[c][x] = bb2; }
  }
  #pragma unroll 1
  for (int ci = 0; ci < 3; ++ci) {
    const float* lrow = lin + ci * IH * IW + ty * IW + lx0;
    const float* wp1 = w1 + ci * 25;
    const float* wp2 = w2 + ci * 25;
    #pragma unroll
    for (int ky = 0; ky < 5; ++ky) {
      float v[8];
      #pragma unroll
      for (int j = 0; j < 8; ++j) v[j] = lrow[ky * IW + j];
      #pragma unroll
      for (int c = 0; c < 3; ++c) {
        #pragma unroll
        for (int kx = 0; kx < 5; ++kx) {
          float wa = wp1[c * 75 + ky * 5 + kx];
          float wb = wp2[c * 75 + ky * 5 + kx];
          #pragma unroll
          for (int x = 0; x < 4; ++x) {
            a1[c][x] = fmaf(v[kx + x], wa, a1[c][x]);
            a2[c][x] = fmaf(v[kx + x], wb, a2[c][x]);
          }
        }
      }
    }
  }
  float sc[3] = {0.f, 0.f, 0.f}, sq[3] = {0.f, 0.f, 0.f};
  bool valid = (py < S) && (px < S);
  if (valid) {
    int hc = S;
    float wy = (float)(((py + 1) * r + hc - 1) / hc - (py * r + hc - 1) / hc);
    float wx[4];
    #pragma unroll
    for (int x = 0; x < 4; ++x) {
      int pxx = px + x;
      wx[x] = (float)(((pxx + 1) * r + hc - 1) / hc - (pxx * r + hc - 1) / hc);
    }
    #pragma unroll
    for (int c = 0; c < 3; ++c) {
      size_t idx = ((size_t)(n * 3 + c) * S + py) * S + px;
      float2* yp = yu + idx;
      *reinterpret_cast<float4*>(yp) =
          make_float4(a1[c][0], a2[c][0], a1[c][1], a2[c][1]);
      *reinterpret_cast<float4*>(yp + 2) =
          make_float4(a1[c][2], a2[c][2], a1[c][3], a2[c][3]);
      #pragma unroll
      for (int x = 0; x < 4; ++x) {
        float wgt = wy * wx[x];
        sc[c] += a1[c][x] * wgt;
        sq[c] += a1[c][x] * a1[c][x] * wgt;
      }
    }
  }
  STATS_REDUCE_ATOMIC(sc, sq, sums, n)
}

// ---- LDS-tiled downsample conv (ratio<2.05): 32x8 tile, float2 out ----
template <bool FUSED>
__global__ __launch_bounds__(256) void conv_dn_t(
    const float* __restrict__ in, const float2* __restrict__ pyu,
    float2* __restrict__ yu,
    const float* __restrict__ w1, const float* __restrict__ b1,
    const float* __restrict__ w2, const float* __restrict__ b2,
    float* __restrict__ sums, int Hin, int S, int hc, int logr,
    int tilesX, int tilesY,
    const float* __restrict__ psums,
    const float* __restrict__ pinp, const float* __restrict__ plnp,
    const float* __restrict__ pbnp, const float* __restrict__ pbnw,
    const float* __restrict__ pbnb, const float* __restrict__ pp1,
    const float* __restrict__ pp2, const float* __restrict__ pnoise,
    int pN, int Sp, int logrp) {
  const int TW = 32, TH = 8, IW = 68, IH = 20;
  __shared__ float lin[3 * IH * IW];
  __shared__ float pA[3], pB[3], pP2v;
  int tpi = tilesX * tilesY;
  int n = blockIdx.x / tpi;
  int trem = blockIdx.x - n * tpi;
  int tyB = trem / tilesX, txB = trem - tyB * tilesX;
  int px0 = txB * TW, py0 = tyB * TH;
  int sy0 = (py0 * hc) >> logr, sx0 = (px0 * hc) >> logr;
  const float* inb = in + (size_t)n * 3 * Hin * Hin;
  if (FUSED) {
    compute_AB(psums, n, pN, (float)(Hin * Hin), pinp, plnp, pbnp, pbnw, pbnb,
               pp1, pp2, pA, pB, &pP2v);
    size_t pbase = (size_t)n * 3 * Sp * Sp;
    for (int t = threadIdx.x; t < 3 * IH * IW; t += 256) {
      int cc = t / (IH * IW);
      int rem = t - cc * IH * IW;
      int rr = rem / IW, col = rem - rr * IW;
      int gy = sy0 + rr; gy = gy < Hin ? gy : Hin - 1;
      int gx = sx0 + col; gx = gx < Hin ? gx : Hin - 1;
      int si = ((gy * Sp) >> logrp) * Sp + ((gx * Sp) >> logrp);
      float2 v = pyu[pbase + cc * Sp * Sp + si];
      float val = pA[cc] * v.x + pB[cc] + pP2v * v.y;
      if (pnoise) val += pnoise[((size_t)cc * Hin + gy) * Hin + gx];
      lin[t] = val;
    }
  } else {
    for (int t = threadIdx.x; t < 3 * IH * IW; t += 256) {
      int cc = t / (IH * IW);
      int rem = t - cc * IH * IW;
      int rr = rem / IW, col = rem - rr * IW;
      int gy = sy0 + rr; gy = gy < Hin ? gy : Hin - 1;
      int gx = sx0 + col; gx = gx < Hin ? gx : Hin - 1;
      lin[t] = inb[((size_t)cc * Hin + gy) * Hin + gx];
    }
  }
  __syncthreads();
  int tx = threadIdx.x & 31, ty = threadIdx.x >> 5;
  int px = px0 + tx, py = py0 + ty;
  int sxl = ((px * hc) >> logr) - sx0;
  int syl = ((py * hc) >> logr) - sy0;
  float a1[3], a2[3];
  #pragma unroll
  for (int c = 0; c < 3; ++c) { a1[c] = b1[c]; a2[c] = b2[c]; }
  #pragma unroll 1
  for (int ci = 0; ci < 3; ++ci) {
    const float* lrow = lin + ci * IH * IW + syl * IW + sxl;
    const float* wp1 = w1 + ci * 25;
    const float* wp2 = w2 + ci * 25;
    #pragma unroll
    for (int ky = 0; ky < 5; ++ky) {
      float v[5];
      #pragma unroll
      for (int j = 0; j < 5; ++j) v[j] = lrow[ky * IW + j];
      #pragma unroll
      for (int c = 0; c < 3; ++c) {
        #pragma unroll
        for (int kx = 0; kx < 5; ++kx) {
          a1[c] = fmaf(v[kx], wp1[c * 75 + ky * 5 + kx], a1[c]);
          a2[c] = fmaf(v[kx], wp2[c * 75 + ky * 5 + kx], a2[c]);
        }
      }
    }
  }
  float sc[3] = {0.f, 0.f, 0.f}, sq[3] = {0.f, 0.f, 0.f};
  bool valid = (py < S) && (px < S);
  if (valid) {
    #pragma unroll
    for (int c = 0; c < 3; ++c) {
      size_t idx = ((size_t)(n * 3 + c) * S + py) * S + px;
      yu[idx] = make_float2(a1[c], a2[c]);
      sc[c] += a1[c];
      sq[c] += a1[c] * a1[c];
    }
  }
  STATS_REDUCE_ATOMIC(sc, sq, sums, n)
}

// ---- tiny-source upsample conv (S<=12), direct input, float2 out ----
__global__ __launch_bounds__(256) void conv_src_f2(
    const float* __restrict__ in, float2* __restrict__ yu,
    const float* __restrict__ w1, const float* __restrict__ b1,
    const float* __restrict__ w2, const float* __restrict__ b2,
    float* __restrict__ sums, int N, int Hin, int S, int hc, int r) {
  int n = blockIdx.x;
  int t = threadIdx.x;
  int SX = S / 2;
  int py = t / SX;
  int px0 = (t - py * SX) * 2;
  bool valid = (py < S);
  float a1[3][2], a2[3][2];
  #pragma unroll
  for (int c = 0; c < 3; ++c) {
    float bb1 = b1[c], bb2 = b2[c];
    a1[c][0] = bb1; a1[c][1] = bb1; a2[c][0] = bb2; a2[c][1] = bb2;
  }
  float sc[3] = {0.f, 0.f, 0.f}, sq[3] = {0.f, 0.f, 0.f};
  if (valid) {
    const float* ip0 = in + ((size_t)(n * 3) * Hin + py) * Hin + px0;
    #pragma unroll
    for (int ci = 0; ci < 3; ++ci) {
      const float* ip = ip0 + (size_t)ci * Hin * Hin;
      #pragma unroll
      for (int ky = 0; ky < 5; ++ky) {
        const float* row = ip + ky * Hin;
        float v[6];
        #pragma unroll
        for (int kx = 0; kx < 6; ++kx) v[kx] = row[kx];
        #pragma unroll
        for (int c = 0; c < 3; ++c) {
          const float* wp1 = w1 + c * 75 + ci * 25 + ky * 5;
          const float* wp2 = w2 + c * 75 + ci * 25 + ky * 5;
          #pragma unroll
          for (int kx = 0; kx < 5; ++kx) {
            float wv1 = wp1[kx], wv2 = wp2[kx];
            a1[c][0] = fmaf(v[kx], wv1, a1[c][0]);
            a1[c][1] = fmaf(v[kx + 1], wv1, a1[c][1]);
            a2[c][0] = fmaf(v[kx], wv2, a2[c][0]);
            a2[c][1] = fmaf(v[kx + 1], wv2, a2[c][1]);
          }
        }
      }
    }
    float wy = (float)(((py + 1) * r + hc - 1) / hc - (py * r + hc - 1) / hc);
    float wx0 = (float)(((px0 + 1) * r + hc - 1) / hc - (px0 * r + hc - 1) / hc);
    float wx1 = (float)(((px0 + 2) * r + hc - 1) / hc - ((px0 + 1) * r + hc - 1) / hc);
    int base = (n * 3) * S * S + py * S + px0;
    #pragma unroll
    for (int c = 0; c < 3; ++c) {
      yu[base + c * S * S] = make_float2(a1[c][0], a2[c][0]);
      yu[base + c * S * S + 1] = make_float2(a1[c][1], a2[c][1]);
      sc[c] += a1[c][0] * wy * wx0 + a1[c][1] * wy * wx1;
      sq[c] += a1[c][0] * a1[c][0] * wy * wx0 + a1[c][1] * a1[c][1] * wy * wx1;
    }
  }
  STATS_REDUCE_ATOMIC(sc, sq, sums, n)
}

// ---- whole noise path in one block ----
__global__ __launch_bounds__(256) void noise_all(
    const float* __restrict__ z, const float* __restrict__ lw,
    const float* __restrict__ lb,
    const float* __restrict__ cw, const float* __restrict__ cb,
    const float* __restrict__ c2w, const float* __restrict__ c2b,
    const float* __restrict__ inp, const float* __restrict__ lnp,
    const float* __restrict__ bnp, const float* __restrict__ bnw,
    const float* __restrict__ bnb, const float* __restrict__ p1p,
    const float* __restrict__ p2p, float* __restrict__ nb0) {
  __shared__ float zL[512];
  __shared__ float L0[768];
  __shared__ float ys0[432], u20[432];
  __shared__ float buf1[3072];
  __shared__ float ys1[2352], u21[2352];
  __shared__ float redS[4][3], redQ[4][3];
  __shared__ float AB[6];
  int tid = threadIdx.x;
  for (int t = tid; t < 512; t += 256) zL[t] = z[t];
  __syncthreads();
  for (int j = tid; j < 768; j += 256) {
    const float* wr = lw + (size_t)j * 512;
    float acc = lb[j];
    for (int k = 0; k < 512; ++k) acc = fmaf(zL[k], wr[k], acc);
    L0[j] = acc;
  }
  __syncthreads();
  // ---- conv0: (3,16,16) -> S=12, r=32 ----
  {
    float sc[3] = {0, 0, 0}, sq[3] = {0, 0, 0};
    for (int p = tid; p < 144; p += 256) {
      int py = p / 12, px = p - py * 12;
      float a1[3], a2[3];
      #pragma unroll
      for (int c = 0; c < 3; ++c) { a1[c] = cb[c]; a2[c] = c2b[c]; }
      for (int ci = 0; ci < 3; ++ci)
        #pragma unroll
        for (int ky = 0; ky < 5; ++ky) {
          const float* row = &L0[ci * 256 + (py + ky) * 16 + px];
          #pragma unroll
          for (int c = 0; c < 3; ++c)
            #pragma unroll
            for (int kx = 0; kx < 5; ++kx) {
              a1[c] = fmaf(row[kx], cw[c * 75 + ci * 25 + ky * 5 + kx], a1[c]);
              a2[c] = fmaf(row[kx], c2w[c * 75 + ci * 25 + ky * 5 + kx], a2[c]);
            }
        }
      int wy = ((py + 1) * 32 + 11) / 12 - (py * 32 + 11) / 12;
      int wx = ((px + 1) * 32 + 11) / 12 - (px * 32 + 11) / 12;
      float wgt = (float)(wy * wx);
      #pragma unroll
      for (int c = 0; c < 3; ++c) {
        ys0[c * 144 + p] = a1[c];
        u20[c * 144 + p] = a2[c];
        sc[c] += a1[c] * wgt;
        sq[c] += a1[c] * a1[c] * wgt;
      }
    }
    #pragma unroll
    for (int off = 32; off; off >>= 1)
      #pragma unroll
      for (int c = 0; c < 3; ++c) {
        sc[c] += __shfl_down(sc[c], off);
        sq[c] += __shfl_down(sq[c], off);
      }
    int wid = tid >> 6, lane = tid & 63;
    if (lane == 0)
      #pragma unroll
      for (int c = 0; c < 3; ++c) { redS[wid][c] = sc[c]; redQ[wid][c] = sq[c]; }
    __syncthreads();
    if (tid < 3) {
      int c = tid;
      float s1 = redS[0][c] + redS[1][c] + redS[2][c] + redS[3][c];
      float s2 = redQ[0][c] + redQ[1][c] + redQ[2][c] + redQ[3][c];
      float si_ = inp[0] + inp[1] + inp[2] + lnp[0] + lnp[1] + lnp[2];
      float sb = bnp[0] + bnp[1] + bnp[2];
      float2 ab = ab_from(s1, s2, s1, s2, 1024.f, 1.f, si_, sb, bnw[c], bnb[c], p1p[0]);
      AB[c] = ab.x; AB[3 + c] = ab.y;
    }
    __syncthreads();
  }
  {
    float P2a = p2p[0];
    for (int t = tid; t < 3072; t += 256) {
      int c = t >> 10, p = t & 1023;
      int oy = p >> 5, ox = p & 31;
      int si = ((oy * 12) >> 5) * 12 + ((ox * 12) >> 5);
      buf1[t] = AB[c] * ys0[c * 144 + si] + AB[3 + c] + P2a * u20[c * 144 + si];
    }
  }
  __syncthreads();
  // ---- conv1: (3,32,32) -> S=28, r=64 ----
  {
    const float* w1 = cw + 225;
    const float* w2 = c2w + 225;
    float sc[3] = {0, 0, 0}, sq[3] = {0, 0, 0};
    for (int p = tid; p < 784; p += 256) {
      int py = p / 28, px = p - py * 28;
      float a1[3], a2[3];
      #pragma unroll
      for (int c = 0; c < 3; ++c) { a1[c] = cb[3 + c]; a2[c] = c2b[3 + c]; }
      for (int ci = 0; ci < 3; ++ci)
        #pragma unroll
        for (int ky = 0; ky < 5; ++ky) {
          const float* row = &buf1[ci * 1024 + (py + ky) * 32 + px];
          #pragma unroll
          for (int c = 0; c < 3; ++c)
            #pragma unroll
            for (int kx = 0; kx < 5; ++kx) {
              a1[c] = fmaf(row[kx], w1[c * 75 + ci * 25 + ky * 5 + kx], a1[c]);
              a2[c] = fmaf(row[kx], w2[c * 75 + ci * 25 + ky * 5 + kx], a2[c]);
            }
        }
      int wy = ((py + 1) * 64 + 27) / 28 - (py * 64 + 27) / 28;
      int wx = ((px + 1) * 64 + 27) / 28 - (px * 64 + 27) / 28;
      float wgt = (float)(wy * wx);
      #pragma unroll
      for (int c = 0; c < 3; ++c) {
        ys1[c * 784 + p] = a1[c];
        u21[c * 784 + p] = a2[c];
        sc[c] += a1[c] * wgt;
        sq[c] += a1[c] * a1[c] * wgt;
      }
    }
    #pragma unroll
    for (int off = 32; off; off >>= 1)
      #pragma unroll
      for (int c = 0; c < 3; ++c) {
        sc[c] += __shfl_down(sc[c], off);
        sq[c] += __shfl_down(sq[c], off);
      }
    int wid = tid >> 6, lane = tid & 63;
    __syncthreads();  // protect redS reuse
    if (lane == 0)
      #pragma unroll
      for (int c = 0; c < 3; ++c) { redS[wid][c] = sc[c]; redQ[wid][c] = sq[c]; }
    __syncthreads();
    if (tid < 3) {
      int c = tid;
      float s1 = redS[0][c] + redS[1][c] + redS[2][c] + redS[3][c];
      float s2 = redQ[0][c] + redQ[1][c] + redQ[2][c] + redQ[3][c];
      float si_ = inp[3] + inp[4] + inp[5] + lnp[3] + lnp[4] + lnp[5];
      float sb = bnp[3] + bnp[4] + bnp[5];
      float2 ab = ab_from(s1, s2, s1, s2, 4096.f, 1.f, si_, sb, bnw[3 + c], bnb[3 + c], p1p[1]);
      AB[c] = ab.x; AB[3 + c] = ab.y;
    }
    __syncthreads();
  }
  {
    float P2b = p2p[1];
    for (int t = tid; t < 12288; t += 256) {
      int c = t >> 12, p = t & 4095;
      int oy = p >> 6, ox = p & 63;
      int si = ((oy * 28) >> 6) * 28 + ((ox * 28) >> 6);
      nb0[t] = AB[c] * ys1[c * 784 + si] + AB[3 + c] + P2b * u21[c * 784 + si];
    }
  }
}

// ---- attention HW=1024, pass 1 (fused y2+QKV recompute) ----
__global__ __launch_bounds__(256) void attn_rows_f(
    const float2* __restrict__ yu, const float* __restrict__ sums,
    const float* __restrict__ inp, const float* __restrict__ lnp,
    const float* __restrict__ bnp, const float* __restrict__ bnw,
    const float* __restrict__ bnb, const float* __restrict__ p1p,
    const float* __restrict__ p2p,
    const float* __restrict__ qw, const float* __restrict__ qb,
    const float* __restrict__ kw, const float* __restrict__ kb,
    float* __restrict__ Mp, float* __restrict__ Lp, int S) {
  __shared__ float pA[3], pB[3], pP2v;
  __shared__ float y2s[768], qs[768];
  int bid = blockIdx.x;
  int np = bid & 3; bid >>= 2;
  int mc = bid & 3;
  int b = bid >> 2;
  compute_AB(sums, b, 32, 1024.f, inp, lnp, bnp, bnw, bnb, p1p, p2p, pA, pB, &pP2v);
  size_t ybase = (size_t)b * 3 * S * S;
  for (int t = threadIdx.x; t < 768; t += 256) {
    int c = t >> 8, j = t & 255;
    int n = (np << 8) + j;
    int oy = n >> 5, ox = n & 31;
    int si = ((oy * S) >> 5) * S + ((ox * S) >> 5);
    float2 v = yu[ybase + c * S * S + si];
    y2s[t] = pA[c] * v.x + pB[c] + pP2v * v.y;
  }
  __syncthreads();
  for (int t = threadIdx.x; t < 768; t += 256) {
    int o = t >> 8, j = t & 255;
    qs[t] = qb[o] + qw[o * 3] * y2s[j] + qw[o * 3 + 1] * y2s[256 + j] +
            qw[o * 3 + 2] * y2s[512 + j];
  }
  __syncthreads();
  int m = (mc << 8) + threadIdx.x;
  int oy = m >> 5, ox = m & 31;
  int si = ((oy * S) >> 5) * S + ((ox * S) >> 5);
  float ym[3];
  #pragma unroll
  for (int c = 0; c < 3; ++c) {
    float2 v = yu[ybase + c * S * S + si];
    ym[c] = pA[c] * v.x + pB[c] + pP2v * v.y;
  }
  float k0 = (kb[0] + kw[0] * ym[0] + kw[1] * ym[1] + kw[2] * ym[2]) * LOG2E;
  float k1 = (kb[1] + kw[3] * ym[0] + kw[4] * ym[1] + kw[5] * ym[2]) * LOG2E;
  float k2 = (kb[2] + kw[6] * ym[0] + kw[7] * ym[1] + kw[8] * ym[2]) * LOG2E;
  float mr = -1e30f;
  for (int j = 0; j < 256; ++j) {
    float s = k0 * qs[j] + k1 * qs[256 + j] + k2 * qs[512 + j];
    mr = fmaxf(mr, s);
  }
  float l = 0.f;
  for (int j = 0; j < 256; ++j) {
    float s = k0 * qs[j] + k1 * qs[256 + j] + k2 * qs[512 + j];
    l += exp2f(s - mr);
  }
  int idx = (b * 4 + np) * 1024 + m;
  Mp[idx] = mr;
  Lp[idx] = l;
}

// ---- attention HW=1024, pass 2 (fused y2+QKV recompute, atomic out) ----
__global__ __launch_bounds__(256) void attn_out_f(
    const float2* __restrict__ yu, const float* __restrict__ sums,
    const float* __restrict__ inp, const float* __restrict__ lnp,
    const float* __restrict__ bnp, const float* __restrict__ bnw,
    const float* __restrict__ bnb, const float* __restrict__ p1p,
    const float* __restrict__ p2p,
    const float* __restrict__ qw, const float* __restrict__ qb,
    const float* __restrict__ kw, const float* __restrict__ kb,
    const float* __restrict__ vw, const float* __restrict__ vb,
    const float* __restrict__ Mp, const float* __restrict__ Lp,
    float* __restrict__ aout, int S) {
  __shared__ float pA[3], pB[3], pP2v;
  __shared__ float ym[768], ks[768], vs[768], Ms[256], Ls[256];
  int bid = blockIdx.x;
  int mp = bid & 3; bid >>= 2;
  int nc = bid & 3;
  int b = bid >> 2;
  compute_AB(sums, b, 32, 1024.f, inp, lnp, bnp, bnw, bnb, p1p, p2p, pA, pB, &pP2v);
  size_t ybase = (size_t)b * 3 * S * S;
  for (int t = threadIdx.x; t < 768; t += 256) {
    int c = t >> 8, j = t & 255;
    int m = (mp << 8) + j;
    int oy = m >> 5, ox = m & 31;
    int si = ((oy * S) >> 5) * S + ((ox * S) >> 5);
    float2 v = yu[ybase + c * S * S + si];
    ym[t] = pA[c] * v.x + pB[c] + pP2v * v.y;
  }
  __syncthreads();
  for (int t = threadIdx.x; t < 768; t += 256) {
    int o = t >> 8, j = t & 255;
    float y0 = ym[j], y1 = ym[256 + j], y2v = ym[512 + j];
    ks[t] = (kb[o] + kw[o * 3] * y0 + kw[o * 3 + 1] * y1 + kw[o * 3 + 2] * y2v) * LOG2E;
    vs[t] = vb[o] + vw[o * 3] * y0 + vw[o * 3 + 1] * y1 + vw[o * 3 + 2] * y2v;
  }
  {
    int t = threadIdx.x;
    int m = (mp << 8) + t;
    float M0 = Mp[(b * 4 + 0) * 1024 + m], M1 = Mp[(b * 4 + 1) * 1024 + m];
    float M2 = Mp[(b * 4 + 2) * 1024 + m], M3 = Mp[(b * 4 + 3) * 1024 + m];
    float L0 = Lp[(b * 4 + 0) * 1024 + m], L1 = Lp[(b * 4 + 1) * 1024 + m];
    float L2 = Lp[(b * 4 + 2) * 1024 + m], L3 = Lp[(b * 4 + 3) * 1024 + m];
    float MM = fmaxf(fmaxf(M0, M1), fmaxf(M2, M3));
    float LL = L0 * exp2f(M0 - MM) + L1 * exp2f(M1 - MM) +
               L2 * exp2f(M2 - MM) + L3 * exp2f(M3 - MM);
    Ms[t] = MM;
    Ls[t] = 1.0f / LL;
  }
  __syncthreads();
  int n = (nc << 8) + threadIdx.x;
  int oy = n >> 5, ox = n & 31;
  int si = ((oy * S) >> 5) * S + ((ox * S) >> 5);
  float yn[3];
  #pragma unroll
  for (int c = 0; c < 3; ++c) {
    float2 v = yu[ybase + c * S * S + si];
    yn[c] = pA[c] * v.x + pB[c] + pP2v * v.y;
  }
  float q0 = qb[0] + qw[0] * yn[0] + qw[1] * yn[1] + qw[2] * yn[2];
  float q1 = qb[1] + qw[3] * yn[0] + qw[4] * yn[1] + qw[5] * yn[2];
  float q2 = qb[2] + qw[6] * yn[0] + qw[7] * yn[1] + qw[8] * yn[2];
  float a0 = 0.f, a1 = 0.f, a2 = 0.f;
  for (int j = 0; j < 256; ++j) {
    float s = ks[j] * q0 + ks[256 + j] * q1 + ks[512 + j] * q2;
    float w = exp2f(s - Ms[j]) * Ls[j];
    a0 = fmaf(vs[j], w, a0);
    a1 = fmaf(vs[256 + j], w, a1);
    a2 = fmaf(vs[512 + j], w, a2);
  }
  if (mp == 0) { a0 += yn[0]; a1 += yn[1]; a2 += yn[2]; }
  size_t o0 = (size_t)b * 3 * 1024 + n;
  atomicAdd(&aout[o0], a0);
  atomicAdd(&aout[o0 + 1024], a1);
  atomicAdd(&aout[o0 + 2048], a2);
}

// ---- attention HW=256, fully fused (y2+QKV+softmax+out+residual) ----
__global__ __launch_bounds__(256) void attn256_f(
    const float2* __restrict__ yu, const float* __restrict__ sums,
    const float* __restrict__ inp, const float* __restrict__ lnp,
    const float* __restrict__ bnp, const float* __restrict__ bnw,
    const float* __restrict__ bnb, const float* __restrict__ p1p,
    const float* __restrict__ p2p,
    const float* __restrict__ qw, const float* __restrict__ qb,
    const float* __restrict__ kw, const float* __restrict__ kb,
    const float* __restrict__ vw, const float* __restrict__ vb,
    float* __restrict__ aout, int S) {
  __shared__ float pA[3], pB[3], pP2v;
  __shared__ float y2s[768], qs[768], ks[768], vs[768], Ms[256], Ls[256];
  int b = blockIdx.x;
  compute_AB(sums, b, 32, 256.f, inp, lnp, bnp, bnw, bnb, p1p, p2p, pA, pB, &pP2v);
  size_t ybase = (size_t)b * 3 * S * S;
  for (int t = threadIdx.x; t < 768; t += 256) {
    int c = t >> 8, p = t & 255;
    int oy = p >> 4, ox = p & 15;
    int si = ((oy * S) >> 4) * S + ((ox * S) >> 4);
    float2 v = yu[ybase + c * S * S + si];
    y2s[t] = pA[c] * v.x + pB[c] + pP2v * v.y;
  }
  __syncthreads();
  for (int t = threadIdx.x; t < 768; t += 256) {
    int o = t >> 8, p = t & 255;
    float y0 = y2s[p], y1 = y2s[256 + p], y2v = y2s[512 + p];
    qs[t] = qb[o] + qw[o * 3] * y0 + qw[o * 3 + 1] * y1 + qw[o * 3 + 2] * y2v;
    ks[t] = (kb[o] + kw[o * 3] * y0 + kw[o * 3 + 1] * y1 + kw[o * 3 + 2] * y2v) * LOG2E;
    vs[t] = vb[o] + vw[o * 3] * y0 + vw[o * 3 + 1] * y1 + vw[o * 3 + 2] * y2v;
  }
  __syncthreads();
  {
    int m = threadIdx.x;
    float kx = ks[m], ky = ks[256 + m], kz = ks[512 + m];
    float mr = -1e30f;
    for (int j = 0; j < 256; ++j) {
      float s = kx * qs[j] + ky * qs[256 + j] + kz * qs[512 + j];
      mr = fmaxf(mr, s);
    }
    float l = 0.f;
    for (int j = 0; j < 256; ++j) {
      float s = kx * qs[j] + ky * qs[256 + j] + kz * qs[512 + j];
      l += exp2f(s - mr);
    }
    Ms[m] = mr;
    Ls[m] = 1.0f / l;
  }
  __syncthreads();
  int n = threadIdx.x;
  float q0 = qs[n], q1 = qs[256 + n], q2 = qs[512 + n];
  float a0 = 0.f, a1 = 0.f, a2 = 0.f;
  for (int j = 0; j < 256; ++j) {
    float s = ks[j] * q0 + ks[256 + j] * q1 + ks[512 + j] * q2;
    float w = exp2f(s - Ms[j]) * Ls[j];
    a0 = fmaf(vs[j], w, a0);
    a1 = fmaf(vs[256 + j], w, a1);
    a2 = fmaf(vs[512 + j], w, a2);
  }
  size_t o0 = (size_t)b * 768 + n;
  aout[o0] = a0 + y2s[n];
  aout[o0 + 256] = a1 + y2s[256 + n];
  aout[o0 + 512] = a2 + y2s[512 + n];
}

// ---- final: affine + p2*u2 + tanh -> out ----
__global__ __launch_bounds__(256) void elem_final(
    const float2* __restrict__ yu, const float* __restrict__ sums,
    const float* __restrict__ inp, const float* __restrict__ lnp,
    const float* __restrict__ bnp, const float* __restrict__ bnw,
    const float* __restrict__ bnb, const float* __restrict__ p1p,
    const float* __restrict__ p2p, float* __restrict__ out, int S) {
  __shared__ float pA[3], pB[3], pP2v;
  int n = blockIdx.x >> 8;
  int p = ((blockIdx.x & 255) << 8) + threadIdx.x;
  compute_AB(sums, n, 32, 65536.f, inp, lnp, bnp, bnw, bnb, p1p, p2p, pA, pB, &pP2v);
  int oy = p >> 8, ox = p & 255;
  int si = ((oy * S) >> 8) * S + ((ox * S) >> 8);
  size_t ybase = (size_t)n * 3 * S * S;
  #pragma unroll
  for (int c = 0; c < 3; ++c) {
    float2 v = yu[ybase + c * S * S + si];
    out[((size_t)(n * 3 + c) << 16) + p] = tanhf(pA[c] * v.x + pB[c] + pP2v * v.y);
  }
}

#define NPX nullptr, nullptr, nullptr, nullptr, nullptr, nullptr, nullptr, \
            nullptr, nullptr, 0, 0, 0

extern "C" void kernel_launch(void* const* d_in, const int* in_sizes, int n_in,
                              void* d_out, int out_size, void* d_ws, size_t ws_size,
                              hipStream_t stream) {
  const float* x       = (const float*)d_in[0];
  const float* noise_z = (const float*)d_in[1];
  const float* lin_w   = (const float*)d_in[2];
  const float* lin_b   = (const float*)d_in[3];
  const float* conv_w  = (const float*)d_in[4];
  const float* conv_b  = (const float*)d_in[5];
  const float* conv2_w = (const float*)d_in[6];
  const float* conv2_b = (const float*)d_in[7];
  const float* q_w     = (const float*)d_in[8];
  const float* q_b     = (const float*)d_in[9];
  const float* k_w     = (const float*)d_in[10];
  const float* k_b     = (const float*)d_in[11];
  const float* v_w     = (const float*)d_in[12];
  const float* v_b     = (const float*)d_in[13];
  const float* in_p    = (const float*)d_in[14];
  const float* ln_p    = (const float*)d_in[15];
  const float* bn_p    = (const float*)d_in[16];
  const float* bn_w    = (const float*)d_in[17];
  const float* bn_b    = (const float*)d_in[18];
  const float* p1      = (const float*)d_in[19];
  const float* p2      = (const float*)d_in[20];
  float* out = (float*)d_out;

  float* ws = (float*)d_ws;
  size_t off = 0;
  auto alloc = [&](size_t nf) { float* p = ws + off; off += nf; return p; };
  float* SUMS = alloc(2304);
  float* A5   = alloc(98304);
  float* A8   = alloc(98304);
  float* A6   = alloc(24576);
  float* A7   = alloc(24576);
  float2* YU2 = (float2*)alloc(12192768);  // 252^2 * 96 * 2
  float2* PA  = (float2*)alloc(3145728);   // up to 128^2 * 96 * 2
  float2* PB  = (float2*)alloc(3145728);
  float* Mp   = alloc(131072);
  float* Lp   = alloc(131072);
  float* NB0  = alloc(12288);

  hipMemsetAsync(SUMS, 0, (2304 + 98304 + 98304) * sizeof(float), stream);

  const float* nul = nullptr;
  const float2* nul2 = nullptr;

  // noise path (blocks 0,1) -> NB0 (1,3,64,64)
  noise_all<<<1, 256, 0, stream>>>(noise_z, lin_w, lin_b, conv_w, conv_b,
      conv2_w, conv2_b, in_p, ln_p, bn_p, bn_w, bn_b, p1, p2, NB0);

  // conv2: x -> YU2 (S=252, r=256)
  conv_up_t<false><<<2048, 256, 0, stream>>>(x, nul2, YU2, conv_w + 450,
      conv_b + 6, conv2_w + 450, conv2_b + 6, SUMS + 384, 256, 252, 256, 4, 16,
      NPX);
  // conv3: fused(b2) YU2 -> PA (S=128); prev Sp=252, logrp=8
  conv_dn_t<true><<<2048, 256, 0, stream>>>(nul, YU2, PA, conv_w + 675,
      conv_b + 9, conv2_w + 675, conv2_b + 9, SUMS + 576, 256, 128, 252, 7, 4, 16,
      SUMS + 384, in_p + 6, ln_p + 6, bn_p + 6, bn_w + 6, bn_b + 6, p1 + 2,
      p2 + 2, nul, 32, 252, 8);
  // conv4: fused(b3) PA -> PB (S=64); prev Sp=128, logrp=7 (identity)
  conv_dn_t<true><<<512, 256, 0, stream>>>(nul, PA, PB, conv_w + 900,
      conv_b + 12, conv2_w + 900, conv2_b + 12, SUMS + 768, 128, 64, 124, 6, 2, 8,
      SUMS + 576, in_p + 9, ln_p + 9, bn_p + 9, bn_w + 9, bn_b + 9, p1 + 3,
      p2 + 3, nul, 32, 128, 7);
  // conv5: fused(b4)+noise PB -> PA (S=32); prev Sp=64, logrp=6 (identity)
  conv_dn_t<true><<<128, 256, 0, stream>>>(nul, PB, PA, conv_w + 1125,
      conv_b + 15, conv2_w + 1125, conv2_b + 15, SUMS + 960, 64, 32, 60, 5, 1, 4,
      SUMS + 768, in_p + 12, ln_p + 12, bn_p + 12, bn_w + 12, bn_b + 12, p1 + 4,
      p2 + 4, NB0, 32, 64, 6);
  // attn5 (HW=1024) on PA (S=32)
  attn_rows_f<<<512, 256, 0, stream>>>(PA, SUMS + 960, in_p + 15, ln_p + 15,
      bn_p + 15, bn_w + 15, bn_b + 15, p1 + 5, p2 + 5,
      q_w + 45, q_b + 15, k_w + 45, k_b + 15, Mp, Lp, 32);
  attn_out_f<<<512, 256, 0, stream>>>(PA, SUMS + 960, in_p + 15, ln_p + 15,
      bn_p + 15, bn_w + 15, bn_b + 15, p1 + 5, p2 + 5,
      q_w + 45, q_b + 15, k_w + 45, k_b + 15, v_w + 45, v_b + 15, Mp, Lp, A5, 32);
  // conv6: direct A5 -> PB (S=16)
  conv_dn_t<false><<<64, 256, 0, stream>>>(A5, nul2, PB, conv_w + 1350,
      conv_b + 18, conv2_w + 1350, conv2_b + 18, SUMS + 1152, 32, 16, 28, 4, 1, 2,
      NPX);
  // attn6 (HW=256) on PB (S=16)
  attn256_f<<<32, 256, 0, stream>>>(PB, SUMS + 1152, in_p + 18, ln_p + 18,
      bn_p + 18, bn_w + 18, bn_b + 18, p1 + 6, p2 + 6,
      q_w + 54, q_b + 18, k_w + 54, k_b + 18, v_w + 54, v_b + 18, A6, 16);
  // conv7: direct A6 -> PA (S=12, r=16)
  conv_src_f2<<<32, 256, 0, stream>>>(A6, PA, conv_w + 1575, conv_b + 21,
      conv2_w + 1575, conv2_b + 21, SUMS + 1344, 32, 16, 12, 12, 16);
  // attn7 (HW=256) on PA (S=12)
  attn256_f<<<32, 256, 0, stream>>>(PA, SUMS + 1344, in_p + 21, ln_p + 21,
      bn_p + 21, bn_w + 21, bn_b + 21, p1 + 7, p2 + 7,
      q_w + 63, q_b + 21, k_w + 63, k_b + 21, v_w + 63, v_b + 21, A7, 12);
  // conv8: direct A7 -> PB (S=12, r=32)
  conv_src_f2<<<32, 256, 0, stream>>>(A7, PB, conv_w + 1800, conv_b + 24,
      conv2_w + 1800, conv2_b + 24, SUMS + 1536, 32, 16, 12, 12, 32);
  // attn8 (HW=1024) on PB (S=12)
  attn_rows_f<<<512, 256, 0, stream>>>(PB, SUMS + 1536, in_p + 24, ln_p + 24,
      bn_p + 24, bn_w + 24, bn_b + 24, p1 + 8, p2 + 8,
      q_w + 72, q_b + 24, k_w + 72, k_b + 24, Mp, Lp, 12);
  attn_out_f<<<512, 256, 0, stream>>>(PB, SUMS + 1536, in_p + 24, ln_p + 24,
      bn_p + 24, bn_w + 24, bn_b + 24, p1 + 8, p2 + 8,
      q_w + 72, q_b + 24, k_w + 72, k_b + 24, v_w + 72, v_b + 24, Mp, Lp, A8, 12);
  // conv9: direct A8 -> PA (S=28, r=64)
  conv_up_t<false><<<64, 256, 0, stream>>>(A8, nul2, PA, conv_w + 2025,
      conv_b + 27, conv2_w + 2025, conv2_b + 27, SUMS + 1728, 32, 28, 64, 1, 2,
      NPX);
  // conv10: fused(b9) PA -> PB (S=60); prev Sp=28, logrp=6
  conv_up_t<true><<<128, 256, 0, stream>>>(nul, PA, PB, conv_w + 2250,
      conv_b + 30, conv2_w + 2250, conv2_b + 30, SUMS + 1920, 64, 60, 128, 1, 4,
      SUMS + 1728, in_p + 27, ln_p + 27, bn_p + 27, bn_w + 27, bn_b + 27,
      p1 + 9, p2 + 9, nul, 32, 28, 6);
  // conv11: fused(b10) PB -> YU2 (S=124); prev Sp=60, logrp=7
  conv_up_t<true><<<512, 256, 0, stream>>>(nul, PB, YU2, conv_w + 2475,
      conv_b + 33, conv2_w + 2475, conv2_b + 33, SUMS + 2112, 128, 124, 256, 2, 8,
      SUMS + 1920, in_p + 30, ln_p + 30, bn_p + 30, bn_w + 30, bn_b + 30,
      p1 + 10, p2 + 10, nul, 32, 60, 7);
  // final: tanh -> out
  elem_final<<<8192, 256, 0, stream>>>(YU2, SUMS + 2112, in_p + 33, ln_p + 33,
      bn_p + 33, bn_w + 33, bn_b + 33, p1 + 11, p2 + 11, out, 124);
}

// Round 7
// 550.261 us; speedup vs baseline: 1.6030x; 1.0804x over previous
//
#include <hip/hip_runtime.h>
#include <math.h>

#define EPS 1e-5f
#define LOG2E 1.44269504088896340736f

// ---- shared affine-fold helper: A,B from sums (instance+batch norm + p1) ----
__device__ __forceinline__ float2 ab_from(float s1, float s2, float bs, float bs2,
    float hw, float Nf, float si_, float sb, float bnw_c, float bnb_c, float p1v) {
  float inv = 1.0f / hw;
  float mi = s1 * inv, vi = s2 * inv - mi * mi;
  float ri = rsqrtf(vi + EPS);
  float invb = 1.0f / (Nf * hw);
  float mb = bs * invb, vb = bs2 * invb - mb * mb;
  float rb = rsqrtf(vb + EPS);
  float A = 1.0f + si_ * ri + sb * rb * bnw_c;
  float B = -(si_ * ri * mi + sb * rb * bnw_c * mb) + sb * bnb_c;
  return make_float2(A * p1v, B * p1v);
}

__device__ __forceinline__ void compute_AB(
    const float* __restrict__ sums, int n, int N, float hw,
    const float* __restrict__ inp, const float* __restrict__ lnp,
    const float* __restrict__ bnp, const float* __restrict__ bnw,
    const float* __restrict__ bnb, const float* __restrict__ p1p,
    const float* __restrict__ p2p, float* pA, float* pB, float* pP2) {
  if (threadIdx.x == 0) *pP2 = p2p[0];
  if (threadIdx.x < 3) {
    int c = threadIdx.x;
    float si_ = inp[0] + inp[1] + inp[2] + lnp[0] + lnp[1] + lnp[2];
    float sb = bnp[0] + bnp[1] + bnp[2];
    float s1 = sums[2 * (n * 3 + c)], s2 = sums[2 * (n * 3 + c) + 1];
    float bs = 0.f, bs2 = 0.f;
    for (int nn = 0; nn < N; ++nn) {
      bs += sums[2 * (nn * 3 + c)];
      bs2 += sums[2 * (nn * 3 + c) + 1];
    }
    float2 ab = ab_from(s1, s2, bs, bs2, hw, (float)N, si_, sb, bnw[c], bnb[c], p1p[0]);
    pA[c] = ab.x;
    pB[c] = ab.y;
  }
  __syncthreads();
}

// stats block-reduce (all threads must participate)
#define STATS_REDUCE_ATOMIC(scv, sqv, sumsp, nvar)                            \
  {                                                                           \
    _Pragma("unroll")                                                         \
    for (int off = 32; off; off >>= 1) {                                      \
      _Pragma("unroll")                                                       \
      for (int c = 0; c < 3; ++c) {                                           \
        scv[c] += __shfl_down(scv[c], off);                                   \
        sqv[c] += __shfl_down(sqv[c], off);                                   \
      }                                                                       \
    }                                                                         \
    __shared__ float redS[4][3], redQ[4][3];                                  \
    int wid = threadIdx.x >> 6, lane = threadIdx.x & 63;                      \
    if (lane == 0) {                                                          \
      _Pragma("unroll")                                                       \
      for (int c = 0; c < 3; ++c) { redS[wid][c] = scv[c]; redQ[wid][c] = sqv[c]; } \
    }                                                                         \
    __syncthreads();                                                          \
    if (threadIdx.x < 3) {                                                    \
      int c = threadIdx.x;                                                    \
      atomicAdd(&sumsp[2 * ((nvar) * 3 + c)],                                 \
                redS[0][c] + redS[1][c] + redS[2][c] + redS[3][c]);           \
      atomicAdd(&sumsp[2 * ((nvar) * 3 + c) + 1],                             \
                redQ[0][c] + redQ[1][c] + redQ[2][c] + redQ[3][c]);           \
    }                                                                         \
  }

// ---- LDS-tiled upsample conv (S==hc): 64x16 tile, TX=4, float2 out ----
template <bool FUSED>
__global__ __launch_bounds__(256) void conv_up_t(
    const float* __restrict__ in, const float2* __restrict__ pyu,
    float2* __restrict__ yu,
    const float* __restrict__ w1, const float* __restrict__ b1,
    const float* __restrict__ w2, const float* __restrict__ b2,
    float* __restrict__ sums, int Hin, int S, int r, int tilesX, int tilesY,
    const float* __restrict__ psums,
    const float* __restrict__ pinp, const float* __restrict__ plnp,
    const float* __restrict__ pbnp, const float* __restrict__ pbnw,
    const float* __restrict__ pbnb, const float* __restrict__ pp1,
    const float* __restrict__ pp2, const float* __restrict__ pnoise,
    int pN, int Sp, int logrp) {
  const int TW = 64, TH = 16, IW = 68, IH = 20;
  __shared__ float lin[3 * IH * IW];
  __shared__ float pA[3], pB[3], pP2v;
  int tpi = tilesX * tilesY;
  int n = blockIdx.x / tpi;
  int trem = blockIdx.x - n * tpi;
  int tyB = trem / tilesX, txB = trem - tyB * tilesX;
  int px0 = txB * TW, py0 = tyB * TH;
  const float* inb = in + (size_t)n * 3 * Hin * Hin;
  if (FUSED) {
    compute_AB(psums, n, pN, (float)(Hin * Hin), pinp, plnp, pbnp, pbnw, pbnb,
               pp1, pp2, pA, pB, &pP2v);
    size_t pbase = (size_t)n * 3 * Sp * Sp;
    for (int t = threadIdx.x; t < 3 * IH * IW; t += 256) {
      int cc = t / (IH * IW);
      int rem = t - cc * IH * IW;
      int rr = rem / IW, col = rem - rr * IW;
      int gy = py0 + rr; gy = gy < Hin ? gy : Hin - 1;
      int gx = px0 + col; gx = gx < Hin ? gx : Hin - 1;
      int si = ((gy * Sp) >> logrp) * Sp + ((gx * Sp) >> logrp);
      float2 v = pyu[pbase + cc * Sp * Sp + si];
      float val = pA[cc] * v.x + pB[cc] + pP2v * v.y;
      if (pnoise) val += pnoise[((size_t)cc * Hin + gy) * Hin + gx];
      lin[t] = val;
    }
  } else {
    if (px0 + IW <= Hin && py0 + IH <= Hin) {
      for (int t = threadIdx.x; t < 3 * IH * 17; t += 256) {
        int cc = t / (IH * 17);
        int rem = t - cc * (IH * 17);
        int rr = rem / 17, j = rem - rr * 17;
        float4 v = *reinterpret_cast<const float4*>(
            inb + ((size_t)cc * Hin + py0 + rr) * Hin + px0 + 4 * j);
        *reinterpret_cast<float4*>(&lin[(cc * IH + rr) * IW + 4 * j]) = v;
      }
    } else {
      for (int t = threadIdx.x; t < 3 * IH * IW; t += 256) {
        int cc = t / (IH * IW);
        int rem = t - cc * IH * IW;
        int rr = rem / IW, col = rem - rr * IW;
        int gy = py0 + rr; gy = gy < Hin ? gy : Hin - 1;
        int gx = px0 + col; gx = gx < Hin ? gx : Hin - 1;
        lin[t] = inb[((size_t)cc * Hin + gy) * Hin + gx];
      }
    }
  }
  __syncthreads();
  int tx = threadIdx.x & 15, ty = threadIdx.x >> 4;
  int lx0 = tx * 4;
  int px = px0 + lx0, py = py0 + ty;
  float a1[3][4], a2[3][4];
  #pragma unroll
  for (int c = 0; c < 3; ++c) {
    float bb1 = b1[c], bb2 = b2[c];
    #pragma unroll
    for (int x = 0; x < 4; ++x) { a1[c][x] = bb1; a2[c][x] = bb2; }
  }
  #pragma unroll 1
  for (int ci = 0; ci < 3; ++ci) {
    const float* lrow = lin + ci * IH * IW + ty * IW + lx0;
    const float* wp1 = w1 + ci * 25;
    const float* wp2 = w2 + ci * 25;
    #pragma unroll
    for (int ky = 0; ky < 5; ++ky) {
      float v[8];
      #pragma unroll
      for (int j = 0; j < 8; ++j) v[j] = lrow[ky * IW + j];
      #pragma unroll
      for (int c = 0; c < 3; ++c) {
        #pragma unroll
        for (int kx = 0; kx < 5; ++kx) {
          float wa = wp1[c * 75 + ky * 5 + kx];
          float wb = wp2[c * 75 + ky * 5 + kx];
          #pragma unroll
          for (int x = 0; x < 4; ++x) {
            a1[c][x] = fmaf(v[kx + x], wa, a1[c][x]);
            a2[c][x] = fmaf(v[kx + x], wb, a2[c][x]);
          }
        }
      }
    }
  }
  float sc[3] = {0.f, 0.f, 0.f}, sq[3] = {0.f, 0.f, 0.f};
  bool valid = (py < S) && (px < S);
  if (valid) {
    int hc = S;
    float wy = (float)(((py + 1) * r + hc - 1) / hc - (py * r + hc - 1) / hc);
    float wx[4];
    #pragma unroll
    for (int x = 0; x < 4; ++x) {
      int pxx = px + x;
      wx[x] = (float)(((pxx + 1) * r + hc - 1) / hc - (pxx * r + hc - 1) / hc);
    }
    #pragma unroll
    for (int c = 0; c < 3; ++c) {
      size_t idx = ((size_t)(n * 3 + c) * S + py) * S + px;
      float2* yp = yu + idx;
      *reinterpret_cast<float4*>(yp) =
          make_float4(a1[c][0], a2[c][0], a1[c][1], a2[c][1]);
      *reinterpret_cast<float4*>(yp + 2) =
          make_float4(a1[c][2], a2[c][2], a1[c][3], a2[c][3]);
      #pragma unroll
      for (int x = 0; x < 4; ++x) {
        float wgt = wy * wx[x];
        sc[c] += a1[c][x] * wgt;
        sq[c] += a1[c][x] * a1[c][x] * wgt;
      }
    }
  }
  STATS_REDUCE_ATOMIC(sc, sq, sums, n)
}

// ---- LDS-tiled downsample conv (ratio<2.05): 32x8 tile, float2 out ----
template <bool FUSED>
__global__ __launch_bounds__(256) void conv_dn_t(
    const float* __restrict__ in, const float2* __restrict__ pyu,
    float2* __restrict__ yu,
    const float* __restrict__ w1, const float* __restrict__ b1,
    const float* __restrict__ w2, const float* __restrict__ b2,
    float* __restrict__ sums, int Hin, int S, int hc, int logr,
    int tilesX, int tilesY,
    const float* __restrict__ psums,
    const float* __restrict__ pinp, const float* __restrict__ plnp,
    const float* __restrict__ pbnp, const float* __restrict__ pbnw,
    const float* __restrict__ pbnb, const float* __restrict__ pp1,
    const float* __restrict__ pp2, const float* __restrict__ pnoise,
    int pN, int Sp, int logrp) {
  const int TW = 32, TH = 8, IW = 68, IH = 20;
  __shared__ float lin[3 * IH * IW];
  __shared__ float pA[3], pB[3], pP2v;
  int tpi = tilesX * tilesY;
  int n = blockIdx.x / tpi;
  int trem = blockIdx.x - n * tpi;
  int tyB = trem / tilesX, txB = trem - tyB * tilesX;
  int px0 = txB * TW, py0 = tyB * TH;
  int sy0 = (py0 * hc) >> logr, sx0 = (px0 * hc) >> logr;
  const float* inb = in + (size_t)n * 3 * Hin * Hin;
  if (FUSED) {
    compute_AB(psums, n, pN, (float)(Hin * Hin), pinp, plnp, pbnp, pbnw, pbnb,
               pp1, pp2, pA, pB, &pP2v);
    size_t pbase = (size_t)n * 3 * Sp * Sp;
    for (int t = threadIdx.x; t < 3 * IH * IW; t += 256) {
      int cc = t / (IH * IW);
      int rem = t - cc * IH * IW;
      int rr = rem / IW, col = rem - rr * IW;
      int gy = sy0 + rr; gy = gy < Hin ? gy : Hin - 1;
      int gx = sx0 + col; gx = gx < Hin ? gx : Hin - 1;
      int si = ((gy * Sp) >> logrp) * Sp + ((gx * Sp) >> logrp);
      float2 v = pyu[pbase + cc * Sp * Sp + si];
      float val = pA[cc] * v.x + pB[cc] + pP2v * v.y;
      if (pnoise) val += pnoise[((size_t)cc * Hin + gy) * Hin + gx];
      lin[t] = val;
    }
  } else {
    for (int t = threadIdx.x; t < 3 * IH * IW; t += 256) {
      int cc = t / (IH * IW);
      int rem = t - cc * IH * IW;
      int rr = rem / IW, col = rem - rr * IW;
      int gy = sy0 + rr; gy = gy < Hin ? gy : Hin - 1;
      int gx = sx0 + col; gx = gx < Hin ? gx : Hin - 1;
      lin[t] = inb[((size_t)cc * Hin + gy) * Hin + gx];
    }
  }
  __syncthreads();
  int tx = threadIdx.x & 31, ty = threadIdx.x >> 5;
  int px = px0 + tx, py = py0 + ty;
  int sxl = ((px * hc) >> logr) - sx0;
  int syl = ((py * hc) >> logr) - sy0;
  float a1[3], a2[3];
  #pragma unroll
  for (int c = 0; c < 3; ++c) { a1[c] = b1[c]; a2[c] = b2[c]; }
  #pragma unroll 1
  for (int ci = 0; ci < 3; ++ci) {
    const float* lrow = lin + ci * IH * IW + syl * IW + sxl;
    const float* wp1 = w1 + ci * 25;
    const float* wp2 = w2 + ci * 25;
    #pragma unroll
    for (int ky = 0; ky < 5; ++ky) {
      float v[5];
      #pragma unroll
      for (int j = 0; j < 5; ++j) v[j] = lrow[ky * IW + j];
      #pragma unroll
      for (int c = 0; c < 3; ++c) {
        #pragma unroll
        for (int kx = 0; kx < 5; ++kx) {
          a1[c] = fmaf(v[kx], wp1[c * 75 + ky * 5 + kx], a1[c]);
          a2[c] = fmaf(v[kx], wp2[c * 75 + ky * 5 + kx], a2[c]);
        }
      }
    }
  }
  float sc[3] = {0.f, 0.f, 0.f}, sq[3] = {0.f, 0.f, 0.f};
  bool valid = (py < S) && (px < S);
  if (valid) {
    #pragma unroll
    for (int c = 0; c < 3; ++c) {
      size_t idx = ((size_t)(n * 3 + c) * S + py) * S + px;
      yu[idx] = make_float2(a1[c], a2[c]);
      sc[c] += a1[c];
      sq[c] += a1[c] * a1[c];
    }
  }
  STATS_REDUCE_ATOMIC(sc, sq, sums, n)
}

// ---- tiny-source upsample conv (S<=12), direct input, float2 out ----
__global__ __launch_bounds__(256) void conv_src_f2(
    const float* __restrict__ in, float2* __restrict__ yu,
    const float* __restrict__ w1, const float* __restrict__ b1,
    const float* __restrict__ w2, const float* __restrict__ b2,
    float* __restrict__ sums, int N, int Hin, int S, int hc, int r) {
  int n = blockIdx.x;
  int t = threadIdx.x;
  int SX = S / 2;
  int py = t / SX;
  int px0 = (t - py * SX) * 2;
  bool valid = (py < S);
  float a1[3][2], a2[3][2];
  #pragma unroll
  for (int c = 0; c < 3; ++c) {
    float bb1 = b1[c], bb2 = b2[c];
    a1[c][0] = bb1; a1[c][1] = bb1; a2[c][0] = bb2; a2[c][1] = bb2;
  }
  float sc[3] = {0.f, 0.f, 0.f}, sq[3] = {0.f, 0.f, 0.f};
  if (valid) {
    const float* ip0 = in + ((size_t)(n * 3) * Hin + py) * Hin + px0;
    #pragma unroll
    for (int ci = 0; ci < 3; ++ci) {
      const float* ip = ip0 + (size_t)ci * Hin * Hin;
      #pragma unroll
      for (int ky = 0; ky < 5; ++ky) {
        const float* row = ip + ky * Hin;
        float v[6];
        #pragma unroll
        for (int kx = 0; kx < 6; ++kx) v[kx] = row[kx];
        #pragma unroll
        for (int c = 0; c < 3; ++c) {
          const float* wp1 = w1 + c * 75 + ci * 25 + ky * 5;
          const float* wp2 = w2 + c * 75 + ci * 25 + ky * 5;
          #pragma unroll
          for (int kx = 0; kx < 5; ++kx) {
            float wv1 = wp1[kx], wv2 = wp2[kx];
            a1[c][0] = fmaf(v[kx], wv1, a1[c][0]);
            a1[c][1] = fmaf(v[kx + 1], wv1, a1[c][1]);
            a2[c][0] = fmaf(v[kx], wv2, a2[c][0]);
            a2[c][1] = fmaf(v[kx + 1], wv2, a2[c][1]);
          }
        }
      }
    }
    float wy = (float)(((py + 1) * r + hc - 1) / hc - (py * r + hc - 1) / hc);
    float wx0 = (float)(((px0 + 1) * r + hc - 1) / hc - (px0 * r + hc - 1) / hc);
    float wx1 = (float)(((px0 + 2) * r + hc - 1) / hc - ((px0 + 1) * r + hc - 1) / hc);
    int base = (n * 3) * S * S + py * S + px0;
    #pragma unroll
    for (int c = 0; c < 3; ++c) {
      yu[base + c * S * S] = make_float2(a1[c][0], a2[c][0]);
      yu[base + c * S * S + 1] = make_float2(a1[c][1], a2[c][1]);
      sc[c] += a1[c][0] * wy * wx0 + a1[c][1] * wy * wx1;
      sq[c] += a1[c][0] * a1[c][0] * wy * wx0 + a1[c][1] * a1[c][1] * wy * wx1;
    }
  }
  STATS_REDUCE_ATOMIC(sc, sq, sums, n)
}

// ---- Linear 512->768: one wave per output row, coalesced float4 ----
__global__ __launch_bounds__(256) void linear_wave(
    const float* __restrict__ z, const float* __restrict__ w,
    const float* __restrict__ b, float* __restrict__ out) {
  int row = (blockIdx.x << 2) + (threadIdx.x >> 6);
  int lane = threadIdx.x & 63;
  const float4* wr = reinterpret_cast<const float4*>(w + (size_t)row * 512);
  const float4* zz = reinterpret_cast<const float4*>(z);
  float acc = 0.f;
  #pragma unroll
  for (int i = 0; i < 2; ++i) {
    float4 wv = wr[lane + 64 * i];
    float4 zv = zz[lane + 64 * i];
    acc += wv.x * zv.x + wv.y * zv.y + wv.z * zv.z + wv.w * zv.w;
  }
  #pragma unroll
  for (int off = 32; off; off >>= 1) acc += __shfl_down(acc, off);
  if (lane == 0) out[row] = acc + b[row];
}

// ---- noise conv path (blocks 0,1) in one block, L0 from global ----
__global__ __launch_bounds__(256) void noise_rest(
    const float* __restrict__ L0g,
    const float* __restrict__ cw, const float* __restrict__ cb,
    const float* __restrict__ c2w, const float* __restrict__ c2b,
    const float* __restrict__ inp, const float* __restrict__ lnp,
    const float* __restrict__ bnp, const float* __restrict__ bnw,
    const float* __restrict__ bnb, const float* __restrict__ p1p,
    const float* __restrict__ p2p, float* __restrict__ nb0) {
  __shared__ float L0[768];
  __shared__ float ys0[432], u20[432];
  __shared__ float buf1[3072];
  __shared__ float ys1[2352], u21[2352];
  __shared__ float redS[4][3], redQ[4][3];
  __shared__ float AB[6];
  int tid = threadIdx.x;
  for (int t = tid; t < 768; t += 256) L0[t] = L0g[t];
  __syncthreads();
  // ---- conv0: (3,16,16) -> S=12, r=32 ----
  {
    float sc[3] = {0, 0, 0}, sq[3] = {0, 0, 0};
    for (int p = tid; p < 144; p += 256) {
      int py = p / 12, px = p - py * 12;
      float a1[3], a2[3];
      #pragma unroll
      for (int c = 0; c < 3; ++c) { a1[c] = cb[c]; a2[c] = c2b[c]; }
      for (int ci = 0; ci < 3; ++ci)
        #pragma unroll
        for (int ky = 0; ky < 5; ++ky) {
          const float* row = &L0[ci * 256 + (py + ky) * 16 + px];
          #pragma unroll
          for (int c = 0; c < 3; ++c)
            #pragma unroll
            for (int kx = 0; kx < 5; ++kx) {
              a1[c] = fmaf(row[kx], cw[c * 75 + ci * 25 + ky * 5 + kx], a1[c]);
              a2[c] = fmaf(row[kx], c2w[c * 75 + ci * 25 + ky * 5 + kx], a2[c]);
            }
        }
      int wy = ((py + 1) * 32 + 11) / 12 - (py * 32 + 11) / 12;
      int wx = ((px + 1) * 32 + 11) / 12 - (px * 32 + 11) / 12;
      float wgt = (float)(wy * wx);
      #pragma unroll
      for (int c = 0; c < 3; ++c) {
        ys0[c * 144 + p] = a1[c];
        u20[c * 144 + p] = a2[c];
        sc[c] += a1[c] * wgt;
        sq[c] += a1[c] * a1[c] * wgt;
      }
    }
    #pragma unroll
    for (int off = 32; off; off >>= 1)
      #pragma unroll
      for (int c = 0; c < 3; ++c) {
        sc[c] += __shfl_down(sc[c], off);
        sq[c] += __shfl_down(sq[c], off);
      }
    int wid = tid >> 6, lane = tid & 63;
    if (lane == 0)
      #pragma unroll
      for (int c = 0; c < 3; ++c) { redS[wid][c] = sc[c]; redQ[wid][c] = sq[c]; }
    __syncthreads();
    if (tid < 3) {
      int c = tid;
      float s1 = redS[0][c] + redS[1][c] + redS[2][c] + redS[3][c];
      float s2 = redQ[0][c] + redQ[1][c] + redQ[2][c] + redQ[3][c];
      float si_ = inp[0] + inp[1] + inp[2] + lnp[0] + lnp[1] + lnp[2];
      float sb = bnp[0] + bnp[1] + bnp[2];
      float2 ab = ab_from(s1, s2, s1, s2, 1024.f, 1.f, si_, sb, bnw[c], bnb[c], p1p[0]);
      AB[c] = ab.x; AB[3 + c] = ab.y;
    }
    __syncthreads();
  }
  {
    float P2a = p2p[0];
    for (int t = tid; t < 3072; t += 256) {
      int c = t >> 10, p = t & 1023;
      int oy = p >> 5, ox = p & 31;
      int si = ((oy * 12) >> 5) * 12 + ((ox * 12) >> 5);
      buf1[t] = AB[c] * ys0[c * 144 + si] + AB[3 + c] + P2a * u20[c * 144 + si];
    }
  }
  __syncthreads();
  // ---- conv1: (3,32,32) -> S=28, r=64 ----
  {
    const float* w1 = cw + 225;
    const float* w2 = c2w + 225;
    float sc[3] = {0, 0, 0}, sq[3] = {0, 0, 0};
    for (int p = tid; p < 784; p += 256) {
      int py = p / 28, px = p - py * 28;
      float a1[3], a2[3];
      #pragma unroll
      for (int c = 0; c < 3; ++c) { a1[c] = cb[3 + c]; a2[c] = c2b[3 + c]; }
      for (int ci = 0; ci < 3; ++ci)
        #pragma unroll
        for (int ky = 0; ky < 5; ++ky) {
          const float* row = &buf1[ci * 1024 + (py + ky) * 32 + px];
          #pragma unroll
          for (int c = 0; c < 3; ++c)
            #pragma unroll
            for (int kx = 0; kx < 5; ++kx) {
              a1[c] = fmaf(row[kx], w1[c * 75 + ci * 25 + ky * 5 + kx], a1[c]);
              a2[c] = fmaf(row[kx], w2[c * 75 + ci * 25 + ky * 5 + kx], a2[c]);
            }
        }
      int wy = ((py + 1) * 64 + 27) / 28 - (py * 64 + 27) / 28;
      int wx = ((px + 1) * 64 + 27) / 28 - (px * 64 + 27) / 28;
      float wgt = (float)(wy * wx);
      #pragma unroll
      for (int c = 0; c < 3; ++c) {
        ys1[c * 784 + p] = a1[c];
        u21[c * 784 + p] = a2[c];
        sc[c] += a1[c] * wgt;
        sq[c] += a1[c] * a1[c] * wgt;
      }
    }
    #pragma unroll
    for (int off = 32; off; off >>= 1)
      #pragma unroll
      for (int c = 0; c < 3; ++c) {
        sc[c] += __shfl_down(sc[c], off);
        sq[c] += __shfl_down(sq[c], off);
      }
    int wid = tid >> 6, lane = tid & 63;
    __syncthreads();  // protect redS reuse
    if (lane == 0)
      #pragma unroll
      for (int c = 0; c < 3; ++c) { redS[wid][c] = sc[c]; redQ[wid][c] = sq[c]; }
    __syncthreads();
    if (tid < 3) {
      int c = tid;
      float s1 = redS[0][c] + redS[1][c] + redS[2][c] + redS[3][c];
      float s2 = redQ[0][c] + redQ[1][c] + redQ[2][c] + redQ[3][c];
      float si_ = inp[3] + inp[4] + inp[5] + lnp[3] + lnp[4] + lnp[5];
      float sb = bnp[3] + bnp[4] + bnp[5];
      float2 ab = ab_from(s1, s2, s1, s2, 4096.f, 1.f, si_, sb, bnw[3 + c], bnb[3 + c], p1p[1]);
      AB[c] = ab.x; AB[3 + c] = ab.y;
    }
    __syncthreads();
  }
  {
    float P2b = p2p[1];
    for (int t = tid; t < 12288; t += 256) {
      int c = t >> 12, p = t & 4095;
      int oy = p >> 6, ox = p & 63;
      int si = ((oy * 28) >> 6) * 28 + ((ox * 28) >> 6);
      nb0[t] = AB[c] * ys1[c * 784 + si] + AB[3 + c] + P2b * u21[c * 784 + si];
    }
  }
}

// ---- attention HW=1024, pass 1 (fused y2+QKV recompute) ----
__global__ __launch_bounds__(256) void attn_rows_f(
    const float2* __restrict__ yu, const float* __restrict__ sums,
    const float* __restrict__ inp, const float* __restrict__ lnp,
    const float* __restrict__ bnp, const float* __restrict__ bnw,
    const float* __restrict__ bnb, const float* __restrict__ p1p,
    const float* __restrict__ p2p,
    const float* __restrict__ qw, const float* __restrict__ qb,
    const float* __restrict__ kw, const float* __restrict__ kb,
    float* __restrict__ Mp, float* __restrict__ Lp, int S) {
  __shared__ float pA[3], pB[3], pP2v;
  __shared__ float y2s[768], qs[768];
  int bid = blockIdx.x;
  int np = bid & 3; bid >>= 2;
  int mc = bid & 3;
  int b = bid >> 2;
  compute_AB(sums, b, 32, 1024.f, inp, lnp, bnp, bnw, bnb, p1p, p2p, pA, pB, &pP2v);
  size_t ybase = (size_t)b * 3 * S * S;
  for (int t = threadIdx.x; t < 768; t += 256) {
    int c = t >> 8, j = t & 255;
    int n = (np << 8) + j;
    int oy = n >> 5, ox = n & 31;
    int si = ((oy * S) >> 5) * S + ((ox * S) >> 5);
    float2 v = yu[ybase + c * S * S + si];
    y2s[t] = pA[c] * v.x + pB[c] + pP2v * v.y;
  }
  __syncthreads();
  for (int t = threadIdx.x; t < 768; t += 256) {
    int o = t >> 8, j = t & 255;
    qs[t] = qb[o] + qw[o * 3] * y2s[j] + qw[o * 3 + 1] * y2s[256 + j] +
            qw[o * 3 + 2] * y2s[512 + j];
  }
  __syncthreads();
  int m = (mc << 8) + threadIdx.x;
  int oy = m >> 5, ox = m & 31;
  int si = ((oy * S) >> 5) * S + ((ox * S) >> 5);
  float ym[3];
  #pragma unroll
  for (int c = 0; c < 3; ++c) {
    float2 v = yu[ybase + c * S * S + si];
    ym[c] = pA[c] * v.x + pB[c] + pP2v * v.y;
  }
  float k0 = (kb[0] + kw[0] * ym[0] + kw[1] * ym[1] + kw[2] * ym[2]) * LOG2E;
  float k1 = (kb[1] + kw[3] * ym[0] + kw[4] * ym[1] + kw[5] * ym[2]) * LOG2E;
  float k2 = (kb[2] + kw[6] * ym[0] + kw[7] * ym[1] + kw[8] * ym[2]) * LOG2E;
  float mr = -1e30f;
  for (int j = 0; j < 256; ++j) {
    float s = k0 * qs[j] + k1 * qs[256 + j] + k2 * qs[512 + j];
    mr = fmaxf(mr, s);
  }
  float l = 0.f;
  for (int j = 0; j < 256; ++j) {
    float s = k0 * qs[j] + k1 * qs[256 + j] + k2 * qs[512 + j];
    l += exp2f(s - mr);
  }
  int idx = (b * 4 + np) * 1024 + m;
  Mp[idx] = mr;
  Lp[idx] = l;
}

// ---- attention HW=1024, pass 2 (fused y2+QKV recompute, atomic out) ----
__global__ __launch_bounds__(256) void attn_out_f(
    const float2* __restrict__ yu, const float* __restrict__ sums,
    const float* __restrict__ inp, const float* __restrict__ lnp,
    const float* __restrict__ bnp, const float* __restrict__ bnw,
    const float* __restrict__ bnb, const float* __restrict__ p1p,
    const float* __restrict__ p2p,
    const float* __restrict__ qw, const float* __restrict__ qb,
    const float* __restrict__ kw, const float* __restrict__ kb,
    const float* __restrict__ vw, const float* __restrict__ vb,
    const float* __restrict__ Mp, const float* __restrict__ Lp,
    float* __restrict__ aout, int S) {
  __shared__ float pA[3], pB[3], pP2v;
  __shared__ float ym[768], ks[768], vs[768], Ms[256], Ls[256];
  int bid = blockIdx.x;
  int mp = bid & 3; bid >>= 2;
  int nc = bid & 3;
  int b = bid >> 2;
  compute_AB(sums, b, 32, 1024.f, inp, lnp, bnp, bnw, bnb, p1p, p2p, pA, pB, &pP2v);
  size_t ybase = (size_t)b * 3 * S * S;
  for (int t = threadIdx.x; t < 768; t += 256) {
    int c = t >> 8, j = t & 255;
    int m = (mp << 8) + j;
    int oy = m >> 5, ox = m & 31;
    int si = ((oy * S) >> 5) * S + ((ox * S) >> 5);
    float2 v = yu[ybase + c * S * S + si];
    ym[t] = pA[c] * v.x + pB[c] + pP2v * v.y;
  }
  __syncthreads();
  for (int t = threadIdx.x; t < 768; t += 256) {
    int o = t >> 8, j = t & 255;
    float y0 = ym[j], y1 = ym[256 + j], y2v = ym[512 + j];
    ks[t] = (kb[o] + kw[o * 3] * y0 + kw[o * 3 + 1] * y1 + kw[o * 3 + 2] * y2v) * LOG2E;
    vs[t] = vb[o] + vw[o * 3] * y0 + vw[o * 3 + 1] * y1 + vw[o * 3 + 2] * y2v;
  }
  {
    int t = threadIdx.x;
    int m = (mp << 8) + t;
    float M0 = Mp[(b * 4 + 0) * 1024 + m], M1 = Mp[(b * 4 + 1) * 1024 + m];
    float M2 = Mp[(b * 4 + 2) * 1024 + m], M3 = Mp[(b * 4 + 3) * 1024 + m];
    float L0 = Lp[(b * 4 + 0) * 1024 + m], L1 = Lp[(b * 4 + 1) * 1024 + m];
    float L2 = Lp[(b * 4 + 2) * 1024 + m], L3 = Lp[(b * 4 + 3) * 1024 + m];
    float MM = fmaxf(fmaxf(M0, M1), fmaxf(M2, M3));
    float LL = L0 * exp2f(M0 - MM) + L1 * exp2f(M1 - MM) +
               L2 * exp2f(M2 - MM) + L3 * exp2f(M3 - MM);
    Ms[t] = MM;
    Ls[t] = 1.0f / LL;
  }
  __syncthreads();
  int n = (nc << 8) + threadIdx.x;
  int oy = n >> 5, ox = n & 31;
  int si = ((oy * S) >> 5) * S + ((ox * S) >> 5);
  float yn[3];
  #pragma unroll
  for (int c = 0; c < 3; ++c) {
    float2 v = yu[ybase + c * S * S + si];
    yn[c] = pA[c] * v.x + pB[c] + pP2v * v.y;
  }
  float q0 = qb[0] + qw[0] * yn[0] + qw[1] * yn[1] + qw[2] * yn[2];
  float q1 = qb[1] + qw[3] * yn[0] + qw[4] * yn[1] + qw[5] * yn[2];
  float q2 = qb[2] + qw[6] * yn[0] + qw[7] * yn[1] + qw[8] * yn[2];
  float a0 = 0.f, a1 = 0.f, a2 = 0.f;
  for (int j = 0; j < 256; ++j) {
    float s = ks[j] * q0 + ks[256 + j] * q1 + ks[512 + j] * q2;
    float w = exp2f(s - Ms[j]) * Ls[j];
    a0 = fmaf(vs[j], w, a0);
    a1 = fmaf(vs[256 + j], w, a1);
    a2 = fmaf(vs[512 + j], w, a2);
  }
  if (mp == 0) { a0 += yn[0]; a1 += yn[1]; a2 += yn[2]; }
  size_t o0 = (size_t)b * 3 * 1024 + n;
  atomicAdd(&aout[o0], a0);
  atomicAdd(&aout[o0 + 1024], a1);
  atomicAdd(&aout[o0 + 2048], a2);
}

// ---- attention HW=256, fully fused (y2+QKV+softmax+out+residual) ----
__global__ __launch_bounds__(256) void attn256_f(
    const float2* __restrict__ yu, const float* __restrict__ sums,
    const float* __restrict__ inp, const float* __restrict__ lnp,
    const float* __restrict__ bnp, const float* __restrict__ bnw,
    const float* __restrict__ bnb, const float* __restrict__ p1p,
    const float* __restrict__ p2p,
    const float* __restrict__ qw, const float* __restrict__ qb,
    const float* __restrict__ kw, const float* __restrict__ kb,
    const float* __restrict__ vw, const float* __restrict__ vb,
    float* __restrict__ aout, int S) {
  __shared__ float pA[3], pB[3], pP2v;
  __shared__ float y2s[768], qs[768], ks[768], vs[768], Ms[256], Ls[256];
  int b = blockIdx.x;
  compute_AB(sums, b, 32, 256.f, inp, lnp, bnp, bnw, bnb, p1p, p2p, pA, pB, &pP2v);
  size_t ybase = (size_t)b * 3 * S * S;
  for (int t = threadIdx.x; t < 768; t += 256) {
    int c = t >> 8, p = t & 255;
    int oy = p >> 4, ox = p & 15;
    int si = ((oy * S) >> 4) * S + ((ox * S) >> 4);
    float2 v = yu[ybase + c * S * S + si];
    y2s[t] = pA[c] * v.x + pB[c] + pP2v * v.y;
  }
  __syncthreads();
  for (int t = threadIdx.x; t < 768; t += 256) {
    int o = t >> 8, p = t & 255;
    float y0 = y2s[p], y1 = y2s[256 + p], y2v = y2s[512 + p];
    qs[t] = qb[o] + qw[o * 3] * y0 + qw[o * 3 + 1] * y1 + qw[o * 3 + 2] * y2v;
    ks[t] = (kb[o] + kw[o * 3] * y0 + kw[o * 3 + 1] * y1 + kw[o * 3 + 2] * y2v) * LOG2E;
    vs[t] = vb[o] + vw[o * 3] * y0 + vw[o * 3 + 1] * y1 + vw[o * 3 + 2] * y2v;
  }
  __syncthreads();
  {
    int m = threadIdx.x;
    float kx = ks[m], ky = ks[256 + m], kz = ks[512 + m];
    float mr = -1e30f;
    for (int j = 0; j < 256; ++j) {
      float s = kx * qs[j] + ky * qs[256 + j] + kz * qs[512 + j];
      mr = fmaxf(mr, s);
    }
    float l = 0.f;
    for (int j = 0; j < 256; ++j) {
      float s = kx * qs[j] + ky * qs[256 + j] + kz * qs[512 + j];
      l += exp2f(s - mr);
    }
    Ms[m] = mr;
    Ls[m] = 1.0f / l;
  }
  __syncthreads();
  int n = threadIdx.x;
  float q0 = qs[n], q1 = qs[256 + n], q2 = qs[512 + n];
  float a0 = 0.f, a1 = 0.f, a2 = 0.f;
  for (int j = 0; j < 256; ++j) {
    float s = ks[j] * q0 + ks[256 + j] * q1 + ks[512 + j] * q2;
    float w = exp2f(s - Ms[j]) * Ls[j];
    a0 = fmaf(vs[j], w, a0);
    a1 = fmaf(vs[256 + j], w, a1);
    a2 = fmaf(vs[512 + j], w, a2);
  }
  size_t o0 = (size_t)b * 768 + n;
  aout[o0] = a0 + y2s[n];
  aout[o0 + 256] = a1 + y2s[256 + n];
  aout[o0 + 512] = a2 + y2s[512 + n];
}

// ---- final: affine + p2*u2 + tanh -> out ----
__global__ __launch_bounds__(256) void elem_final(
    const float2* __restrict__ yu, const float* __restrict__ sums,
    const float* __restrict__ inp, const float* __restrict__ lnp,
    const float* __restrict__ bnp, const float* __restrict__ bnw,
    const float* __restrict__ bnb, const float* __restrict__ p1p,
    const float* __restrict__ p2p, float* __restrict__ out, int S) {
  __shared__ float pA[3], pB[3], pP2v;
  int n = blockIdx.x >> 8;
  int p = ((blockIdx.x & 255) << 8) + threadIdx.x;
  compute_AB(sums, n, 32, 65536.f, inp, lnp, bnp, bnw, bnb, p1p, p2p, pA, pB, &pP2v);
  int oy = p >> 8, ox = p & 255;
  int si = ((oy * S) >> 8) * S + ((ox * S) >> 8);
  size_t ybase = (size_t)n * 3 * S * S;
  #pragma unroll
  for (int c = 0; c < 3; ++c) {
    float2 v = yu[ybase + c * S * S + si];
    out[((size_t)(n * 3 + c) << 16) + p] = tanhf(pA[c] * v.x + pB[c] + pP2v * v.y);
  }
}

#define NPX nullptr, nullptr, nullptr, nullptr, nullptr, nullptr, nullptr, \
            nullptr, nullptr, 0, 0, 0

extern "C" void kernel_launch(void* const* d_in, const int* in_sizes, int n_in,
                              void* d_out, int out_size, void* d_ws, size_t ws_size,
                              hipStream_t stream) {
  const float* x       = (const float*)d_in[0];
  const float* noise_z = (const float*)d_in[1];
  const float* lin_w   = (const float*)d_in[2];
  const float* lin_b   = (const float*)d_in[3];
  const float* conv_w  = (const float*)d_in[4];
  const float* conv_b  = (const float*)d_in[5];
  const float* conv2_w = (const float*)d_in[6];
  const float* conv2_b = (const float*)d_in[7];
  const float* q_w     = (const float*)d_in[8];
  const float* q_b     = (const float*)d_in[9];
  const float* k_w     = (const float*)d_in[10];
  const float* k_b     = (const float*)d_in[11];
  const float* v_w     = (const float*)d_in[12];
  const float* v_b     = (const float*)d_in[13];
  const float* in_p    = (const float*)d_in[14];
  const float* ln_p    = (const float*)d_in[15];
  const float* bn_p    = (const float*)d_in[16];
  const float* bn_w    = (const float*)d_in[17];
  const float* bn_b    = (const float*)d_in[18];
  const float* p1      = (const float*)d_in[19];
  const float* p2      = (const float*)d_in[20];
  float* out = (float*)d_out;

  float* ws = (float*)d_ws;
  size_t off = 0;
  auto alloc = [&](size_t nf) { float* p = ws + off; off += nf; return p; };
  float* SUMS = alloc(2304);
  float* A5   = alloc(98304);
  float* A8   = alloc(98304);
  float* A6   = alloc(24576);
  float* A7   = alloc(24576);
  float2* YU2 = (float2*)alloc(12192768);  // 252^2 * 96 * 2
  float2* PA  = (float2*)alloc(3145728);   // up to 128^2 * 96 * 2
  float2* PB  = (float2*)alloc(3145728);
  float* Mp   = alloc(131072);
  float* Lp   = alloc(131072);
  float* NB0  = alloc(12288);
  float* LIN  = alloc(768);

  hipMemsetAsync(SUMS, 0, (2304 + 98304 + 98304) * sizeof(float), stream);

  const float* nul = nullptr;
  const float2* nul2 = nullptr;

  // noise path: parallel linear, then small conv pipeline (blocks 0,1) -> NB0
  linear_wave<<<192, 256, 0, stream>>>(noise_z, lin_w, lin_b, LIN);
  noise_rest<<<1, 256, 0, stream>>>(LIN, conv_w, conv_b, conv2_w, conv2_b,
      in_p, ln_p, bn_p, bn_w, bn_b, p1, p2, NB0);

  // conv2: x -> YU2 (S=252, r=256)
  conv_up_t<false><<<2048, 256, 0, stream>>>(x, nul2, YU2, conv_w + 450,
      conv_b + 6, conv2_w + 450, conv2_b + 6, SUMS + 384, 256, 252, 256, 4, 16,
      NPX);
  // conv3: fused(b2) YU2 -> PA (S=128); prev Sp=252, logrp=8
  conv_dn_t<true><<<2048, 256, 0, stream>>>(nul, YU2, PA, conv_w + 675,
      conv_b + 9, conv2_w + 675, conv2_b + 9, SUMS + 576, 256, 128, 252, 7, 4, 16,
      SUMS + 384, in_p + 6, ln_p + 6, bn_p + 6, bn_w + 6, bn_b + 6, p1 + 2,
      p2 + 2, nul, 32, 252, 8);
  // conv4: fused(b3) PA -> PB (S=64); prev Sp=128, logrp=7 (identity)
  conv_dn_t<true><<<512, 256, 0, stream>>>(nul, PA, PB, conv_w + 900,
      conv_b + 12, conv2_w + 900, conv2_b + 12, SUMS + 768, 128, 64, 124, 6, 2, 8,
      SUMS + 576, in_p + 9, ln_p + 9, bn_p + 9, bn_w + 9, bn_b + 9, p1 + 3,
      p2 + 3, nul, 32, 128, 7);
  // conv5: fused(b4)+noise PB -> PA (S=32); prev Sp=64, logrp=6 (identity)
  conv_dn_t<true><<<128, 256, 0, stream>>>(nul, PB, PA, conv_w + 1125,
      conv_b + 15, conv2_w + 1125, conv2_b + 15, SUMS + 960, 64, 32, 60, 5, 1, 4,
      SUMS + 768, in_p + 12, ln_p + 12, bn_p + 12, bn_w + 12, bn_b + 12, p1 + 4,
      p2 + 4, NB0, 32, 64, 6);
  // attn5 (HW=1024) on PA (S=32)
  attn_rows_f<<<512, 256, 0, stream>>>(PA, SUMS + 960, in_p + 15, ln_p + 15,
      bn_p + 15, bn_w + 15, bn_b + 15, p1 + 5, p2 + 5,
      q_w + 45, q_b + 15, k_w + 45, k_b + 15, Mp, Lp, 32);
  attn_out_f<<<512, 256, 0, stream>>>(PA, SUMS + 960, in_p + 15, ln_p + 15,
      bn_p + 15, bn_w + 15, bn_b + 15, p1 + 5, p2 + 5,
      q_w + 45, q_b + 15, k_w + 45, k_b + 15, v_w + 45, v_b + 15, Mp, Lp, A5, 32);
  // conv6: direct A5 -> PB (S=16)
  conv_dn_t<false><<<64, 256, 0, stream>>>(A5, nul2, PB, conv_w + 1350,
      conv_b + 18, conv2_w + 1350, conv2_b + 18, SUMS + 1152, 32, 16, 28, 4, 1, 2,
      NPX);
  // attn6 (HW=256) on PB (S=16)
  attn256_f<<<32, 256, 0, stream>>>(PB, SUMS + 1152, in_p + 18, ln_p + 18,
      bn_p + 18, bn_w + 18, bn_b + 18, p1 + 6, p2 + 6,
      q_w + 54, q_b + 18, k_w + 54, k_b + 18, v_w + 54, v_b + 18, A6, 16);
  // conv7: direct A6 -> PA (S=12, r=16)
  conv_src_f2<<<32, 256, 0, stream>>>(A6, PA, conv_w + 1575, conv_b + 21,
      conv2_w + 1575, conv2_b + 21, SUMS + 1344, 32, 16, 12, 12, 16);
  // attn7 (HW=256) on PA (S=12)
  attn256_f<<<32, 256, 0, stream>>>(PA, SUMS + 1344, in_p + 21, ln_p + 21,
      bn_p + 21, bn_w + 21, bn_b + 21, p1 + 7, p2 + 7,
      q_w + 63, q_b + 21, k_w + 63, k_b + 21, v_w + 63, v_b + 21, A7, 12);
  // conv8: direct A7 -> PB (S=12, r=32)
  conv_src_f2<<<32, 256, 0, stream>>>(A7, PB, conv_w + 1800, conv_b + 24,
      conv2_w + 1800, conv2_b + 24, SUMS + 1536, 32, 16, 12, 12, 32);
  // attn8 (HW=1024) on PB (S=12)
  attn_rows_f<<<512, 256, 0, stream>>>(PB, SUMS + 1536, in_p + 24, ln_p + 24,
      bn_p + 24, bn_w + 24, bn_b + 24, p1 + 8, p2 + 8,
      q_w + 72, q_b + 24, k_w + 72, k_b + 24, Mp, Lp, 12);
  attn_out_f<<<512, 256, 0, stream>>>(PB, SUMS + 1536, in_p + 24, ln_p + 24,
      bn_p + 24, bn_w + 24, bn_b + 24, p1 + 8, p2 + 8,
      q_w + 72, q_b + 24, k_w + 72, k_b + 24, v_w + 72, v_b + 24, Mp, Lp, A8, 12);
  // conv9: direct A8 -> PA (S=28, r=64)
  conv_up_t<false><<<64, 256, 0, stream>>>(A8, nul2, PA, conv_w + 2025,
      conv_b + 27, conv2_w + 2025, conv2_b + 27, SUMS + 1728, 32, 28, 64, 1, 2,
      NPX);
  // conv10: fused(b9) PA -> PB (S=60); prev Sp=28, logrp=6
  conv_up_t<true><<<128, 256, 0, stream>>>(nul, PA, PB, conv_w + 2250,
      conv_b + 30, conv2_w + 2250, conv2_b + 30, SUMS + 1920, 64, 60, 128, 1, 4,
      SUMS + 1728, in_p + 27, ln_p + 27, bn_p + 27, bn_w + 27, bn_b + 27,
      p1 + 9, p2 + 9, nul, 32, 28, 6);
  // conv11: fused(b10) PB -> YU2 (S=124); prev Sp=60, logrp=7
  conv_up_t<true><<<512, 256, 0, stream>>>(nul, PB, YU2, conv_w + 2475,
      conv_b + 33, conv2_w + 2475, conv2_b + 33, SUMS + 2112, 128, 124, 256, 2, 8,
      SUMS + 1920, in_p + 30, ln_p + 30, bn_p + 30, bn_w + 30, bn_b + 30,
      p1 + 10, p2 + 10, nul, 32, 60, 7);
  // final: tanh -> out
  elem_final<<<8192, 256, 0, stream>>>(YU2, SUMS + 2112, in_p + 33, ln_p + 33,
      bn_p + 33, bn_w + 33, bn_b + 33, p1 + 11, p2 + 11, out, 124);
}

// Round 8
// 547.288 us; speedup vs baseline: 1.6117x; 1.0054x over previous
//
#include <hip/hip_runtime.h>
#include <math.h>

#define EPS 1e-5f
#define LOG2E 1.44269504088896340736f

// ---- shared affine-fold helper: A,B from sums (instance+batch norm + p1) ----
__device__ __forceinline__ float2 ab_from(float s1, float s2, float bs, float bs2,
    float hw, float Nf, float si_, float sb, float bnw_c, float bnb_c, float p1v) {
  float inv = 1.0f / hw;
  float mi = s1 * inv, vi = s2 * inv - mi * mi;
  float ri = rsqrtf(vi + EPS);
  float invb = 1.0f / (Nf * hw);
  float mb = bs * invb, vb = bs2 * invb - mb * mb;
  float rb = rsqrtf(vb + EPS);
  float A = 1.0f + si_ * ri + sb * rb * bnw_c;
  float B = -(si_ * ri * mi + sb * rb * bnw_c * mb) + sb * bnb_c;
  return make_float2(A * p1v, B * p1v);
}

__device__ __forceinline__ void compute_AB(
    const float* __restrict__ sums, int n, int N, float hw,
    const float* __restrict__ inp, const float* __restrict__ lnp,
    const float* __restrict__ bnp, const float* __restrict__ bnw,
    const float* __restrict__ bnb, const float* __restrict__ p1p,
    const float* __restrict__ p2p, float* pA, float* pB, float* pP2) {
  if (threadIdx.x == 0) *pP2 = p2p[0];
  if (threadIdx.x < 3) {
    int c = threadIdx.x;
    float si_ = inp[0] + inp[1] + inp[2] + lnp[0] + lnp[1] + lnp[2];
    float sb = bnp[0] + bnp[1] + bnp[2];
    float s1 = sums[2 * (n * 3 + c)], s2 = sums[2 * (n * 3 + c) + 1];
    float bs = 0.f, bs2 = 0.f;
    for (int nn = 0; nn < N; ++nn) {
      bs += sums[2 * (nn * 3 + c)];
      bs2 += sums[2 * (nn * 3 + c) + 1];
    }
    float2 ab = ab_from(s1, s2, bs, bs2, hw, (float)N, si_, sb, bnw[c], bnb[c], p1p[0]);
    pA[c] = ab.x;
    pB[c] = ab.y;
  }
  __syncthreads();
}

// stats block-reduce (all threads must participate)
#define STATS_REDUCE_ATOMIC(scv, sqv, sumsp, nvar)                            \
  {                                                                           \
    _Pragma("unroll")                                                         \
    for (int off = 32; off; off >>= 1) {                                      \
      _Pragma("unroll")                                                       \
      for (int c = 0; c < 3; ++c) {                                           \
        scv[c] += __shfl_down(scv[c], off);                                   \
        sqv[c] += __shfl_down(sqv[c], off);                                   \
      }                                                                       \
    }                                                                         \
    __shared__ float redS[4][3], redQ[4][3];                                  \
    int wid = threadIdx.x >> 6, lane = threadIdx.x & 63;                      \
    if (lane == 0) {                                                          \
      _Pragma("unroll")                                                       \
      for (int c = 0; c < 3; ++c) { redS[wid][c] = scv[c]; redQ[wid][c] = sqv[c]; } \
    }                                                                         \
    __syncthreads();                                                          \
    if (threadIdx.x < 3) {                                                    \
      int c = threadIdx.x;                                                    \
      atomicAdd(&sumsp[2 * ((nvar) * 3 + c)],                                 \
                redS[0][c] + redS[1][c] + redS[2][c] + redS[3][c]);           \
      atomicAdd(&sumsp[2 * ((nvar) * 3 + c) + 1],                             \
                redQ[0][c] + redQ[1][c] + redQ[2][c] + redQ[3][c]);           \
    }                                                                         \
  }

// ---- LDS-tiled upsample conv (S==hc): 64x16 tile, TX=4, float2 out ----
template <bool FUSED>
__global__ __launch_bounds__(256) void conv_up_t(
    const float* __restrict__ in, const float2* __restrict__ pyu,
    float2* __restrict__ yu,
    const float* __restrict__ w1, const float* __restrict__ b1,
    const float* __restrict__ w2, const float* __restrict__ b2,
    float* __restrict__ sums, int Hin, int S, int r, int tilesX, int tilesY,
    const float* __restrict__ psums,
    const float* __restrict__ pinp, const float* __restrict__ plnp,
    const float* __restrict__ pbnp, const float* __restrict__ pbnw,
    const float* __restrict__ pbnb, const float* __restrict__ pp1,
    const float* __restrict__ pp2, const float* __restrict__ pnoise,
    int pN, int Sp, int logrp) {
  const int TW = 64, TH = 16, IW = 68, IH = 20;
  __shared__ float lin[3 * IH * IW];
  __shared__ float pA[3], pB[3], pP2v;
  int tpi = tilesX * tilesY;
  int n = blockIdx.x / tpi;
  int trem = blockIdx.x - n * tpi;
  int tyB = trem / tilesX, txB = trem - tyB * tilesX;
  int px0 = txB * TW, py0 = tyB * TH;
  const float* inb = in + (size_t)n * 3 * Hin * Hin;
  if (FUSED) {
    compute_AB(psums, n, pN, (float)(Hin * Hin), pinp, plnp, pbnp, pbnw, pbnb,
               pp1, pp2, pA, pB, &pP2v);
    size_t pbase = (size_t)n * 3 * Sp * Sp;
    for (int t = threadIdx.x; t < 3 * IH * IW; t += 256) {
      int cc = t / (IH * IW);
      int rem = t - cc * IH * IW;
      int rr = rem / IW, col = rem - rr * IW;
      int gy = py0 + rr; gy = gy < Hin ? gy : Hin - 1;
      int gx = px0 + col; gx = gx < Hin ? gx : Hin - 1;
      int si = ((gy * Sp) >> logrp) * Sp + ((gx * Sp) >> logrp);
      float2 v = pyu[pbase + cc * Sp * Sp + si];
      float val = pA[cc] * v.x + pB[cc] + pP2v * v.y;
      if (pnoise) val += pnoise[((size_t)cc * Hin + gy) * Hin + gx];
      lin[t] = val;
    }
  } else {
    if (px0 + IW <= Hin && py0 + IH <= Hin) {
      for (int t = threadIdx.x; t < 3 * IH * 17; t += 256) {
        int cc = t / (IH * 17);
        int rem = t - cc * (IH * 17);
        int rr = rem / 17, j = rem - rr * 17;
        float4 v = *reinterpret_cast<const float4*>(
            inb + ((size_t)cc * Hin + py0 + rr) * Hin + px0 + 4 * j);
        *reinterpret_cast<float4*>(&lin[(cc * IH + rr) * IW + 4 * j]) = v;
      }
    } else {
      for (int t = threadIdx.x; t < 3 * IH * IW; t += 256) {
        int cc = t / (IH * IW);
        int rem = t - cc * IH * IW;
        int rr = rem / IW, col = rem - rr * IW;
        int gy = py0 + rr; gy = gy < Hin ? gy : Hin - 1;
        int gx = px0 + col; gx = gx < Hin ? gx : Hin - 1;
        lin[t] = inb[((size_t)cc * Hin + gy) * Hin + gx];
      }
    }
  }
  __syncthreads();
  int tx = threadIdx.x & 15, ty = threadIdx.x >> 4;
  int lx0 = tx * 4;
  int px = px0 + lx0, py = py0 + ty;
  float a1[3][4], a2[3][4];
  #pragma unroll
  for (int c = 0; c < 3; ++c) {
    float bb1 = b1[c], bb2 = b2[c];
    #pragma unroll
    for (int x = 0; x < 4; ++x) { a1[c][x] = bb1; a2[c][x] = bb2; }
  }
  #pragma unroll
  for (int ci = 0; ci < 3; ++ci) {
    const float* lrow = lin + ci * IH * IW + ty * IW + lx0;
    const float* wp1 = w1 + ci * 25;
    const float* wp2 = w2 + ci * 25;
    #pragma unroll
    for (int ky = 0; ky < 5; ++ky) {
      float v[8];
      #pragma unroll
      for (int j = 0; j < 8; ++j) v[j] = lrow[ky * IW + j];
      #pragma unroll
      for (int c = 0; c < 3; ++c) {
        #pragma unroll
        for (int kx = 0; kx < 5; ++kx) {
          float wa = wp1[c * 75 + ky * 5 + kx];
          float wb = wp2[c * 75 + ky * 5 + kx];
          #pragma unroll
          for (int x = 0; x < 4; ++x) {
            a1[c][x] = fmaf(v[kx + x], wa, a1[c][x]);
            a2[c][x] = fmaf(v[kx + x], wb, a2[c][x]);
          }
        }
      }
    }
  }
  float sc[3] = {0.f, 0.f, 0.f}, sq[3] = {0.f, 0.f, 0.f};
  bool valid = (py < S) && (px < S);
  if (valid) {
    int hc = S;
    float wy = (float)(((py + 1) * r + hc - 1) / hc - (py * r + hc - 1) / hc);
    float wx[4];
    #pragma unroll
    for (int x = 0; x < 4; ++x) {
      int pxx = px + x;
      wx[x] = (float)(((pxx + 1) * r + hc - 1) / hc - (pxx * r + hc - 1) / hc);
    }
    #pragma unroll
    for (int c = 0; c < 3; ++c) {
      size_t idx = ((size_t)(n * 3 + c) * S + py) * S + px;
      float2* yp = yu + idx;
      *reinterpret_cast<float4*>(yp) =
          make_float4(a1[c][0], a2[c][0], a1[c][1], a2[c][1]);
      *reinterpret_cast<float4*>(yp + 2) =
          make_float4(a1[c][2], a2[c][2], a1[c][3], a2[c][3]);
      #pragma unroll
      for (int x = 0; x < 4; ++x) {
        float wgt = wy * wx[x];
        sc[c] += a1[c][x] * wgt;
        sq[c] += a1[c][x] * a1[c][x] * wgt;
      }
    }
  }
  STATS_REDUCE_ATOMIC(sc, sq, sums, n)
}

// ---- LDS-tiled downsample conv (ratio<2.05): 32x8 tile, float2 out ----
// IDENT: prev-gather is identity (Sp==Hin, logrp==log2(Hin)) -> coalesced reads
template <bool FUSED, bool IDENT>
__global__ __launch_bounds__(256) void conv_dn_t(
    const float* __restrict__ in, const float2* __restrict__ pyu,
    float2* __restrict__ yu,
    const float* __restrict__ w1, const float* __restrict__ b1,
    const float* __restrict__ w2, const float* __restrict__ b2,
    float* __restrict__ sums, int Hin, int S, int hc, int logr,
    int tilesX, int tilesY,
    const float* __restrict__ psums,
    const float* __restrict__ pinp, const float* __restrict__ plnp,
    const float* __restrict__ pbnp, const float* __restrict__ pbnw,
    const float* __restrict__ pbnb, const float* __restrict__ pp1,
    const float* __restrict__ pp2, const float* __restrict__ pnoise,
    int pN, int Sp, int logrp) {
  const int TW = 32, TH = 8, IW = 68, IH = 20;
  __shared__ float lin[3 * IH * IW];
  __shared__ float pA[3], pB[3], pP2v;
  int tpi = tilesX * tilesY;
  int n = blockIdx.x / tpi;
  int trem = blockIdx.x - n * tpi;
  int tyB = trem / tilesX, txB = trem - tyB * tilesX;
  int px0 = txB * TW, py0 = tyB * TH;
  int sy0 = (py0 * hc) >> logr, sx0 = (px0 * hc) >> logr;
  const float* inb = in + (size_t)n * 3 * Hin * Hin;
  if (FUSED) {
    compute_AB(psums, n, pN, (float)(Hin * Hin), pinp, plnp, pbnp, pbnw, pbnb,
               pp1, pp2, pA, pB, &pP2v);
    size_t pbase = (size_t)n * 3 * Sp * Sp;
    for (int t = threadIdx.x; t < 3 * IH * IW; t += 256) {
      int cc = t / (IH * IW);
      int rem = t - cc * IH * IW;
      int rr = rem / IW, col = rem - rr * IW;
      int gy = sy0 + rr; gy = gy < Hin ? gy : Hin - 1;
      int gx = sx0 + col; gx = gx < Hin ? gx : Hin - 1;
      int si;
      if (IDENT) si = gy * Sp + gx;
      else si = ((gy * Sp) >> logrp) * Sp + ((gx * Sp) >> logrp);
      float2 v = pyu[pbase + cc * Sp * Sp + si];
      float val = pA[cc] * v.x + pB[cc] + pP2v * v.y;
      if (pnoise) val += pnoise[((size_t)cc * Hin + gy) * Hin + gx];
      lin[t] = val;
    }
  } else {
    for (int t = threadIdx.x; t < 3 * IH * IW; t += 256) {
      int cc = t / (IH * IW);
      int rem = t - cc * IH * IW;
      int rr = rem / IW, col = rem - rr * IW;
      int gy = sy0 + rr; gy = gy < Hin ? gy : Hin - 1;
      int gx = sx0 + col; gx = gx < Hin ? gx : Hin - 1;
      lin[t] = inb[((size_t)cc * Hin + gy) * Hin + gx];
    }
  }
  __syncthreads();
  int tx = threadIdx.x & 31, ty = threadIdx.x >> 5;
  int px = px0 + tx, py = py0 + ty;
  int sxl = ((px * hc) >> logr) - sx0;
  int syl = ((py * hc) >> logr) - sy0;
  float a1[3], a2[3];
  #pragma unroll
  for (int c = 0; c < 3; ++c) { a1[c] = b1[c]; a2[c] = b2[c]; }
  #pragma unroll
  for (int ci = 0; ci < 3; ++ci) {
    const float* lrow = lin + ci * IH * IW + syl * IW + sxl;
    const float* wp1 = w1 + ci * 25;
    const float* wp2 = w2 + ci * 25;
    #pragma unroll
    for (int ky = 0; ky < 5; ++ky) {
      float v[5];
      #pragma unroll
      for (int j = 0; j < 5; ++j) v[j] = lrow[ky * IW + j];
      #pragma unroll
      for (int c = 0; c < 3; ++c) {
        #pragma unroll
        for (int kx = 0; kx < 5; ++kx) {
          a1[c] = fmaf(v[kx], wp1[c * 75 + ky * 5 + kx], a1[c]);
          a2[c] = fmaf(v[kx], wp2[c * 75 + ky * 5 + kx], a2[c]);
        }
      }
    }
  }
  float sc[3] = {0.f, 0.f, 0.f}, sq[3] = {0.f, 0.f, 0.f};
  bool valid = (py < S) && (px < S);
  if (valid) {
    #pragma unroll
    for (int c = 0; c < 3; ++c) {
      size_t idx = ((size_t)(n * 3 + c) * S + py) * S + px;
      yu[idx] = make_float2(a1[c], a2[c]);
      sc[c] += a1[c];
      sq[c] += a1[c] * a1[c];
    }
  }
  STATS_REDUCE_ATOMIC(sc, sq, sums, n)
}

// ---- Linear 512->768: one wave per output row, coalesced float4 ----
__global__ __launch_bounds__(256) void linear_wave(
    const float* __restrict__ z, const float* __restrict__ w,
    const float* __restrict__ b, float* __restrict__ out) {
  int row = (blockIdx.x << 2) + (threadIdx.x >> 6);
  int lane = threadIdx.x & 63;
  const float4* wr = reinterpret_cast<const float4*>(w + (size_t)row * 512);
  const float4* zz = reinterpret_cast<const float4*>(z);
  float acc = 0.f;
  #pragma unroll
  for (int i = 0; i < 2; ++i) {
    float4 wv = wr[lane + 64 * i];
    float4 zv = zz[lane + 64 * i];
    acc += wv.x * zv.x + wv.y * zv.y + wv.z * zv.z + wv.w * zv.w;
  }
  #pragma unroll
  for (int off = 32; off; off >>= 1) acc += __shfl_down(acc, off);
  if (lane == 0) out[row] = acc + b[row];
}

// ---- noise conv path (blocks 0,1) in one block, L0 from global ----
__global__ __launch_bounds__(256) void noise_rest(
    const float* __restrict__ L0g,
    const float* __restrict__ cw, const float* __restrict__ cb,
    const float* __restrict__ c2w, const float* __restrict__ c2b,
    const float* __restrict__ inp, const float* __restrict__ lnp,
    const float* __restrict__ bnp, const float* __restrict__ bnw,
    const float* __restrict__ bnb, const float* __restrict__ p1p,
    const float* __restrict__ p2p, float* __restrict__ nb0) {
  __shared__ float L0[768];
  __shared__ float ys0[432], u20[432];
  __shared__ float buf1[3072];
  __shared__ float ys1[2352], u21[2352];
  __shared__ float redS[4][3], redQ[4][3];
  __shared__ float AB[6];
  int tid = threadIdx.x;
  for (int t = tid; t < 768; t += 256) L0[t] = L0g[t];
  __syncthreads();
  // ---- conv0: (3,16,16) -> S=12, r=32 ----
  {
    float sc[3] = {0, 0, 0}, sq[3] = {0, 0, 0};
    for (int p = tid; p < 144; p += 256) {
      int py = p / 12, px = p - py * 12;
      float a1[3], a2[3];
      #pragma unroll
      for (int c = 0; c < 3; ++c) { a1[c] = cb[c]; a2[c] = c2b[c]; }
      for (int ci = 0; ci < 3; ++ci)
        #pragma unroll
        for (int ky = 0; ky < 5; ++ky) {
          const float* row = &L0[ci * 256 + (py + ky) * 16 + px];
          #pragma unroll
          for (int c = 0; c < 3; ++c)
            #pragma unroll
            for (int kx = 0; kx < 5; ++kx) {
              a1[c] = fmaf(row[kx], cw[c * 75 + ci * 25 + ky * 5 + kx], a1[c]);
              a2[c] = fmaf(row[kx], c2w[c * 75 + ci * 25 + ky * 5 + kx], a2[c]);
            }
        }
      int wy = ((py + 1) * 32 + 11) / 12 - (py * 32 + 11) / 12;
      int wx = ((px + 1) * 32 + 11) / 12 - (px * 32 + 11) / 12;
      float wgt = (float)(wy * wx);
      #pragma unroll
      for (int c = 0; c < 3; ++c) {
        ys0[c * 144 + p] = a1[c];
        u20[c * 144 + p] = a2[c];
        sc[c] += a1[c] * wgt;
        sq[c] += a1[c] * a1[c] * wgt;
      }
    }
    #pragma unroll
    for (int off = 32; off; off >>= 1)
      #pragma unroll
      for (int c = 0; c < 3; ++c) {
        sc[c] += __shfl_down(sc[c], off);
        sq[c] += __shfl_down(sq[c], off);
      }
    int wid = tid >> 6, lane = tid & 63;
    if (lane == 0)
      #pragma unroll
      for (int c = 0; c < 3; ++c) { redS[wid][c] = sc[c]; redQ[wid][c] = sq[c]; }
    __syncthreads();
    if (tid < 3) {
      int c = tid;
      float s1 = redS[0][c] + redS[1][c] + redS[2][c] + redS[3][c];
      float s2 = redQ[0][c] + redQ[1][c] + redQ[2][c] + redQ[3][c];
      float si_ = inp[0] + inp[1] + inp[2] + lnp[0] + lnp[1] + lnp[2];
      float sb = bnp[0] + bnp[1] + bnp[2];
      float2 ab = ab_from(s1, s2, s1, s2, 1024.f, 1.f, si_, sb, bnw[c], bnb[c], p1p[0]);
      AB[c] = ab.x; AB[3 + c] = ab.y;
    }
    __syncthreads();
  }
  {
    float P2a = p2p[0];
    for (int t = tid; t < 3072; t += 256) {
      int c = t >> 10, p = t & 1023;
      int oy = p >> 5, ox = p & 31;
      int si = ((oy * 12) >> 5) * 12 + ((ox * 12) >> 5);
      buf1[t] = AB[c] * ys0[c * 144 + si] + AB[3 + c] + P2a * u20[c * 144 + si];
    }
  }
  __syncthreads();
  // ---- conv1: (3,32,32) -> S=28, r=64 ----
  {
    const float* w1 = cw + 225;
    const float* w2 = c2w + 225;
    float sc[3] = {0, 0, 0}, sq[3] = {0, 0, 0};
    for (int p = tid; p < 784; p += 256) {
      int py = p / 28, px = p - py * 28;
      float a1[3], a2[3];
      #pragma unroll
      for (int c = 0; c < 3; ++c) { a1[c] = cb[3 + c]; a2[c] = c2b[3 + c]; }
      for (int ci = 0; ci < 3; ++ci)
        #pragma unroll
        for (int ky = 0; ky < 5; ++ky) {
          const float* row = &buf1[ci * 1024 + (py + ky) * 32 + px];
          #pragma unroll
          for (int c = 0; c < 3; ++c)
            #pragma unroll
            for (int kx = 0; kx < 5; ++kx) {
              a1[c] = fmaf(row[kx], w1[c * 75 + ci * 25 + ky * 5 + kx], a1[c]);
              a2[c] = fmaf(row[kx], w2[c * 75 + ci * 25 + ky * 5 + kx], a2[c]);
            }
        }
      int wy = ((py + 1) * 64 + 27) / 28 - (py * 64 + 27) / 28;
      int wx = ((px + 1) * 64 + 27) / 28 - (px * 64 + 27) / 28;
      float wgt = (float)(wy * wx);
      #pragma unroll
      for (int c = 0; c < 3; ++c) {
        ys1[c * 784 + p] = a1[c];
        u21[c * 784 + p] = a2[c];
        sc[c] += a1[c] * wgt;
        sq[c] += a1[c] * a1[c] * wgt;
      }
    }
    #pragma unroll
    for (int off = 32; off; off >>= 1)
      #pragma unroll
      for (int c = 0; c < 3; ++c) {
        sc[c] += __shfl_down(sc[c], off);
        sq[c] += __shfl_down(sq[c], off);
      }
    int wid = tid >> 6, lane = tid & 63;
    __syncthreads();  // protect redS reuse
    if (lane == 0)
      #pragma unroll
      for (int c = 0; c < 3; ++c) { redS[wid][c] = sc[c]; redQ[wid][c] = sq[c]; }
    __syncthreads();
    if (tid < 3) {
      int c = tid;
      float s1 = redS[0][c] + redS[1][c] + redS[2][c] + redS[3][c];
      float s2 = redQ[0][c] + redQ[1][c] + redQ[2][c] + redQ[3][c];
      float si_ = inp[3] + inp[4] + inp[5] + lnp[3] + lnp[4] + lnp[5];
      float sb = bnp[3] + bnp[4] + bnp[5];
      float2 ab = ab_from(s1, s2, s1, s2, 4096.f, 1.f, si_, sb, bnw[3 + c], bnb[3 + c], p1p[1]);
      AB[c] = ab.x; AB[3 + c] = ab.y;
    }
    __syncthreads();
  }
  {
    float P2b = p2p[1];
    for (int t = tid; t < 12288; t += 256) {
      int c = t >> 12, p = t & 4095;
      int oy = p >> 6, ox = p & 63;
      int si = ((oy * 28) >> 6) * 28 + ((ox * 28) >> 6);
      nb0[t] = AB[c] * ys1[c * 784 + si] + AB[3 + c] + P2b * u21[c * 784 + si];
    }
  }
}

// ---- attention HW=1024, pass 1 (fused y2+QKV recompute) ----
__global__ __launch_bounds__(256) void attn_rows_f(
    const float2* __restrict__ yu, const float* __restrict__ sums,
    const float* __restrict__ inp, const float* __restrict__ lnp,
    const float* __restrict__ bnp, const float* __restrict__ bnw,
    const float* __restrict__ bnb, const float* __restrict__ p1p,
    const float* __restrict__ p2p,
    const float* __restrict__ qw, const float* __restrict__ qb,
    const float* __restrict__ kw, const float* __restrict__ kb,
    float* __restrict__ Mp, float* __restrict__ Lp, int S) {
  __shared__ float pA[3], pB[3], pP2v;
  __shared__ float y2s[768], qs[768];
  int bid = blockIdx.x;
  int np = bid & 3; bid >>= 2;
  int mc = bid & 3;
  int b = bid >> 2;
  compute_AB(sums, b, 32, 1024.f, inp, lnp, bnp, bnw, bnb, p1p, p2p, pA, pB, &pP2v);
  size_t ybase = (size_t)b * 3 * S * S;
  for (int t = threadIdx.x; t < 768; t += 256) {
    int c = t >> 8, j = t & 255;
    int n = (np << 8) + j;
    int oy = n >> 5, ox = n & 31;
    int si = ((oy * S) >> 5) * S + ((ox * S) >> 5);
    float2 v = yu[ybase + c * S * S + si];
    y2s[t] = pA[c] * v.x + pB[c] + pP2v * v.y;
  }
  __syncthreads();
  for (int t = threadIdx.x; t < 768; t += 256) {
    int o = t >> 8, j = t & 255;
    qs[t] = qb[o] + qw[o * 3] * y2s[j] + qw[o * 3 + 1] * y2s[256 + j] +
            qw[o * 3 + 2] * y2s[512 + j];
  }
  __syncthreads();
  int m = (mc << 8) + threadIdx.x;
  int oy = m >> 5, ox = m & 31;
  int si = ((oy * S) >> 5) * S + ((ox * S) >> 5);
  float ym[3];
  #pragma unroll
  for (int c = 0; c < 3; ++c) {
    float2 v = yu[ybase + c * S * S + si];
    ym[c] = pA[c] * v.x + pB[c] + pP2v * v.y;
  }
  float k0 = (kb[0] + kw[0] * ym[0] + kw[1] * ym[1] + kw[2] * ym[2]) * LOG2E;
  float k1 = (kb[1] + kw[3] * ym[0] + kw[4] * ym[1] + kw[5] * ym[2]) * LOG2E;
  float k2 = (kb[2] + kw[6] * ym[0] + kw[7] * ym[1] + kw[8] * ym[2]) * LOG2E;
  float mr = -1e30f;
  for (int j = 0; j < 256; ++j) {
    float s = k0 * qs[j] + k1 * qs[256 + j] + k2 * qs[512 + j];
    mr = fmaxf(mr, s);
  }
  float l = 0.f;
  for (int j = 0; j < 256; ++j) {
    float s = k0 * qs[j] + k1 * qs[256 + j] + k2 * qs[512 + j];
    l += exp2f(s - mr);
  }
  int idx = (b * 4 + np) * 1024 + m;
  Mp[idx] = mr;
  Lp[idx] = l;
}

// ---- attention HW=1024, pass 2 (fused y2+QKV recompute, atomic out) ----
__global__ __launch_bounds__(256) void attn_out_f(
    const float2* __restrict__ yu, const float* __restrict__ sums,
    const float* __restrict__ inp, const float* __restrict__ lnp,
    const float* __restrict__ bnp, const float* __restrict__ bnw,
    const float* __restrict__ bnb, const float* __restrict__ p1p,
    const float* __restrict__ p2p,
    const float* __restrict__ qw, const float* __restrict__ qb,
    const float* __restrict__ kw, const float* __restrict__ kb,
    const float* __restrict__ vw, const float* __restrict__ vb,
    const float* __restrict__ Mp, const float* __restrict__ Lp,
    float* __restrict__ aout, int S) {
  __shared__ float pA[3], pB[3], pP2v;
  __shared__ float ym[768], ks[768], vs[768], Ms[256], Ls[256];
  int bid = blockIdx.x;
  int mp = bid & 3; bid >>= 2;
  int nc = bid & 3;
  int b = bid >> 2;
  compute_AB(sums, b, 32, 1024.f, inp, lnp, bnp, bnw, bnb, p1p, p2p, pA, pB, &pP2v);
  size_t ybase = (size_t)b * 3 * S * S;
  for (int t = threadIdx.x; t < 768; t += 256) {
    int c = t >> 8, j = t & 255;
    int m = (mp << 8) + j;
    int oy = m >> 5, ox = m & 31;
    int si = ((oy * S) >> 5) * S + ((ox * S) >> 5);
    float2 v = yu[ybase + c * S * S + si];
    ym[t] = pA[c] * v.x + pB[c] + pP2v * v.y;
  }
  __syncthreads();
  for (int t = threadIdx.x; t < 768; t += 256) {
    int o = t >> 8, j = t & 255;
    float y0 = ym[j], y1 = ym[256 + j], y2v = ym[512 + j];
    ks[t] = (kb[o] + kw[o * 3] * y0 + kw[o * 3 + 1] * y1 + kw[o * 3 + 2] * y2v) * LOG2E;
    vs[t] = vb[o] + vw[o * 3] * y0 + vw[o * 3 + 1] * y1 + vw[o * 3 + 2] * y2v;
  }
  {
    int t = threadIdx.x;
    int m = (mp << 8) + t;
    float M0 = Mp[(b * 4 + 0) * 1024 + m], M1 = Mp[(b * 4 + 1) * 1024 + m];
    float M2 = Mp[(b * 4 + 2) * 1024 + m], M3 = Mp[(b * 4 + 3) * 1024 + m];
    float L0 = Lp[(b * 4 + 0) * 1024 + m], L1 = Lp[(b * 4 + 1) * 1024 + m];
    float L2 = Lp[(b * 4 + 2) * 1024 + m], L3 = Lp[(b * 4 + 3) * 1024 + m];
    float MM = fmaxf(fmaxf(M0, M1), fmaxf(M2, M3));
    float LL = L0 * exp2f(M0 - MM) + L1 * exp2f(M1 - MM) +
               L2 * exp2f(M2 - MM) + L3 * exp2f(M3 - MM);
    Ms[t] = MM;
    Ls[t] = 1.0f / LL;
  }
  __syncthreads();
  int n = (nc << 8) + threadIdx.x;
  int oy = n >> 5, ox = n & 31;
  int si = ((oy * S) >> 5) * S + ((ox * S) >> 5);
  float yn[3];
  #pragma unroll
  for (int c = 0; c < 3; ++c) {
    float2 v = yu[ybase + c * S * S + si];
    yn[c] = pA[c] * v.x + pB[c] + pP2v * v.y;
  }
  float q0 = qb[0] + qw[0] * yn[0] + qw[1] * yn[1] + qw[2] * yn[2];
  float q1 = qb[1] + qw[3] * yn[0] + qw[4] * yn[1] + qw[5] * yn[2];
  float q2 = qb[2] + qw[6] * yn[0] + qw[7] * yn[1] + qw[8] * yn[2];
  float a0 = 0.f, a1 = 0.f, a2 = 0.f;
  for (int j = 0; j < 256; ++j) {
    float s = ks[j] * q0 + ks[256 + j] * q1 + ks[512 + j] * q2;
    float w = exp2f(s - Ms[j]) * Ls[j];
    a0 = fmaf(vs[j], w, a0);
    a1 = fmaf(vs[256 + j], w, a1);
    a2 = fmaf(vs[512 + j], w, a2);
  }
  if (mp == 0) { a0 += yn[0]; a1 += yn[1]; a2 += yn[2]; }
  size_t o0 = (size_t)b * 3 * 1024 + n;
  atomicAdd(&aout[o0], a0);
  atomicAdd(&aout[o0 + 1024], a1);
  atomicAdd(&aout[o0 + 2048], a2);
}

// ---- attention HW=256 fused with the FOLLOWING 5x5 conv (16x16 image in LDS) ----
// input: yu at S x S grid (prev conv); output: conv result at 12x12 grid + stats
__global__ __launch_bounds__(256) void attn256_conv(
    const float2* __restrict__ yu, const float* __restrict__ sums,
    const float* __restrict__ inp, const float* __restrict__ lnp,
    const float* __restrict__ bnp, const float* __restrict__ bnw,
    const float* __restrict__ bnb, const float* __restrict__ p1p,
    const float* __restrict__ p2p,
    const float* __restrict__ qw, const float* __restrict__ qb,
    const float* __restrict__ kw, const float* __restrict__ kb,
    const float* __restrict__ vw, const float* __restrict__ vb,
    const float* __restrict__ cw1, const float* __restrict__ cb1,
    const float* __restrict__ cw2, const float* __restrict__ cb2,
    float2* __restrict__ yu_out, float* __restrict__ sums_out, int S, int r) {
  __shared__ float pA[3], pB[3], pP2v;
  __shared__ float y2s[768], qs[768], ks[768], vs[768], Ms[256], Ls[256];
  int b = blockIdx.x;
  compute_AB(sums, b, 32, 256.f, inp, lnp, bnp, bnw, bnb, p1p, p2p, pA, pB, &pP2v);
  size_t ybase = (size_t)b * 3 * S * S;
  for (int t = threadIdx.x; t < 768; t += 256) {
    int c = t >> 8, p = t & 255;
    int oy = p >> 4, ox = p & 15;
    int si = ((oy * S) >> 4) * S + ((ox * S) >> 4);
    float2 v = yu[ybase + c * S * S + si];
    y2s[t] = pA[c] * v.x + pB[c] + pP2v * v.y;
  }
  __syncthreads();
  for (int t = threadIdx.x; t < 768; t += 256) {
    int o = t >> 8, p = t & 255;
    float y0 = y2s[p], y1 = y2s[256 + p], y2v = y2s[512 + p];
    qs[t] = qb[o] + qw[o * 3] * y0 + qw[o * 3 + 1] * y1 + qw[o * 3 + 2] * y2v;
    ks[t] = (kb[o] + kw[o * 3] * y0 + kw[o * 3 + 1] * y1 + kw[o * 3 + 2] * y2v) * LOG2E;
    vs[t] = vb[o] + vw[o * 3] * y0 + vw[o * 3 + 1] * y1 + vw[o * 3 + 2] * y2v;
  }
  __syncthreads();
  {
    int m = threadIdx.x;
    float kx = ks[m], ky = ks[256 + m], kz = ks[512 + m];
    float mr = -1e30f;
    for (int j = 0; j < 256; ++j) {
      float s = kx * qs[j] + ky * qs[256 + j] + kz * qs[512 + j];
      mr = fmaxf(mr, s);
    }
    float l = 0.f;
    for (int j = 0; j < 256; ++j) {
      float s = kx * qs[j] + ky * qs[256 + j] + kz * qs[512 + j];
      l += exp2f(s - mr);
    }
    Ms[m] = mr;
    Ls[m] = 1.0f / l;
  }
  __syncthreads();
  {
    int n = threadIdx.x;
    float q0 = qs[n], q1 = qs[256 + n], q2 = qs[512 + n];
    float a0 = 0.f, a1 = 0.f, a2 = 0.f;
    for (int j = 0; j < 256; ++j) {
      float s = ks[j] * q0 + ks[256 + j] * q1 + ks[512 + j] * q2;
      float w = exp2f(s - Ms[j]) * Ls[j];
      a0 = fmaf(vs[j], w, a0);
      a1 = fmaf(vs[256 + j], w, a1);
      a2 = fmaf(vs[512 + j], w, a2);
    }
    // residual, in-place into y2s (thread n owns these 3 slots)
    y2s[n] += a0;
    y2s[256 + n] += a1;
    y2s[512 + n] += a2;
  }
  __syncthreads();
  // ---- conv 5x5 valid on the 16x16 image in y2s -> 12x12 grid ----
  float sc[3] = {0.f, 0.f, 0.f}, sq[3] = {0.f, 0.f, 0.f};
  int p = threadIdx.x;
  if (p < 144) {
    int py = p / 12, px = p - py * 12;
    float a1[3], a2[3];
    #pragma unroll
    for (int c = 0; c < 3; ++c) { a1[c] = cb1[c]; a2[c] = cb2[c]; }
    #pragma unroll
    for (int ci = 0; ci < 3; ++ci) {
      #pragma unroll
      for (int ky = 0; ky < 5; ++ky) {
        const float* row = &y2s[ci * 256 + (py + ky) * 16 + px];
        #pragma unroll
        for (int c = 0; c < 3; ++c) {
          #pragma unroll
          for (int kx = 0; kx < 5; ++kx) {
            a1[c] = fmaf(row[kx], cw1[c * 75 + ci * 25 + ky * 5 + kx], a1[c]);
            a2[c] = fmaf(row[kx], cw2[c * 75 + ci * 25 + ky * 5 + kx], a2[c]);
          }
        }
      }
    }
    float wy = (float)(((py + 1) * r + 11) / 12 - (py * r + 11) / 12);
    float wx = (float)(((px + 1) * r + 11) / 12 - (px * r + 11) / 12);
    float wgt = wy * wx;
    #pragma unroll
    for (int c = 0; c < 3; ++c) {
      yu_out[(size_t)(b * 3 + c) * 144 + p] = make_float2(a1[c], a2[c]);
      sc[c] += a1[c] * wgt;
      sq[c] += a1[c] * a1[c] * wgt;
    }
  }
  STATS_REDUCE_ATOMIC(sc, sq, sums_out, b)
}

// ---- final: affine + p2*u2 + tanh -> out ----
__global__ __launch_bounds__(256) void elem_final(
    const float2* __restrict__ yu, const float* __restrict__ sums,
    const float* __restrict__ inp, const float* __restrict__ lnp,
    const float* __restrict__ bnp, const float* __restrict__ bnw,
    const float* __restrict__ bnb, const float* __restrict__ p1p,
    const float* __restrict__ p2p, float* __restrict__ out, int S) {
  __shared__ float pA[3], pB[3], pP2v;
  int n = blockIdx.x >> 8;
  int p = ((blockIdx.x & 255) << 8) + threadIdx.x;
  compute_AB(sums, n, 32, 65536.f, inp, lnp, bnp, bnw, bnb, p1p, p2p, pA, pB, &pP2v);
  int oy = p >> 8, ox = p & 255;
  int si = ((oy * S) >> 8) * S + ((ox * S) >> 8);
  size_t ybase = (size_t)n * 3 * S * S;
  #pragma unroll
  for (int c = 0; c < 3; ++c) {
    float2 v = yu[ybase + c * S * S + si];
    out[((size_t)(n * 3 + c) << 16) + p] = tanhf(pA[c] * v.x + pB[c] + pP2v * v.y);
  }
}

#define NPX nullptr, nullptr, nullptr, nullptr, nullptr, nullptr, nullptr, \
            nullptr, nullptr, 0, 0, 0

extern "C" void kernel_launch(void* const* d_in, const int* in_sizes, int n_in,
                              void* d_out, int out_size, void* d_ws, size_t ws_size,
                              hipStream_t stream) {
  const float* x       = (const float*)d_in[0];
  const float* noise_z = (const float*)d_in[1];
  const float* lin_w   = (const float*)d_in[2];
  const float* lin_b   = (const float*)d_in[3];
  const float* conv_w  = (const float*)d_in[4];
  const float* conv_b  = (const float*)d_in[5];
  const float* conv2_w = (const float*)d_in[6];
  const float* conv2_b = (const float*)d_in[7];
  const float* q_w     = (const float*)d_in[8];
  const float* q_b     = (const float*)d_in[9];
  const float* k_w     = (const float*)d_in[10];
  const float* k_b     = (const float*)d_in[11];
  const float* v_w     = (const float*)d_in[12];
  const float* v_b     = (const float*)d_in[13];
  const float* in_p    = (const float*)d_in[14];
  const float* ln_p    = (const float*)d_in[15];
  const float* bn_p    = (const float*)d_in[16];
  const float* bn_w    = (const float*)d_in[17];
  const float* bn_b    = (const float*)d_in[18];
  const float* p1      = (const float*)d_in[19];
  const float* p2      = (const float*)d_in[20];
  float* out = (float*)d_out;

  float* ws = (float*)d_ws;
  size_t off = 0;
  auto alloc = [&](size_t nf) { float* p = ws + off; off += nf; return p; };
  float* SUMS = alloc(2304);
  float* A5   = alloc(98304);
  float* A8   = alloc(98304);
  float2* YU2 = (float2*)alloc(12192768);  // 252^2 * 96 * 2
  float2* PA  = (float2*)alloc(3145728);   // up to 128^2 * 96 * 2
  float2* PB  = (float2*)alloc(3145728);
  float* Mp   = alloc(131072);
  float* Lp   = alloc(131072);
  float* NB0  = alloc(12288);
  float* LIN  = alloc(768);

  hipMemsetAsync(SUMS, 0, (2304 + 98304 + 98304) * sizeof(float), stream);

  const float* nul = nullptr;
  const float2* nul2 = nullptr;

  // noise path: parallel linear, then small conv pipeline (blocks 0,1) -> NB0
  linear_wave<<<192, 256, 0, stream>>>(noise_z, lin_w, lin_b, LIN);
  noise_rest<<<1, 256, 0, stream>>>(LIN, conv_w, conv_b, conv2_w, conv2_b,
      in_p, ln_p, bn_p, bn_w, bn_b, p1, p2, NB0);

  // conv2: x -> YU2 (S=252, r=256)
  conv_up_t<false><<<2048, 256, 0, stream>>>(x, nul2, YU2, conv_w + 450,
      conv_b + 6, conv2_w + 450, conv2_b + 6, SUMS + 384, 256, 252, 256, 4, 16,
      NPX);
  // conv3: fused(b2) YU2 -> PA (S=128); prev Sp=252, logrp=8 (true gather)
  conv_dn_t<true, false><<<2048, 256, 0, stream>>>(nul, YU2, PA, conv_w + 675,
      conv_b + 9, conv2_w + 675, conv2_b + 9, SUMS + 576, 256, 128, 252, 7, 4, 16,
      SUMS + 384, in_p + 6, ln_p + 6, bn_p + 6, bn_w + 6, bn_b + 6, p1 + 2,
      p2 + 2, nul, 32, 252, 8);
  // conv4: fused(b3) PA -> PB (S=64); prev identity (Sp=128==Hin)
  conv_dn_t<true, true><<<512, 256, 0, stream>>>(nul, PA, PB, conv_w + 900,
      conv_b + 12, conv2_w + 900, conv2_b + 12, SUMS + 768, 128, 64, 124, 6, 2, 8,
      SUMS + 576, in_p + 9, ln_p + 9, bn_p + 9, bn_w + 9, bn_b + 9, p1 + 3,
      p2 + 3, nul, 32, 128, 7);
  // conv5: fused(b4)+noise PB -> PA (S=32); prev identity (Sp=64==Hin)
  conv_dn_t<true, true><<<128, 256, 0, stream>>>(nul, PB, PA, conv_w + 1125,
      conv_b + 15, conv2_w + 1125, conv2_b + 15, SUMS + 960, 64, 32, 60, 5, 1, 4,
      SUMS + 768, in_p + 12, ln_p + 12, bn_p + 12, bn_w + 12, bn_b + 12, p1 + 4,
      p2 + 4, NB0, 32, 64, 6);
  // attn5 (HW=1024) on PA (S=32) -> A5
  attn_rows_f<<<512, 256, 0, stream>>>(PA, SUMS + 960, in_p + 15, ln_p + 15,
      bn_p + 15, bn_w + 15, bn_b + 15, p1 + 5, p2 + 5,
      q_w + 45, q_b + 15, k_w + 45, k_b + 15, Mp, Lp, 32);
  attn_out_f<<<512, 256, 0, stream>>>(PA, SUMS + 960, in_p + 15, ln_p + 15,
      bn_p + 15, bn_w + 15, bn_b + 15, p1 + 5, p2 + 5,
      q_w + 45, q_b + 15, k_w + 45, k_b + 15, v_w + 45, v_b + 15, Mp, Lp, A5, 32);
  // conv6: direct A5 -> PB (S=16)
  conv_dn_t<false, false><<<64, 256, 0, stream>>>(A5, nul2, PB, conv_w + 1350,
      conv_b + 18, conv2_w + 1350, conv2_b + 18, SUMS + 1152, 32, 16, 28, 4, 1, 2,
      NPX);
  // attn6 (HW=256) on PB (S=16) + conv7 (r=16) -> PA (S=12), SUMS+1344
  attn256_conv<<<32, 256, 0, stream>>>(PB, SUMS + 1152, in_p + 18, ln_p + 18,
      bn_p + 18, bn_w + 18, bn_b + 18, p1 + 6, p2 + 6,
      q_w + 54, q_b + 18, k_w + 54, k_b + 18, v_w + 54, v_b + 18,
      conv_w + 1575, conv_b + 21, conv2_w + 1575, conv2_b + 21,
      PA, SUMS + 1344, 16, 16);
  // attn7 (HW=256) on PA (S=12) + conv8 (r=32) -> PB (S=12), SUMS+1536
  attn256_conv<<<32, 256, 0, stream>>>(PA, SUMS + 1344, in_p + 21, ln_p + 21,
      bn_p + 21, bn_w + 21, bn_b + 21, p1 + 7, p2 + 7,
      q_w + 63, q_b + 21, k_w + 63, k_b + 21, v_w + 63, v_b + 21,
      conv_w + 1800, conv_b + 24, conv2_w + 1800, conv2_b + 24,
      PB, SUMS + 1536, 12, 32);
  // attn8 (HW=1024) on PB (S=12) -> A8
  attn_rows_f<<<512, 256, 0, stream>>>(PB, SUMS + 1536, in_p + 24, ln_p + 24,
      bn_p + 24, bn_w + 24, bn_b + 24, p1 + 8, p2 + 8,
      q_w + 72, q_b + 24, k_w + 72, k_b + 24, Mp, Lp, 12);
  attn_out_f<<<512, 256, 0, stream>>>(PB, SUMS + 1536, in_p + 24, ln_p + 24,
      bn_p + 24, bn_w + 24, bn_b + 24, p1 + 8, p2 + 8,
      q_w + 72, q_b + 24, k_w + 72, k_b + 24, v_w + 72, v_b + 24, Mp, Lp, A8, 12);
  // conv9: direct A8 -> PA (S=28, r=64)
  conv_up_t<false><<<64, 256, 0, stream>>>(A8, nul2, PA, conv_w + 2025,
      conv_b + 27, conv2_w + 2025, conv2_b + 27, SUMS + 1728, 32, 28, 64, 1, 2,
      NPX);
  // conv10: fused(b9) PA -> PB (S=60); prev Sp=28, logrp=6
  conv_up_t<true><<<128, 256, 0, stream>>>(nul, PA, PB, conv_w + 2250,
      conv_b + 30, conv2_w + 2250, conv2_b + 30, SUMS + 1920, 64, 60, 128, 1, 4,
      SUMS + 1728, in_p + 27, ln_p + 27, bn_p + 27, bn_w + 27, bn_b + 27,
      p1 + 9, p2 + 9, nul, 32, 28, 6);
  // conv11: fused(b10) PB -> YU2 (S=124); prev Sp=60, logrp=7
  conv_up_t<true><<<512, 256, 0, stream>>>(nul, PB, YU2, conv_w + 2475,
      conv_b + 33, conv2_w + 2475, conv2_b + 33, SUMS + 2112, 128, 124, 256, 2, 8,
      SUMS + 1920, in_p + 30, ln_p + 30, bn_p + 30, bn_w + 30, bn_b + 30,
      p1 + 10, p2 + 10, nul, 32, 60, 7);
  // final: tanh -> out
  elem_final<<<8192, 256, 0, stream>>>(YU2, SUMS + 2112, in_p + 33, ln_p + 33,
      bn_p + 33, bn_w + 33, bn_b + 33, p1 + 11, p2 + 11, out, 124);
}

// Round 9
// 530.154 us; speedup vs baseline: 1.6638x; 1.0323x over previous
//
#include <hip/hip_runtime.h>
#include <math.h>

#define EPS 1e-5f
#define LOG2E 1.44269504088896340736f

#define AS_GLOBAL __attribute__((address_space(1)))
#define AS_LDS    __attribute__((address_space(3)))

// ---- shared affine-fold helper: A,B from sums (instance+batch norm + p1) ----
__device__ __forceinline__ float2 ab_from(float s1, float s2, float bs, float bs2,
    float hw, float Nf, float si_, float sb, float bnw_c, float bnb_c, float p1v) {
  float inv = 1.0f / hw;
  float mi = s1 * inv, vi = s2 * inv - mi * mi;
  float ri = rsqrtf(vi + EPS);
  float invb = 1.0f / (Nf * hw);
  float mb = bs * invb, vb = bs2 * invb - mb * mb;
  float rb = rsqrtf(vb + EPS);
  float A = 1.0f + si_ * ri + sb * rb * bnw_c;
  float B = -(si_ * ri * mi + sb * rb * bnw_c * mb) + sb * bnb_c;
  return make_float2(A * p1v, B * p1v);
}

__device__ __forceinline__ void compute_AB(
    const float* __restrict__ sums, int n, int N, float hw,
    const float* __restrict__ inp, const float* __restrict__ lnp,
    const float* __restrict__ bnp, const float* __restrict__ bnw,
    const float* __restrict__ bnb, const float* __restrict__ p1p,
    const float* __restrict__ p2p, float* pA, float* pB, float* pP2) {
  if (threadIdx.x == 0) *pP2 = p2p[0];
  if (threadIdx.x < 3) {
    int c = threadIdx.x;
    float si_ = inp[0] + inp[1] + inp[2] + lnp[0] + lnp[1] + lnp[2];
    float sb = bnp[0] + bnp[1] + bnp[2];
    float s1 = sums[2 * (n * 3 + c)], s2 = sums[2 * (n * 3 + c) + 1];
    float bs = 0.f, bs2 = 0.f;
    for (int nn = 0; nn < N; ++nn) {
      bs += sums[2 * (nn * 3 + c)];
      bs2 += sums[2 * (nn * 3 + c) + 1];
    }
    float2 ab = ab_from(s1, s2, bs, bs2, hw, (float)N, si_, sb, bnw[c], bnb[c], p1p[0]);
    pA[c] = ab.x;
    pB[c] = ab.y;
  }
  __syncthreads();
}

// stats block-reduce (all threads must participate)
#define STATS_REDUCE_ATOMIC(scv, sqv, sumsp, nvar)                            \
  {                                                                           \
    _Pragma("unroll")                                                         \
    for (int off = 32; off; off >>= 1) {                                      \
      _Pragma("unroll")                                                       \
      for (int c = 0; c < 3; ++c) {                                           \
        scv[c] += __shfl_down(scv[c], off);                                   \
        sqv[c] += __shfl_down(sqv[c], off);                                   \
      }                                                                       \
    }                                                                         \
    __shared__ float redS[4][3], redQ[4][3];                                  \
    int wid = threadIdx.x >> 6, lane = threadIdx.x & 63;                      \
    if (lane == 0) {                                                          \
      _Pragma("unroll")                                                       \
      for (int c = 0; c < 3; ++c) { redS[wid][c] = scv[c]; redQ[wid][c] = sqv[c]; } \
    }                                                                         \
    __syncthreads();                                                          \
    if (threadIdx.x < 3) {                                                    \
      int c = threadIdx.x;                                                    \
      atomicAdd(&sumsp[2 * ((nvar) * 3 + c)],                                 \
                redS[0][c] + redS[1][c] + redS[2][c] + redS[3][c]);           \
      atomicAdd(&sumsp[2 * ((nvar) * 3 + c) + 1],                             \
                redQ[0][c] + redQ[1][c] + redQ[2][c] + redQ[3][c]);           \
    }                                                                         \
  }

// ---- LDS-tiled upsample conv (S==hc): 64x16 tile, TX=4, float2 out ----
// SUM4: input is 4 partial buffers (attn partials) summed during staging
template <bool FUSED, bool SUM4>
__global__ __launch_bounds__(256) void conv_up_t(
    const float* __restrict__ in, const float2* __restrict__ pyu,
    float2* __restrict__ yu,
    const float* __restrict__ w1, const float* __restrict__ b1,
    const float* __restrict__ w2, const float* __restrict__ b2,
    float* __restrict__ sums, int Hin, int S, int r, int tilesX, int tilesY,
    const float* __restrict__ psums,
    const float* __restrict__ pinp, const float* __restrict__ plnp,
    const float* __restrict__ pbnp, const float* __restrict__ pbnw,
    const float* __restrict__ pbnb, const float* __restrict__ pp1,
    const float* __restrict__ pp2, const float* __restrict__ pnoise,
    int pN, int Sp, int logrp) {
  const int TW = 64, TH = 16, IW = 68, IH = 20;
  __shared__ float lin[3 * IH * IW];
  __shared__ float pA[3], pB[3], pP2v;
  int tpi = tilesX * tilesY;
  int n = blockIdx.x / tpi;
  int trem = blockIdx.x - n * tpi;
  int tyB = trem / tilesX, txB = trem - tyB * tilesX;
  int px0 = txB * TW, py0 = tyB * TH;
  const float* inb = in + (size_t)n * 3 * Hin * Hin;
  if (FUSED) {
    compute_AB(psums, n, pN, (float)(Hin * Hin), pinp, plnp, pbnp, pbnw, pbnb,
               pp1, pp2, pA, pB, &pP2v);
    size_t pbase = (size_t)n * 3 * Sp * Sp;
    for (int t = threadIdx.x; t < 3 * IH * IW; t += 256) {
      int cc = t / (IH * IW);
      int rem = t - cc * IH * IW;
      int rr = rem / IW, col = rem - rr * IW;
      int gy = py0 + rr; gy = gy < Hin ? gy : Hin - 1;
      int gx = px0 + col; gx = gx < Hin ? gx : Hin - 1;
      int si = ((gy * Sp) >> logrp) * Sp + ((gx * Sp) >> logrp);
      float2 v = pyu[pbase + cc * Sp * Sp + si];
      float val = pA[cc] * v.x + pB[cc] + pP2v * v.y;
      if (pnoise) val += pnoise[((size_t)cc * Hin + gy) * Hin + gx];
      lin[t] = val;
    }
  } else if (SUM4) {
    size_t ps = (size_t)96 * Hin * Hin;
    for (int t = threadIdx.x; t < 3 * IH * IW; t += 256) {
      int cc = t / (IH * IW);
      int rem = t - cc * IH * IW;
      int rr = rem / IW, col = rem - rr * IW;
      int gy = py0 + rr; gy = gy < Hin ? gy : Hin - 1;
      int gx = px0 + col; gx = gx < Hin ? gx : Hin - 1;
      size_t idx = ((size_t)(n * 3 + cc) * Hin + gy) * Hin + gx;
      lin[t] = in[idx] + in[idx + ps] + in[idx + 2 * ps] + in[idx + 3 * ps];
    }
  } else {
    if (px0 + IW <= Hin && py0 + IH <= Hin) {
      // async global->LDS, width=16: LDS dest is wave-uniform base + lane*16
      for (int t4 = threadIdx.x; t4 < 3 * IH * 17; t4 += 256) {
        int cc = t4 / (IH * 17);
        int rem = t4 - cc * (IH * 17);
        int rr = rem / 17, j = rem - rr * 17;
        const float* src = inb + ((size_t)cc * Hin + py0 + rr) * Hin + px0 + 4 * j;
        int base = t4 - (threadIdx.x & 63);  // wave-uniform float4 index
        __builtin_amdgcn_global_load_lds(
            (const AS_GLOBAL void*)src,
            (AS_LDS void*)(lin + 4 * base), 16, 0, 0);
      }
    } else {
      for (int t = threadIdx.x; t < 3 * IH * IW; t += 256) {
        int cc = t / (IH * IW);
        int rem = t - cc * IH * IW;
        int rr = rem / IW, col = rem - rr * IW;
        int gy = py0 + rr; gy = gy < Hin ? gy : Hin - 1;
        int gx = px0 + col; gx = gx < Hin ? gx : Hin - 1;
        lin[t] = inb[((size_t)cc * Hin + gy) * Hin + gx];
      }
    }
  }
  __syncthreads();
  int tx = threadIdx.x & 15, ty = threadIdx.x >> 4;
  int lx0 = tx * 4;
  int px = px0 + lx0, py = py0 + ty;
  float a1[3][4], a2[3][4];
  #pragma unroll
  for (int c = 0; c < 3; ++c) {
    float bb1 = b1[c], bb2 = b2[c];
    #pragma unroll
    for (int x = 0; x < 4; ++x) { a1[c][x] = bb1; a2[c][x] = bb2; }
  }
  #pragma unroll 1
  for (int ci = 0; ci < 3; ++ci) {
    const float* lrow = lin + ci * IH * IW + ty * IW + lx0;
    const float* wp1 = w1 + ci * 25;
    const float* wp2 = w2 + ci * 25;
    #pragma unroll
    for (int ky = 0; ky < 5; ++ky) {
      float v[8];
      #pragma unroll
      for (int j = 0; j < 8; ++j) v[j] = lrow[ky * IW + j];
      #pragma unroll
      for (int c = 0; c < 3; ++c) {
        #pragma unroll
        for (int kx = 0; kx < 5; ++kx) {
          float wa = wp1[c * 75 + ky * 5 + kx];
          float wb = wp2[c * 75 + ky * 5 + kx];
          #pragma unroll
          for (int x = 0; x < 4; ++x) {
            a1[c][x] = fmaf(v[kx + x], wa, a1[c][x]);
            a2[c][x] = fmaf(v[kx + x], wb, a2[c][x]);
          }
        }
      }
    }
  }
  float sc[3] = {0.f, 0.f, 0.f}, sq[3] = {0.f, 0.f, 0.f};
  bool valid = (py < S) && (px < S);
  if (valid) {
    int hc = S;
    float wy = (float)(((py + 1) * r + hc - 1) / hc - (py * r + hc - 1) / hc);
    float wx[4];
    #pragma unroll
    for (int x = 0; x < 4; ++x) {
      int pxx = px + x;
      wx[x] = (float)(((pxx + 1) * r + hc - 1) / hc - (pxx * r + hc - 1) / hc);
    }
    #pragma unroll
    for (int c = 0; c < 3; ++c) {
      size_t idx = ((size_t)(n * 3 + c) * S + py) * S + px;
      float2* yp = yu + idx;
      *reinterpret_cast<float4*>(yp) =
          make_float4(a1[c][0], a2[c][0], a1[c][1], a2[c][1]);
      *reinterpret_cast<float4*>(yp + 2) =
          make_float4(a1[c][2], a2[c][2], a1[c][3], a2[c][3]);
      #pragma unroll
      for (int x = 0; x < 4; ++x) {
        float wgt = wy * wx[x];
        sc[c] += a1[c][x] * wgt;
        sq[c] += a1[c][x] * a1[c][x] * wgt;
      }
    }
  }
  STATS_REDUCE_ATOMIC(sc, sq, sums, n)
}

// ---- LDS-tiled downsample conv (ratio<2.05): 32x8 tile, float2 out ----
template <bool FUSED, bool IDENT, bool SUM4>
__global__ __launch_bounds__(256) void conv_dn_t(
    const float* __restrict__ in, const float2* __restrict__ pyu,
    float2* __restrict__ yu,
    const float* __restrict__ w1, const float* __restrict__ b1,
    const float* __restrict__ w2, const float* __restrict__ b2,
    float* __restrict__ sums, int Hin, int S, int hc, int logr,
    int tilesX, int tilesY,
    const float* __restrict__ psums,
    const float* __restrict__ pinp, const float* __restrict__ plnp,
    const float* __restrict__ pbnp, const float* __restrict__ pbnw,
    const float* __restrict__ pbnb, const float* __restrict__ pp1,
    const float* __restrict__ pp2, const float* __restrict__ pnoise,
    int pN, int Sp, int logrp) {
  const int TW = 32, TH = 8, IW = 68, IH = 20;
  __shared__ float lin[3 * IH * IW];
  __shared__ float pA[3], pB[3], pP2v;
  int tpi = tilesX * tilesY;
  int n = blockIdx.x / tpi;
  int trem = blockIdx.x - n * tpi;
  int tyB = trem / tilesX, txB = trem - tyB * tilesX;
  int px0 = txB * TW, py0 = tyB * TH;
  int sy0 = (py0 * hc) >> logr, sx0 = (px0 * hc) >> logr;
  const float* inb = in + (size_t)n * 3 * Hin * Hin;
  if (FUSED) {
    compute_AB(psums, n, pN, (float)(Hin * Hin), pinp, plnp, pbnp, pbnw, pbnb,
               pp1, pp2, pA, pB, &pP2v);
    size_t pbase = (size_t)n * 3 * Sp * Sp;
    for (int t = threadIdx.x; t < 3 * IH * IW; t += 256) {
      int cc = t / (IH * IW);
      int rem = t - cc * IH * IW;
      int rr = rem / IW, col = rem - rr * IW;
      int gy = sy0 + rr; gy = gy < Hin ? gy : Hin - 1;
      int gx = sx0 + col; gx = gx < Hin ? gx : Hin - 1;
      int si;
      if (IDENT) si = gy * Sp + gx;
      else si = ((gy * Sp) >> logrp) * Sp + ((gx * Sp) >> logrp);
      float2 v = pyu[pbase + cc * Sp * Sp + si];
      float val = pA[cc] * v.x + pB[cc] + pP2v * v.y;
      if (pnoise) val += pnoise[((size_t)cc * Hin + gy) * Hin + gx];
      lin[t] = val;
    }
  } else if (SUM4) {
    size_t ps = (size_t)96 * Hin * Hin;
    for (int t = threadIdx.x; t < 3 * IH * IW; t += 256) {
      int cc = t / (IH * IW);
      int rem = t - cc * IH * IW;
      int rr = rem / IW, col = rem - rr * IW;
      int gy = sy0 + rr; gy = gy < Hin ? gy : Hin - 1;
      int gx = sx0 + col; gx = gx < Hin ? gx : Hin - 1;
      size_t idx = ((size_t)(n * 3 + cc) * Hin + gy) * Hin + gx;
      lin[t] = in[idx] + in[idx + ps] + in[idx + 2 * ps] + in[idx + 3 * ps];
    }
  } else {
    for (int t = threadIdx.x; t < 3 * IH * IW; t += 256) {
      int cc = t / (IH * IW);
      int rem = t - cc * IH * IW;
      int rr = rem / IW, col = rem - rr * IW;
      int gy = sy0 + rr; gy = gy < Hin ? gy : Hin - 1;
      int gx = sx0 + col; gx = gx < Hin ? gx : Hin - 1;
      lin[t] = inb[((size_t)cc * Hin + gy) * Hin + gx];
    }
  }
  __syncthreads();
  int tx = threadIdx.x & 31, ty = threadIdx.x >> 5;
  int px = px0 + tx, py = py0 + ty;
  int sxl = ((px * hc) >> logr) - sx0;
  int syl = ((py * hc) >> logr) - sy0;
  float a1[3], a2[3];
  #pragma unroll
  for (int c = 0; c < 3; ++c) { a1[c] = b1[c]; a2[c] = b2[c]; }
  #pragma unroll
  for (int ci = 0; ci < 3; ++ci) {
    const float* lrow = lin + ci * IH * IW + syl * IW + sxl;
    const float* wp1 = w1 + ci * 25;
    const float* wp2 = w2 + ci * 25;
    #pragma unroll
    for (int ky = 0; ky < 5; ++ky) {
      float v[5];
      #pragma unroll
      for (int j = 0; j < 5; ++j) v[j] = lrow[ky * IW + j];
      #pragma unroll
      for (int c = 0; c < 3; ++c) {
        #pragma unroll
        for (int kx = 0; kx < 5; ++kx) {
          a1[c] = fmaf(v[kx], wp1[c * 75 + ky * 5 + kx], a1[c]);
          a2[c] = fmaf(v[kx], wp2[c * 75 + ky * 5 + kx], a2[c]);
        }
      }
    }
  }
  float sc[3] = {0.f, 0.f, 0.f}, sq[3] = {0.f, 0.f, 0.f};
  bool valid = (py < S) && (px < S);
  if (valid) {
    #pragma unroll
    for (int c = 0; c < 3; ++c) {
      size_t idx = ((size_t)(n * 3 + c) * S + py) * S + px;
      yu[idx] = make_float2(a1[c], a2[c]);
      sc[c] += a1[c];
      sq[c] += a1[c] * a1[c];
    }
  }
  STATS_REDUCE_ATOMIC(sc, sq, sums, n)
}

// ---- Linear 512->768: one wave per output row, coalesced float4 ----
__global__ __launch_bounds__(256) void linear_wave(
    const float* __restrict__ z, const float* __restrict__ w,
    const float* __restrict__ b, float* __restrict__ out) {
  int row = (blockIdx.x << 2) + (threadIdx.x >> 6);
  int lane = threadIdx.x & 63;
  const float4* wr = reinterpret_cast<const float4*>(w + (size_t)row * 512);
  const float4* zz = reinterpret_cast<const float4*>(z);
  float acc = 0.f;
  #pragma unroll
  for (int i = 0; i < 2; ++i) {
    float4 wv = wr[lane + 64 * i];
    float4 zv = zz[lane + 64 * i];
    acc += wv.x * zv.x + wv.y * zv.y + wv.z * zv.z + wv.w * zv.w;
  }
  #pragma unroll
  for (int off = 32; off; off >>= 1) acc += __shfl_down(acc, off);
  if (lane == 0) out[row] = acc + b[row];
}

// ---- noise conv path (blocks 0,1) in one block, L0 from global ----
__global__ __launch_bounds__(256) void noise_rest(
    const float* __restrict__ L0g,
    const float* __restrict__ cw, const float* __restrict__ cb,
    const float* __restrict__ c2w, const float* __restrict__ c2b,
    const float* __restrict__ inp, const float* __restrict__ lnp,
    const float* __restrict__ bnp, const float* __restrict__ bnw,
    const float* __restrict__ bnb, const float* __restrict__ p1p,
    const float* __restrict__ p2p, float* __restrict__ nb0) {
  __shared__ float L0[768];
  __shared__ float ys0[432], u20[432];
  __shared__ float buf1[3072];
  __shared__ float ys1[2352], u21[2352];
  __shared__ float redS[4][3], redQ[4][3];
  __shared__ float AB[6];
  int tid = threadIdx.x;
  for (int t = tid; t < 768; t += 256) L0[t] = L0g[t];
  __syncthreads();
  // ---- conv0: (3,16,16) -> S=12, r=32 ----
  {
    float sc[3] = {0, 0, 0}, sq[3] = {0, 0, 0};
    for (int p = tid; p < 144; p += 256) {
      int py = p / 12, px = p - py * 12;
      float a1[3], a2[3];
      #pragma unroll
      for (int c = 0; c < 3; ++c) { a1[c] = cb[c]; a2[c] = c2b[c]; }
      for (int ci = 0; ci < 3; ++ci)
        #pragma unroll
        for (int ky = 0; ky < 5; ++ky) {
          const float* row = &L0[ci * 256 + (py + ky) * 16 + px];
          #pragma unroll
          for (int c = 0; c < 3; ++c)
            #pragma unroll
            for (int kx = 0; kx < 5; ++kx) {
              a1[c] = fmaf(row[kx], cw[c * 75 + ci * 25 + ky * 5 + kx], a1[c]);
              a2[c] = fmaf(row[kx], c2w[c * 75 + ci * 25 + ky * 5 + kx], a2[c]);
            }
        }
      int wy = ((py + 1) * 32 + 11) / 12 - (py * 32 + 11) / 12;
      int wx = ((px + 1) * 32 + 11) / 12 - (px * 32 + 11) / 12;
      float wgt = (float)(wy * wx);
      #pragma unroll
      for (int c = 0; c < 3; ++c) {
        ys0[c * 144 + p] = a1[c];
        u20[c * 144 + p] = a2[c];
        sc[c] += a1[c] * wgt;
        sq[c] += a1[c] * a1[c] * wgt;
      }
    }
    #pragma unroll
    for (int off = 32; off; off >>= 1)
      #pragma unroll
      for (int c = 0; c < 3; ++c) {
        sc[c] += __shfl_down(sc[c], off);
        sq[c] += __shfl_down(sq[c], off);
      }
    int wid = tid >> 6, lane = tid & 63;
    if (lane == 0)
      #pragma unroll
      for (int c = 0; c < 3; ++c) { redS[wid][c] = sc[c]; redQ[wid][c] = sq[c]; }
    __syncthreads();
    if (tid < 3) {
      int c = tid;
      float s1 = redS[0][c] + redS[1][c] + redS[2][c] + redS[3][c];
      float s2 = redQ[0][c] + redQ[1][c] + redQ[2][c] + redQ[3][c];
      float si_ = inp[0] + inp[1] + inp[2] + lnp[0] + lnp[1] + lnp[2];
      float sb = bnp[0] + bnp[1] + bnp[2];
      float2 ab = ab_from(s1, s2, s1, s2, 1024.f, 1.f, si_, sb, bnw[c], bnb[c], p1p[0]);
      AB[c] = ab.x; AB[3 + c] = ab.y;
    }
    __syncthreads();
  }
  {
    float P2a = p2p[0];
    for (int t = tid; t < 3072; t += 256) {
      int c = t >> 10, p = t & 1023;
      int oy = p >> 5, ox = p & 31;
      int si = ((oy * 12) >> 5) * 12 + ((ox * 12) >> 5);
      buf1[t] = AB[c] * ys0[c * 144 + si] + AB[3 + c] + P2a * u20[c * 144 + si];
    }
  }
  __syncthreads();
  // ---- conv1: (3,32,32) -> S=28, r=64 ----
  {
    const float* w1 = cw + 225;
    const float* w2 = c2w + 225;
    float sc[3] = {0, 0, 0}, sq[3] = {0, 0, 0};
    for (int p = tid; p < 784; p += 256) {
      int py = p / 28, px = p - py * 28;
      float a1[3], a2[3];
      #pragma unroll
      for (int c = 0; c < 3; ++c) { a1[c] = cb[3 + c]; a2[c] = c2b[3 + c]; }
      for (int ci = 0; ci < 3; ++ci)
        #pragma unroll
        for (int ky = 0; ky < 5; ++ky) {
          const float* row = &buf1[ci * 1024 + (py + ky) * 32 + px];
          #pragma unroll
          for (int c = 0; c < 3; ++c)
            #pragma unroll
            for (int kx = 0; kx < 5; ++kx) {
              a1[c] = fmaf(row[kx], w1[c * 75 + ci * 25 + ky * 5 + kx], a1[c]);
              a2[c] = fmaf(row[kx], w2[c * 75 + ci * 25 + ky * 5 + kx], a2[c]);
            }
        }
      int wy = ((py + 1) * 64 + 27) / 28 - (py * 64 + 27) / 28;
      int wx = ((px + 1) * 64 + 27) / 28 - (px * 64 + 27) / 28;
      float wgt = (float)(wy * wx);
      #pragma unroll
      for (int c = 0; c < 3; ++c) {
        ys1[c * 784 + p] = a1[c];
        u21[c * 784 + p] = a2[c];
        sc[c] += a1[c] * wgt;
        sq[c] += a1[c] * a1[c] * wgt;
      }
    }
    #pragma unroll
    for (int off = 32; off; off >>= 1)
      #pragma unroll
      for (int c = 0; c < 3; ++c) {
        sc[c] += __shfl_down(sc[c], off);
        sq[c] += __shfl_down(sq[c], off);
      }
    int wid = tid >> 6, lane = tid & 63;
    __syncthreads();  // protect redS reuse
    if (lane == 0)
      #pragma unroll
      for (int c = 0; c < 3; ++c) { redS[wid][c] = sc[c]; redQ[wid][c] = sq[c]; }
    __syncthreads();
    if (tid < 3) {
      int c = tid;
      float s1 = redS[0][c] + redS[1][c] + redS[2][c] + redS[3][c];
      float s2 = redQ[0][c] + redQ[1][c] + redQ[2][c] + redQ[3][c];
      float si_ = inp[3] + inp[4] + inp[5] + lnp[3] + lnp[4] + lnp[5];
      float sb = bnp[3] + bnp[4] + bnp[5];
      float2 ab = ab_from(s1, s2, s1, s2, 4096.f, 1.f, si_, sb, bnw[3 + c], bnb[3 + c], p1p[1]);
      AB[c] = ab.x; AB[3 + c] = ab.y;
    }
    __syncthreads();
  }
  {
    float P2b = p2p[1];
    for (int t = tid; t < 12288; t += 256) {
      int c = t >> 12, p = t & 4095;
      int oy = p >> 6, ox = p & 63;
      int si = ((oy * 28) >> 6) * 28 + ((ox * 28) >> 6);
      nb0[t] = AB[c] * ys1[c * 784 + si] + AB[3 + c] + P2b * u21[c * 784 + si];
    }
  }
}

// ---- attention HW=1024, pass 1 (fused y2+QKV recompute) ----
__global__ __launch_bounds__(256) void attn_rows_f(
    const float2* __restrict__ yu, const float* __restrict__ sums,
    const float* __restrict__ inp, const float* __restrict__ lnp,
    const float* __restrict__ bnp, const float* __restrict__ bnw,
    const float* __restrict__ bnb, const float* __restrict__ p1p,
    const float* __restrict__ p2p,
    const float* __restrict__ qw, const float* __restrict__ qb,
    const float* __restrict__ kw, const float* __restrict__ kb,
    float* __restrict__ Mp, float* __restrict__ Lp, int S) {
  __shared__ float pA[3], pB[3], pP2v;
  __shared__ float y2s[768], qs[768];
  int bid = blockIdx.x;
  int np = bid & 3; bid >>= 2;
  int mc = bid & 3;
  int b = bid >> 2;
  compute_AB(sums, b, 32, 1024.f, inp, lnp, bnp, bnw, bnb, p1p, p2p, pA, pB, &pP2v);
  size_t ybase = (size_t)b * 3 * S * S;
  for (int t = threadIdx.x; t < 768; t += 256) {
    int c = t >> 8, j = t & 255;
    int n = (np << 8) + j;
    int oy = n >> 5, ox = n & 31;
    int si = ((oy * S) >> 5) * S + ((ox * S) >> 5);
    float2 v = yu[ybase + c * S * S + si];
    y2s[t] = pA[c] * v.x + pB[c] + pP2v * v.y;
  }
  __syncthreads();
  for (int t = threadIdx.x; t < 768; t += 256) {
    int o = t >> 8, j = t & 255;
    qs[t] = qb[o] + qw[o * 3] * y2s[j] + qw[o * 3 + 1] * y2s[256 + j] +
            qw[o * 3 + 2] * y2s[512 + j];
  }
  __syncthreads();
  int m = (mc << 8) + threadIdx.x;
  int oy = m >> 5, ox = m & 31;
  int si = ((oy * S) >> 5) * S + ((ox * S) >> 5);
  float ym[3];
  #pragma unroll
  for (int c = 0; c < 3; ++c) {
    float2 v = yu[ybase + c * S * S + si];
    ym[c] = pA[c] * v.x + pB[c] + pP2v * v.y;
  }
  float k0 = (kb[0] + kw[0] * ym[0] + kw[1] * ym[1] + kw[2] * ym[2]) * LOG2E;
  float k1 = (kb[1] + kw[3] * ym[0] + kw[4] * ym[1] + kw[5] * ym[2]) * LOG2E;
  float k2 = (kb[2] + kw[6] * ym[0] + kw[7] * ym[1] + kw[8] * ym[2]) * LOG2E;
  float mr = -1e30f;
  for (int j = 0; j < 256; ++j) {
    float s = k0 * qs[j] + k1 * qs[256 + j] + k2 * qs[512 + j];
    mr = fmaxf(mr, s);
  }
  float l = 0.f;
  for (int j = 0; j < 256; ++j) {
    float s = k0 * qs[j] + k1 * qs[256 + j] + k2 * qs[512 + j];
    l += exp2f(s - mr);
  }
  int idx = (b * 4 + np) * 1024 + m;
  Mp[idx] = mr;
  Lp[idx] = l;
}

// ---- attention HW=1024, pass 2: partial buffers, NO atomics ----
// block (b,nc,mp) writes partial to aout[mp*32*3072 + b*3072 + c*1024 + n]
__global__ __launch_bounds__(256) void attn_out_f(
    const float2* __restrict__ yu, const float* __restrict__ sums,
    const float* __restrict__ inp, const float* __restrict__ lnp,
    const float* __restrict__ bnp, const float* __restrict__ bnw,
    const float* __restrict__ bnb, const float* __restrict__ p1p,
    const float* __restrict__ p2p,
    const float* __restrict__ qw, const float* __restrict__ qb,
    const float* __restrict__ kw, const float* __restrict__ kb,
    const float* __restrict__ vw, const float* __restrict__ vb,
    const float* __restrict__ Mp, const float* __restrict__ Lp,
    float* __restrict__ aout, int S) {
  __shared__ float pA[3], pB[3], pP2v;
  __shared__ float ym[768], ks[768], vs[768], Ms[256], Ls[256];
  int bid = blockIdx.x;
  int mp = bid & 3; bid >>= 2;
  int nc = bid & 3;
  int b = bid >> 2;
  compute_AB(sums, b, 32, 1024.f, inp, lnp, bnp, bnw, bnb, p1p, p2p, pA, pB, &pP2v);
  size_t ybase = (size_t)b * 3 * S * S;
  for (int t = threadIdx.x; t < 768; t += 256) {
    int c = t >> 8, j = t & 255;
    int m = (mp << 8) + j;
    int oy = m >> 5, ox = m & 31;
    int si = ((oy * S) >> 5) * S + ((ox * S) >> 5);
    float2 v = yu[ybase + c * S * S + si];
    ym[t] = pA[c] * v.x + pB[c] + pP2v * v.y;
  }
  __syncthreads();
  for (int t = threadIdx.x; t < 768; t += 256) {
    int o = t >> 8, j = t & 255;
    float y0 = ym[j], y1 = ym[256 + j], y2v = ym[512 + j];
    ks[t] = (kb[o] + kw[o * 3] * y0 + kw[o * 3 + 1] * y1 + kw[o * 3 + 2] * y2v) * LOG2E;
    vs[t] = vb[o] + vw[o * 3] * y0 + vw[o * 3 + 1] * y1 + vw[o * 3 + 2] * y2v;
  }
  {
    int t = threadIdx.x;
    int m = (mp << 8) + t;
    float M0 = Mp[(b * 4 + 0) * 1024 + m], M1 = Mp[(b * 4 + 1) * 1024 + m];
    float M2 = Mp[(b * 4 + 2) * 1024 + m], M3 = Mp[(b * 4 + 3) * 1024 + m];
    float L0 = Lp[(b * 4 + 0) * 1024 + m], L1 = Lp[(b * 4 + 1) * 1024 + m];
    float L2 = Lp[(b * 4 + 2) * 1024 + m], L3 = Lp[(b * 4 + 3) * 1024 + m];
    float MM = fmaxf(fmaxf(M0, M1), fmaxf(M2, M3));
    float LL = L0 * exp2f(M0 - MM) + L1 * exp2f(M1 - MM) +
               L2 * exp2f(M2 - MM) + L3 * exp2f(M3 - MM);
    Ms[t] = MM;
    Ls[t] = 1.0f / LL;
  }
  __syncthreads();
  int n = (nc << 8) + threadIdx.x;
  int oy = n >> 5, ox = n & 31;
  int si = ((oy * S) >> 5) * S + ((ox * S) >> 5);
  float yn[3];
  #pragma unroll
  for (int c = 0; c < 3; ++c) {
    float2 v = yu[ybase + c * S * S + si];
    yn[c] = pA[c] * v.x + pB[c] + pP2v * v.y;
  }
  float q0 = qb[0] + qw[0] * yn[0] + qw[1] * yn[1] + qw[2] * yn[2];
  float q1 = qb[1] + qw[3] * yn[0] + qw[4] * yn[1] + qw[5] * yn[2];
  float q2 = qb[2] + qw[6] * yn[0] + qw[7] * yn[1] + qw[8] * yn[2];
  float a0 = 0.f, a1 = 0.f, a2 = 0.f;
  for (int j = 0; j < 256; ++j) {
    float s = ks[j] * q0 + ks[256 + j] * q1 + ks[512 + j] * q2;
    float w = exp2f(s - Ms[j]) * Ls[j];
    a0 = fmaf(vs[j], w, a0);
    a1 = fmaf(vs[256 + j], w, a1);
    a2 = fmaf(vs[512 + j], w, a2);
  }
  if (mp == 0) { a0 += yn[0]; a1 += yn[1]; a2 += yn[2]; }
  size_t o0 = (size_t)mp * 98304 + (size_t)b * 3072 + n;
  aout[o0] = a0;
  aout[o0 + 1024] = a1;
  aout[o0 + 2048] = a2;
}

// ---- attention HW=256 fused with the FOLLOWING 5x5 conv (16x16 image in LDS) ----
__global__ __launch_bounds__(256) void attn256_conv(
    const float2* __restrict__ yu, const float* __restrict__ sums,
    const float* __restrict__ inp, const float* __restrict__ lnp,
    const float* __restrict__ bnp, const float* __restrict__ bnw,
    const float* __restrict__ bnb, const float* __restrict__ p1p,
    const float* __restrict__ p2p,
    const float* __restrict__ qw, const float* __restrict__ qb,
    const float* __restrict__ kw, const float* __restrict__ kb,
    const float* __restrict__ vw, const float* __restrict__ vb,
    const float* __restrict__ cw1, const float* __restrict__ cb1,
    const float* __restrict__ cw2, const float* __restrict__ cb2,
    float2* __restrict__ yu_out, float* __restrict__ sums_out, int S, int r) {
  __shared__ float pA[3], pB[3], pP2v;
  __shared__ float y2s[768], qs[768], ks[768], vs[768], Ms[256], Ls[256];
  int b = blockIdx.x;
  compute_AB(sums, b, 32, 256.f, inp, lnp, bnp, bnw, bnb, p1p, p2p, pA, pB, &pP2v);
  size_t ybase = (size_t)b * 3 * S * S;
  for (int t = threadIdx.x; t < 768; t += 256) {
    int c = t >> 8, p = t & 255;
    int oy = p >> 4, ox = p & 15;
    int si = ((oy * S) >> 4) * S + ((ox * S) >> 4);
    float2 v = yu[ybase + c * S * S + si];
    y2s[t] = pA[c] * v.x + pB[c] + pP2v * v.y;
  }
  __syncthreads();
  for (int t = threadIdx.x; t < 768; t += 256) {
    int o = t >> 8, p = t & 255;
    float y0 = y2s[p], y1 = y2s[256 + p], y2v = y2s[512 + p];
    qs[t] = qb[o] + qw[o * 3] * y0 + qw[o * 3 + 1] * y1 + qw[o * 3 + 2] * y2v;
    ks[t] = (kb[o] + kw[o * 3] * y0 + kw[o * 3 + 1] * y1 + kw[o * 3 + 2] * y2v) * LOG2E;
    vs[t] = vb[o] + vw[o * 3] * y0 + vw[o * 3 + 1] * y1 + vw[o * 3 + 2] * y2v;
  }
  __syncthreads();
  {
    int m = threadIdx.x;
    float kx = ks[m], ky = ks[256 + m], kz = ks[512 + m];
    float mr = -1e30f;
    for (int j = 0; j < 256; ++j) {
      float s = kx * qs[j] + ky * qs[256 + j] + kz * qs[512 + j];
      mr = fmaxf(mr, s);
    }
    float l = 0.f;
    for (int j = 0; j < 256; ++j) {
      float s = kx * qs[j] + ky * qs[256 + j] + kz * qs[512 + j];
      l += exp2f(s - mr);
    }
    Ms[m] = mr;
    Ls[m] = 1.0f / l;
  }
  __syncthreads();
  {
    int n = threadIdx.x;
    float q0 = qs[n], q1 = qs[256 + n], q2 = qs[512 + n];
    float a0 = 0.f, a1 = 0.f, a2 = 0.f;
    for (int j = 0; j < 256; ++j) {
      float s = ks[j] * q0 + ks[256 + j] * q1 + ks[512 + j] * q2;
      float w = exp2f(s - Ms[j]) * Ls[j];
      a0 = fmaf(vs[j], w, a0);
      a1 = fmaf(vs[256 + j], w, a1);
      a2 = fmaf(vs[512 + j], w, a2);
    }
    y2s[n] += a0;
    y2s[256 + n] += a1;
    y2s[512 + n] += a2;
  }
  __syncthreads();
  // ---- conv 5x5 valid on the 16x16 image in y2s -> 12x12 grid ----
  float sc[3] = {0.f, 0.f, 0.f}, sq[3] = {0.f, 0.f, 0.f};
  int p = threadIdx.x;
  if (p < 144) {
    int py = p / 12, px = p - py * 12;
    float a1[3], a2[3];
    #pragma unroll
    for (int c = 0; c < 3; ++c) { a1[c] = cb1[c]; a2[c] = cb2[c]; }
    #pragma unroll
    for (int ci = 0; ci < 3; ++ci) {
      #pragma unroll
      for (int ky = 0; ky < 5; ++ky) {
        const float* row = &y2s[ci * 256 + (py + ky) * 16 + px];
        #pragma unroll
        for (int c = 0; c < 3; ++c) {
          #pragma unroll
          for (int kx = 0; kx < 5; ++kx) {
            a1[c] = fmaf(row[kx], cw1[c * 75 + ci * 25 + ky * 5 + kx], a1[c]);
            a2[c] = fmaf(row[kx], cw2[c * 75 + ci * 25 + ky * 5 + kx], a2[c]);
          }
        }
      }
    }
    float wy = (float)(((py + 1) * r + 11) / 12 - (py * r + 11) / 12);
    float wx = (float)(((px + 1) * r + 11) / 12 - (px * r + 11) / 12);
    float wgt = wy * wx;
    #pragma unroll
    for (int c = 0; c < 3; ++c) {
      yu_out[(size_t)(b * 3 + c) * 144 + p] = make_float2(a1[c], a2[c]);
      sc[c] += a1[c] * wgt;
      sq[c] += a1[c] * a1[c] * wgt;
    }
  }
  STATS_REDUCE_ATOMIC(sc, sq, sums_out, b)
}

// ---- final: affine + p2*u2 + tanh -> out ----
__global__ __launch_bounds__(256) void elem_final(
    const float2* __restrict__ yu, const float* __restrict__ sums,
    const float* __restrict__ inp, const float* __restrict__ lnp,
    const float* __restrict__ bnp, const float* __restrict__ bnw,
    const float* __restrict__ bnb, const float* __restrict__ p1p,
    const float* __restrict__ p2p, float* __restrict__ out, int S) {
  __shared__ float pA[3], pB[3], pP2v;
  int n = blockIdx.x >> 8;
  int p = ((blockIdx.x & 255) << 8) + threadIdx.x;
  compute_AB(sums, n, 32, 65536.f, inp, lnp, bnp, bnw, bnb, p1p, p2p, pA, pB, &pP2v);
  int oy = p >> 8, ox = p & 255;
  int si = ((oy * S) >> 8) * S + ((ox * S) >> 8);
  size_t ybase = (size_t)n * 3 * S * S;
  #pragma unroll
  for (int c = 0; c < 3; ++c) {
    float2 v = yu[ybase + c * S * S + si];
    out[((size_t)(n * 3 + c) << 16) + p] = tanhf(pA[c] * v.x + pB[c] + pP2v * v.y);
  }
}

#define NPX nullptr, nullptr, nullptr, nullptr, nullptr, nullptr, nullptr, \
            nullptr, nullptr, 0, 0, 0

extern "C" void kernel_launch(void* const* d_in, const int* in_sizes, int n_in,
                              void* d_out, int out_size, void* d_ws, size_t ws_size,
                              hipStream_t stream) {
  const float* x       = (const float*)d_in[0];
  const float* noise_z = (const float*)d_in[1];
  const float* lin_w   = (const float*)d_in[2];
  const float* lin_b   = (const float*)d_in[3];
  const float* conv_w  = (const float*)d_in[4];
  const float* conv_b  = (const float*)d_in[5];
  const float* conv2_w = (const float*)d_in[6];
  const float* conv2_b = (const float*)d_in[7];
  const float* q_w     = (const float*)d_in[8];
  const float* q_b     = (const float*)d_in[9];
  const float* k_w     = (const float*)d_in[10];
  const float* k_b     = (const float*)d_in[11];
  const float* v_w     = (const float*)d_in[12];
  const float* v_b     = (const float*)d_in[13];
  const float* in_p    = (const float*)d_in[14];
  const float* ln_p    = (const float*)d_in[15];
  const float* bn_p    = (const float*)d_in[16];
  const float* bn_w    = (const float*)d_in[17];
  const float* bn_b    = (const float*)d_in[18];
  const float* p1      = (const float*)d_in[19];
  const float* p2      = (const float*)d_in[20];
  float* out = (float*)d_out;

  float* ws = (float*)d_ws;
  size_t off = 0;
  auto alloc = [&](size_t nf) { float* p = ws + off; off += nf; return p; };
  float* SUMS = alloc(2304);
  float* P45  = alloc(393216);   // attn5 partials (4 x 32 x 3072)
  float* P48  = alloc(393216);   // attn8 partials
  float2* YU2 = (float2*)alloc(12192768);  // 252^2 * 96 * 2
  float2* PA  = (float2*)alloc(3145728);
  float2* PB  = (float2*)alloc(3145728);
  float* Mp   = alloc(131072);
  float* Lp   = alloc(131072);
  float* NB0  = alloc(12288);
  float* LIN  = alloc(768);

  hipMemsetAsync(SUMS, 0, 2304 * sizeof(float), stream);

  const float* nul = nullptr;
  const float2* nul2 = nullptr;

  // noise path: parallel linear, then small conv pipeline (blocks 0,1) -> NB0
  linear_wave<<<192, 256, 0, stream>>>(noise_z, lin_w, lin_b, LIN);
  noise_rest<<<1, 256, 0, stream>>>(LIN, conv_w, conv_b, conv2_w, conv2_b,
      in_p, ln_p, bn_p, bn_w, bn_b, p1, p2, NB0);

  // conv2: x -> YU2 (S=252, r=256), async global->LDS staging
  conv_up_t<false, false><<<2048, 256, 0, stream>>>(x, nul2, YU2, conv_w + 450,
      conv_b + 6, conv2_w + 450, conv2_b + 6, SUMS + 384, 256, 252, 256, 4, 16,
      NPX);
  // conv3: fused(b2) YU2 -> PA (S=128); prev Sp=252, logrp=8 (true gather)
  conv_dn_t<true, false, false><<<2048, 256, 0, stream>>>(nul, YU2, PA,
      conv_w + 675, conv_b + 9, conv2_w + 675, conv2_b + 9, SUMS + 576,
      256, 128, 252, 7, 4, 16,
      SUMS + 384, in_p + 6, ln_p + 6, bn_p + 6, bn_w + 6, bn_b + 6, p1 + 2,
      p2 + 2, nul, 32, 252, 8);
  // conv4: fused(b3) PA -> PB (S=64); prev identity
  conv_dn_t<true, true, false><<<512, 256, 0, stream>>>(nul, PA, PB,
      conv_w + 900, conv_b + 12, conv2_w + 900, conv2_b + 12, SUMS + 768,
      128, 64, 124, 6, 2, 8,
      SUMS + 576, in_p + 9, ln_p + 9, bn_p + 9, bn_w + 9, bn_b + 9, p1 + 3,
      p2 + 3, nul, 32, 128, 7);
  // conv5: fused(b4)+noise PB -> PA (S=32); prev identity
  conv_dn_t<true, true, false><<<128, 256, 0, stream>>>(nul, PB, PA,
      conv_w + 1125, conv_b + 15, conv2_w + 1125, conv2_b + 15, SUMS + 960,
      64, 32, 60, 5, 1, 4,
      SUMS + 768, in_p + 12, ln_p + 12, bn_p + 12, bn_w + 12, bn_b + 12, p1 + 4,
      p2 + 4, NB0, 32, 64, 6);
  // attn5 (HW=1024) on PA (S=32) -> partials P45
  attn_rows_f<<<512, 256, 0, stream>>>(PA, SUMS + 960, in_p + 15, ln_p + 15,
      bn_p + 15, bn_w + 15, bn_b + 15, p1 + 5, p2 + 5,
      q_w + 45, q_b + 15, k_w + 45, k_b + 15, Mp, Lp, 32);
  attn_out_f<<<512, 256, 0, stream>>>(PA, SUMS + 960, in_p + 15, ln_p + 15,
      bn_p + 15, bn_w + 15, bn_b + 15, p1 + 5, p2 + 5,
      q_w + 45, q_b + 15, k_w + 45, k_b + 15, v_w + 45, v_b + 15, Mp, Lp, P45, 32);
  // conv6: SUM4 staging from P45 -> PB (S=16)
  conv_dn_t<false, false, true><<<64, 256, 0, stream>>>(P45, nul2, PB,
      conv_w + 1350, conv_b + 18, conv2_w + 1350, conv2_b + 18, SUMS + 1152,
      32, 16, 28, 4, 1, 2, NPX);
  // attn6 (HW=256) on PB (S=16) + conv7 (r=16) -> PA (S=12)
  attn256_conv<<<32, 256, 0, stream>>>(PB, SUMS + 1152, in_p + 18, ln_p + 18,
      bn_p + 18, bn_w + 18, bn_b + 18, p1 + 6, p2 + 6,
      q_w + 54, q_b + 18, k_w + 54, k_b + 18, v_w + 54, v_b + 18,
      conv_w + 1575, conv_b + 21, conv2_w + 1575, conv2_b + 21,
      PA, SUMS + 1344, 16, 16);
  // attn7 (HW=256) on PA (S=12) + conv8 (r=32) -> PB (S=12)
  attn256_conv<<<32, 256, 0, stream>>>(PA, SUMS + 1344, in_p + 21, ln_p + 21,
      bn_p + 21, bn_w + 21, bn_b + 21, p1 + 7, p2 + 7,
      q_w + 63, q_b + 21, k_w + 63, k_b + 21, v_w + 63, v_b + 21,
      conv_w + 1800, conv_b + 24, conv2_w + 1800, conv2_b + 24,
      PB, SUMS + 1536, 12, 32);
  // attn8 (HW=1024) on PB (S=12) -> partials P48
  attn_rows_f<<<512, 256, 0, stream>>>(PB, SUMS + 1536, in_p + 24, ln_p + 24,
      bn_p + 24, bn_w + 24, bn_b + 24, p1 + 8, p2 + 8,
      q_w + 72, q_b + 24, k_w + 72, k_b + 24, Mp, Lp, 12);
  attn_out_f<<<512, 256, 0, stream>>>(PB, SUMS + 1536, in_p + 24, ln_p + 24,
      bn_p + 24, bn_w + 24, bn_b + 24, p1 + 8, p2 + 8,
      q_w + 72, q_b + 24, k_w + 72, k_b + 24, v_w + 72, v_b + 24, Mp, Lp, P48, 12);
  // conv9: SUM4 staging from P48 -> PA (S=28, r=64)
  conv_up_t<false, true><<<64, 256, 0, stream>>>(P48, nul2, PA, conv_w + 2025,
      conv_b + 27, conv2_w + 2025, conv2_b + 27, SUMS + 1728, 32, 28, 64, 1, 2,
      NPX);
  // conv10: fused(b9) PA -> PB (S=60); prev Sp=28, logrp=6
  conv_up_t<true, false><<<128, 256, 0, stream>>>(nul, PA, PB, conv_w + 2250,
      conv_b + 30, conv2_w + 2250, conv2_b + 30, SUMS + 1920, 64, 60, 128, 1, 4,
      SUMS + 1728, in_p + 27, ln_p + 27, bn_p + 27, bn_w + 27, bn_b + 27,
      p1 + 9, p2 + 9, nul, 32, 28, 6);
  // conv11: fused(b10) PB -> YU2 (S=124); prev Sp=60, logrp=7
  conv_up_t<true, false><<<512, 256, 0, stream>>>(nul, PB, YU2, conv_w + 2475,
      conv_b + 33, conv2_w + 2475, conv2_b + 33, SUMS + 2112, 128, 124, 256, 2, 8,
      SUMS + 1920, in_p + 30, ln_p + 30, bn_p + 30, bn_w + 30, bn_b + 30,
      p1 + 10, p2 + 10, nul, 32, 60, 7);
  // final: tanh -> out
  elem_final<<<8192, 256, 0, stream>>>(YU2, SUMS + 2112, in_p + 33, ln_p + 33,
      bn_p + 33, bn_w + 33, bn_b + 33, p1 + 11, p2 + 11, out, 124);
}

// Round 10
// 502.708 us; speedup vs baseline: 1.7546x; 1.0546x over previous
//
#include <hip/hip_runtime.h>
#include <math.h>

#define EPS 1e-5f
#define LOG2E 1.44269504088896340736f

#define AS_GLOBAL __attribute__((address_space(1)))
#define AS_LDS    __attribute__((address_space(3)))

// ---- shared affine-fold helper: A,B from sums (instance+batch norm + p1) ----
__device__ __forceinline__ float2 ab_from(float s1, float s2, float bs, float bs2,
    float hw, float Nf, float si_, float sb, float bnw_c, float bnb_c, float p1v) {
  float inv = 1.0f / hw;
  float mi = s1 * inv, vi = s2 * inv - mi * mi;
  float ri = rsqrtf(vi + EPS);
  float invb = 1.0f / (Nf * hw);
  float mb = bs * invb, vb = bs2 * invb - mb * mb;
  float rb = rsqrtf(vb + EPS);
  float A = 1.0f + si_ * ri + sb * rb * bnw_c;
  float B = -(si_ * ri * mi + sb * rb * bnw_c * mb) + sb * bnb_c;
  return make_float2(A * p1v, B * p1v);
}

__device__ __forceinline__ void compute_AB(
    const float* __restrict__ sums, int n, int N, float hw,
    const float* __restrict__ inp, const float* __restrict__ lnp,
    const float* __restrict__ bnp, const float* __restrict__ bnw,
    const float* __restrict__ bnb, const float* __restrict__ p1p,
    const float* __restrict__ p2p, float* pA, float* pB, float* pP2) {
  if (threadIdx.x == 0) *pP2 = p2p[0];
  if (threadIdx.x < 3) {
    int c = threadIdx.x;
    float si_ = inp[0] + inp[1] + inp[2] + lnp[0] + lnp[1] + lnp[2];
    float sb = bnp[0] + bnp[1] + bnp[2];
    float s1 = sums[2 * (n * 3 + c)], s2 = sums[2 * (n * 3 + c) + 1];
    float bs = 0.f, bs2 = 0.f;
    for (int nn = 0; nn < N; ++nn) {
      bs += sums[2 * (nn * 3 + c)];
      bs2 += sums[2 * (nn * 3 + c) + 1];
    }
    float2 ab = ab_from(s1, s2, bs, bs2, hw, (float)N, si_, sb, bnw[c], bnb[c], p1p[0]);
    pA[c] = ab.x;
    pB[c] = ab.y;
  }
  __syncthreads();
}

// stats block-reduce (256 threads, all must participate)
#define STATS_REDUCE_ATOMIC(scv, sqv, sumsp, nvar)                            \
  {                                                                           \
    _Pragma("unroll")                                                         \
    for (int off = 32; off; off >>= 1) {                                      \
      _Pragma("unroll")                                                       \
      for (int c = 0; c < 3; ++c) {                                           \
        scv[c] += __shfl_down(scv[c], off);                                   \
        sqv[c] += __shfl_down(sqv[c], off);                                   \
      }                                                                       \
    }                                                                         \
    __shared__ float redS[4][3], redQ[4][3];                                  \
    int wid = threadIdx.x >> 6, lane = threadIdx.x & 63;                      \
    if (lane == 0) {                                                          \
      _Pragma("unroll")                                                       \
      for (int c = 0; c < 3; ++c) { redS[wid][c] = scv[c]; redQ[wid][c] = sqv[c]; } \
    }                                                                         \
    __syncthreads();                                                          \
    if (threadIdx.x < 3) {                                                    \
      int c = threadIdx.x;                                                    \
      atomicAdd(&sumsp[2 * ((nvar) * 3 + c)],                                 \
                redS[0][c] + redS[1][c] + redS[2][c] + redS[3][c]);           \
      atomicAdd(&sumsp[2 * ((nvar) * 3 + c) + 1],                             \
                redQ[0][c] + redQ[1][c] + redQ[2][c] + redQ[3][c]);           \
    }                                                                         \
  }

// ---- LDS-tiled upsample conv (S==hc): 64x16 tile, TX=4, float2 out ----
template <bool FUSED, bool SUM4>
__global__ __launch_bounds__(256) void conv_up_t(
    const float* __restrict__ in, const float2* __restrict__ pyu,
    float2* __restrict__ yu,
    const float* __restrict__ w1, const float* __restrict__ b1,
    const float* __restrict__ w2, const float* __restrict__ b2,
    float* __restrict__ sums, int Hin, int S, int r, int tilesX, int tilesY,
    const float* __restrict__ psums,
    const float* __restrict__ pinp, const float* __restrict__ plnp,
    const float* __restrict__ pbnp, const float* __restrict__ pbnw,
    const float* __restrict__ pbnb, const float* __restrict__ pp1,
    const float* __restrict__ pp2, const float* __restrict__ pnoise,
    int pN, int Sp, int logrp) {
  const int TW = 64, TH = 16, IW = 68, IH = 20;
  __shared__ float lin[3 * IH * IW];
  __shared__ float pA[3], pB[3], pP2v;
  int tpi = tilesX * tilesY;
  int n = blockIdx.x / tpi;
  int trem = blockIdx.x - n * tpi;
  int tyB = trem / tilesX, txB = trem - tyB * tilesX;
  int px0 = txB * TW, py0 = tyB * TH;
  const float* inb = in + (size_t)n * 3 * Hin * Hin;
  if (FUSED) {
    compute_AB(psums, n, pN, (float)(Hin * Hin), pinp, plnp, pbnp, pbnw, pbnb,
               pp1, pp2, pA, pB, &pP2v);
    size_t pbase = (size_t)n * 3 * Sp * Sp;
    for (int t = threadIdx.x; t < 3 * IH * IW; t += 256) {
      int cc = t / (IH * IW);
      int rem = t - cc * IH * IW;
      int rr = rem / IW, col = rem - rr * IW;
      int gy = py0 + rr; gy = gy < Hin ? gy : Hin - 1;
      int gx = px0 + col; gx = gx < Hin ? gx : Hin - 1;
      int si = ((gy * Sp) >> logrp) * Sp + ((gx * Sp) >> logrp);
      float2 v = pyu[pbase + cc * Sp * Sp + si];
      float val = pA[cc] * v.x + pB[cc] + pP2v * v.y;
      if (pnoise) val += pnoise[((size_t)cc * Hin + gy) * Hin + gx];
      lin[t] = val;
    }
  } else if (SUM4) {
    size_t ps = (size_t)96 * Hin * Hin;
    for (int t = threadIdx.x; t < 3 * IH * IW; t += 256) {
      int cc = t / (IH * IW);
      int rem = t - cc * IH * IW;
      int rr = rem / IW, col = rem - rr * IW;
      int gy = py0 + rr; gy = gy < Hin ? gy : Hin - 1;
      int gx = px0 + col; gx = gx < Hin ? gx : Hin - 1;
      size_t idx = ((size_t)(n * 3 + cc) * Hin + gy) * Hin + gx;
      lin[t] = in[idx] + in[idx + ps] + in[idx + 2 * ps] + in[idx + 3 * ps];
    }
  } else {
    if (px0 + IW <= Hin && py0 + IH <= Hin) {
      for (int t4 = threadIdx.x; t4 < 3 * IH * 17; t4 += 256) {
        int cc = t4 / (IH * 17);
        int rem = t4 - cc * (IH * 17);
        int rr = rem / 17, j = rem - rr * 17;
        const float* src = inb + ((size_t)cc * Hin + py0 + rr) * Hin + px0 + 4 * j;
        int base = t4 - (threadIdx.x & 63);  // wave-uniform float4 index
        __builtin_amdgcn_global_load_lds(
            (const AS_GLOBAL void*)src,
            (AS_LDS void*)(lin + 4 * base), 16, 0, 0);
      }
    } else {
      for (int t = threadIdx.x; t < 3 * IH * IW; t += 256) {
        int cc = t / (IH * IW);
        int rem = t - cc * IH * IW;
        int rr = rem / IW, col = rem - rr * IW;
        int gy = py0 + rr; gy = gy < Hin ? gy : Hin - 1;
        int gx = px0 + col; gx = gx < Hin ? gx : Hin - 1;
        lin[t] = inb[((size_t)cc * Hin + gy) * Hin + gx];
      }
    }
  }
  __syncthreads();
  int tx = threadIdx.x & 15, ty = threadIdx.x >> 4;
  int lx0 = tx * 4;
  int px = px0 + lx0, py = py0 + ty;
  float a1[3][4], a2[3][4];
  #pragma unroll
  for (int c = 0; c < 3; ++c) {
    float bb1 = b1[c], bb2 = b2[c];
    #pragma unroll
    for (int x = 0; x < 4; ++x) { a1[c][x] = bb1; a2[c][x] = bb2; }
  }
  #pragma unroll 1
  for (int ci = 0; ci < 3; ++ci) {
    const float* lrow = lin + ci * IH * IW + ty * IW + lx0;
    const float* wp1 = w1 + ci * 25;
    const float* wp2 = w2 + ci * 25;
    #pragma unroll
    for (int ky = 0; ky < 5; ++ky) {
      float v[8];
      #pragma unroll
      for (int j = 0; j < 8; ++j) v[j] = lrow[ky * IW + j];
      #pragma unroll
      for (int c = 0; c < 3; ++c) {
        #pragma unroll
        for (int kx = 0; kx < 5; ++kx) {
          float wa = wp1[c * 75 + ky * 5 + kx];
          float wb = wp2[c * 75 + ky * 5 + kx];
          #pragma unroll
          for (int x = 0; x < 4; ++x) {
            a1[c][x] = fmaf(v[kx + x], wa, a1[c][x]);
            a2[c][x] = fmaf(v[kx + x], wb, a2[c][x]);
          }
        }
      }
    }
  }
  float sc[3] = {0.f, 0.f, 0.f}, sq[3] = {0.f, 0.f, 0.f};
  bool valid = (py < S) && (px < S);
  if (valid) {
    int hc = S;
    float wy = (float)(((py + 1) * r + hc - 1) / hc - (py * r + hc - 1) / hc);
    float wx[4];
    #pragma unroll
    for (int x = 0; x < 4; ++x) {
      int pxx = px + x;
      wx[x] = (float)(((pxx + 1) * r + hc - 1) / hc - (pxx * r + hc - 1) / hc);
    }
    #pragma unroll
    for (int c = 0; c < 3; ++c) {
      size_t idx = ((size_t)(n * 3 + c) * S + py) * S + px;
      float2* yp = yu + idx;
      *reinterpret_cast<float4*>(yp) =
          make_float4(a1[c][0], a2[c][0], a1[c][1], a2[c][1]);
      *reinterpret_cast<float4*>(yp + 2) =
          make_float4(a1[c][2], a2[c][2], a1[c][3], a2[c][3]);
      #pragma unroll
      for (int x = 0; x < 4; ++x) {
        float wgt = wy * wx[x];
        sc[c] += a1[c][x] * wgt;
        sq[c] += a1[c][x] * a1[c][x] * wgt;
      }
    }
  }
  STATS_REDUCE_ATOMIC(sc, sq, sums, n)
}

// ---- LDS-tiled downsample conv (ratio<2.05): 32x8 tile, float2 out ----
template <bool FUSED, bool IDENT, bool SUM4>
__global__ __launch_bounds__(256) void conv_dn_t(
    const float* __restrict__ in, const float2* __restrict__ pyu,
    float2* __restrict__ yu,
    const float* __restrict__ w1, const float* __restrict__ b1,
    const float* __restrict__ w2, const float* __restrict__ b2,
    float* __restrict__ sums, int Hin, int S, int hc, int logr,
    int tilesX, int tilesY,
    const float* __restrict__ psums,
    const float* __restrict__ pinp, const float* __restrict__ plnp,
    const float* __restrict__ pbnp, const float* __restrict__ pbnw,
    const float* __restrict__ pbnb, const float* __restrict__ pp1,
    const float* __restrict__ pp2, const float* __restrict__ pnoise,
    int pN, int Sp, int logrp) {
  const int TW = 32, TH = 8, IW = 68, IH = 20;
  __shared__ float lin[3 * IH * IW];
  __shared__ float pA[3], pB[3], pP2v;
  int tpi = tilesX * tilesY;
  int n = blockIdx.x / tpi;
  int trem = blockIdx.x - n * tpi;
  int tyB = trem / tilesX, txB = trem - tyB * tilesX;
  int px0 = txB * TW, py0 = tyB * TH;
  int sy0 = (py0 * hc) >> logr, sx0 = (px0 * hc) >> logr;
  const float* inb = in + (size_t)n * 3 * Hin * Hin;
  if (FUSED) {
    compute_AB(psums, n, pN, (float)(Hin * Hin), pinp, plnp, pbnp, pbnw, pbnb,
               pp1, pp2, pA, pB, &pP2v);
    size_t pbase = (size_t)n * 3 * Sp * Sp;
    for (int t = threadIdx.x; t < 3 * IH * IW; t += 256) {
      int cc = t / (IH * IW);
      int rem = t - cc * IH * IW;
      int rr = rem / IW, col = rem - rr * IW;
      int gy = sy0 + rr; gy = gy < Hin ? gy : Hin - 1;
      int gx = sx0 + col; gx = gx < Hin ? gx : Hin - 1;
      int si;
      if (IDENT) si = gy * Sp + gx;
      else si = ((gy * Sp) >> logrp) * Sp + ((gx * Sp) >> logrp);
      float2 v = pyu[pbase + cc * Sp * Sp + si];
      float val = pA[cc] * v.x + pB[cc] + pP2v * v.y;
      if (pnoise) val += pnoise[((size_t)cc * Hin + gy) * Hin + gx];
      lin[t] = val;
    }
  } else if (SUM4) {
    size_t ps = (size_t)96 * Hin * Hin;
    for (int t = threadIdx.x; t < 3 * IH * IW; t += 256) {
      int cc = t / (IH * IW);
      int rem = t - cc * IH * IW;
      int rr = rem / IW, col = rem - rr * IW;
      int gy = sy0 + rr; gy = gy < Hin ? gy : Hin - 1;
      int gx = sx0 + col; gx = gx < Hin ? gx : Hin - 1;
      size_t idx = ((size_t)(n * 3 + cc) * Hin + gy) * Hin + gx;
      lin[t] = in[idx] + in[idx + ps] + in[idx + 2 * ps] + in[idx + 3 * ps];
    }
  } else {
    for (int t = threadIdx.x; t < 3 * IH * IW; t += 256) {
      int cc = t / (IH * IW);
      int rem = t - cc * IH * IW;
      int rr = rem / IW, col = rem - rr * IW;
      int gy = sy0 + rr; gy = gy < Hin ? gy : Hin - 1;
      int gx = sx0 + col; gx = gx < Hin ? gx : Hin - 1;
      lin[t] = inb[((size_t)cc * Hin + gy) * Hin + gx];
    }
  }
  __syncthreads();
  int tx = threadIdx.x & 31, ty = threadIdx.x >> 5;
  int px = px0 + tx, py = py0 + ty;
  int sxl = ((px * hc) >> logr) - sx0;
  int syl = ((py * hc) >> logr) - sy0;
  float a1[3], a2[3];
  #pragma unroll
  for (int c = 0; c < 3; ++c) { a1[c] = b1[c]; a2[c] = b2[c]; }
  #pragma unroll
  for (int ci = 0; ci < 3; ++ci) {
    const float* lrow = lin + ci * IH * IW + syl * IW + sxl;
    const float* wp1 = w1 + ci * 25;
    const float* wp2 = w2 + ci * 25;
    #pragma unroll
    for (int ky = 0; ky < 5; ++ky) {
      float v[5];
      #pragma unroll
      for (int j = 0; j < 5; ++j) v[j] = lrow[ky * IW + j];
      #pragma unroll
      for (int c = 0; c < 3; ++c) {
        #pragma unroll
        for (int kx = 0; kx < 5; ++kx) {
          a1[c] = fmaf(v[kx], wp1[c * 75 + ky * 5 + kx], a1[c]);
          a2[c] = fmaf(v[kx], wp2[c * 75 + ky * 5 + kx], a2[c]);
        }
      }
    }
  }
  float sc[3] = {0.f, 0.f, 0.f}, sq[3] = {0.f, 0.f, 0.f};
  bool valid = (py < S) && (px < S);
  if (valid) {
    #pragma unroll
    for (int c = 0; c < 3; ++c) {
      size_t idx = ((size_t)(n * 3 + c) * S + py) * S + px;
      yu[idx] = make_float2(a1[c], a2[c]);
      sc[c] += a1[c];
      sq[c] += a1[c] * a1[c];
    }
  }
  STATS_REDUCE_ATOMIC(sc, sq, sums, n)
}

// ---- Linear 512->768: one wave per output row, coalesced float4 ----
__global__ __launch_bounds__(256) void linear_wave(
    const float* __restrict__ z, const float* __restrict__ w,
    const float* __restrict__ b, float* __restrict__ out) {
  int row = (blockIdx.x << 2) + (threadIdx.x >> 6);
  int lane = threadIdx.x & 63;
  const float4* wr = reinterpret_cast<const float4*>(w + (size_t)row * 512);
  const float4* zz = reinterpret_cast<const float4*>(z);
  float acc = 0.f;
  #pragma unroll
  for (int i = 0; i < 2; ++i) {
    float4 wv = wr[lane + 64 * i];
    float4 zv = zz[lane + 64 * i];
    acc += wv.x * zv.x + wv.y * zv.y + wv.z * zv.z + wv.w * zv.w;
  }
  #pragma unroll
  for (int off = 32; off; off >>= 1) acc += __shfl_down(acc, off);
  if (lane == 0) out[row] = acc + b[row];
}

// ---- noise conv path (blocks 0,1) in one block, L0 from global ----
__global__ __launch_bounds__(256) void noise_rest(
    const float* __restrict__ L0g,
    const float* __restrict__ cw, const float* __restrict__ cb,
    const float* __restrict__ c2w, const float* __restrict__ c2b,
    const float* __restrict__ inp, const float* __restrict__ lnp,
    const float* __restrict__ bnp, const float* __restrict__ bnw,
    const float* __restrict__ bnb, const float* __restrict__ p1p,
    const float* __restrict__ p2p, float* __restrict__ nb0) {
  __shared__ float L0[768];
  __shared__ float ys0[432], u20[432];
  __shared__ float buf1[3072];
  __shared__ float ys1[2352], u21[2352];
  __shared__ float redS[4][3], redQ[4][3];
  __shared__ float AB[6];
  int tid = threadIdx.x;
  for (int t = tid; t < 768; t += 256) L0[t] = L0g[t];
  __syncthreads();
  // ---- conv0: (3,16,16) -> S=12, r=32 ----
  {
    float sc[3] = {0, 0, 0}, sq[3] = {0, 0, 0};
    for (int p = tid; p < 144; p += 256) {
      int py = p / 12, px = p - py * 12;
      float a1[3], a2[3];
      #pragma unroll
      for (int c = 0; c < 3; ++c) { a1[c] = cb[c]; a2[c] = c2b[c]; }
      for (int ci = 0; ci < 3; ++ci)
        #pragma unroll
        for (int ky = 0; ky < 5; ++ky) {
          const float* row = &L0[ci * 256 + (py + ky) * 16 + px];
          #pragma unroll
          for (int c = 0; c < 3; ++c)
            #pragma unroll
            for (int kx = 0; kx < 5; ++kx) {
              a1[c] = fmaf(row[kx], cw[c * 75 + ci * 25 + ky * 5 + kx], a1[c]);
              a2[c] = fmaf(row[kx], c2w[c * 75 + ci * 25 + ky * 5 + kx], a2[c]);
            }
        }
      int wy = ((py + 1) * 32 + 11) / 12 - (py * 32 + 11) / 12;
      int wx = ((px + 1) * 32 + 11) / 12 - (px * 32 + 11) / 12;
      float wgt = (float)(wy * wx);
      #pragma unroll
      for (int c = 0; c < 3; ++c) {
        ys0[c * 144 + p] = a1[c];
        u20[c * 144 + p] = a2[c];
        sc[c] += a1[c] * wgt;
        sq[c] += a1[c] * a1[c] * wgt;
      }
    }
    #pragma unroll
    for (int off = 32; off; off >>= 1)
      #pragma unroll
      for (int c = 0; c < 3; ++c) {
        sc[c] += __shfl_down(sc[c], off);
        sq[c] += __shfl_down(sq[c], off);
      }
    int wid = tid >> 6, lane = tid & 63;
    if (lane == 0)
      #pragma unroll
      for (int c = 0; c < 3; ++c) { redS[wid][c] = sc[c]; redQ[wid][c] = sq[c]; }
    __syncthreads();
    if (tid < 3) {
      int c = tid;
      float s1 = redS[0][c] + redS[1][c] + redS[2][c] + redS[3][c];
      float s2 = redQ[0][c] + redQ[1][c] + redQ[2][c] + redQ[3][c];
      float si_ = inp[0] + inp[1] + inp[2] + lnp[0] + lnp[1] + lnp[2];
      float sb = bnp[0] + bnp[1] + bnp[2];
      float2 ab = ab_from(s1, s2, s1, s2, 1024.f, 1.f, si_, sb, bnw[c], bnb[c], p1p[0]);
      AB[c] = ab.x; AB[3 + c] = ab.y;
    }
    __syncthreads();
  }
  {
    float P2a = p2p[0];
    for (int t = tid; t < 3072; t += 256) {
      int c = t >> 10, p = t & 1023;
      int oy = p >> 5, ox = p & 31;
      int si = ((oy * 12) >> 5) * 12 + ((ox * 12) >> 5);
      buf1[t] = AB[c] * ys0[c * 144 + si] + AB[3 + c] + P2a * u20[c * 144 + si];
    }
  }
  __syncthreads();
  // ---- conv1: (3,32,32) -> S=28, r=64 ----
  {
    const float* w1 = cw + 225;
    const float* w2 = c2w + 225;
    float sc[3] = {0, 0, 0}, sq[3] = {0, 0, 0};
    for (int p = tid; p < 784; p += 256) {
      int py = p / 28, px = p - py * 28;
      float a1[3], a2[3];
      #pragma unroll
      for (int c = 0; c < 3; ++c) { a1[c] = cb[3 + c]; a2[c] = c2b[3 + c]; }
      for (int ci = 0; ci < 3; ++ci)
        #pragma unroll
        for (int ky = 0; ky < 5; ++ky) {
          const float* row = &buf1[ci * 1024 + (py + ky) * 32 + px];
          #pragma unroll
          for (int c = 0; c < 3; ++c)
            #pragma unroll
            for (int kx = 0; kx < 5; ++kx) {
              a1[c] = fmaf(row[kx], w1[c * 75 + ci * 25 + ky * 5 + kx], a1[c]);
              a2[c] = fmaf(row[kx], w2[c * 75 + ci * 25 + ky * 5 + kx], a2[c]);
            }
        }
      int wy = ((py + 1) * 64 + 27) / 28 - (py * 64 + 27) / 28;
      int wx = ((px + 1) * 64 + 27) / 28 - (px * 64 + 27) / 28;
      float wgt = (float)(wy * wx);
      #pragma unroll
      for (int c = 0; c < 3; ++c) {
        ys1[c * 784 + p] = a1[c];
        u21[c * 784 + p] = a2[c];
        sc[c] += a1[c] * wgt;
        sq[c] += a1[c] * a1[c] * wgt;
      }
    }
    #pragma unroll
    for (int off = 32; off; off >>= 1)
      #pragma unroll
      for (int c = 0; c < 3; ++c) {
        sc[c] += __shfl_down(sc[c], off);
        sq[c] += __shfl_down(sq[c], off);
      }
    int wid = tid >> 6, lane = tid & 63;
    __syncthreads();  // protect redS reuse
    if (lane == 0)
      #pragma unroll
      for (int c = 0; c < 3; ++c) { redS[wid][c] = sc[c]; redQ[wid][c] = sq[c]; }
    __syncthreads();
    if (tid < 3) {
      int c = tid;
      float s1 = redS[0][c] + redS[1][c] + redS[2][c] + redS[3][c];
      float s2 = redQ[0][c] + redQ[1][c] + redQ[2][c] + redQ[3][c];
      float si_ = inp[3] + inp[4] + inp[5] + lnp[3] + lnp[4] + lnp[5];
      float sb = bnp[3] + bnp[4] + bnp[5];
      float2 ab = ab_from(s1, s2, s1, s2, 4096.f, 1.f, si_, sb, bnw[3 + c], bnb[3 + c], p1p[1]);
      AB[c] = ab.x; AB[3 + c] = ab.y;
    }
    __syncthreads();
  }
  {
    float P2b = p2p[1];
    for (int t = tid; t < 12288; t += 256) {
      int c = t >> 12, p = t & 4095;
      int oy = p >> 6, ox = p & 63;
      int si = ((oy * 28) >> 6) * 28 + ((ox * 28) >> 6);
      nb0[t] = AB[c] * ys1[c * 784 + si] + AB[3 + c] + P2b * u21[c * 784 + si];
    }
  }
}

// ---- attention HW=1024, pass 1 (fused y2+QKV recompute) ----
__global__ __launch_bounds__(256) void attn_rows_f(
    const float2* __restrict__ yu, const float* __restrict__ sums,
    const float* __restrict__ inp, const float* __restrict__ lnp,
    const float* __restrict__ bnp, const float* __restrict__ bnw,
    const float* __restrict__ bnb, const float* __restrict__ p1p,
    const float* __restrict__ p2p,
    const float* __restrict__ qw, const float* __restrict__ qb,
    const float* __restrict__ kw, const float* __restrict__ kb,
    float* __restrict__ Mp, float* __restrict__ Lp, int S) {
  __shared__ float pA[3], pB[3], pP2v;
  __shared__ float y2s[768], qs[768];
  int bid = blockIdx.x;
  int np = bid & 3; bid >>= 2;
  int mc = bid & 3;
  int b = bid >> 2;
  compute_AB(sums, b, 32, 1024.f, inp, lnp, bnp, bnw, bnb, p1p, p2p, pA, pB, &pP2v);
  size_t ybase = (size_t)b * 3 * S * S;
  for (int t = threadIdx.x; t < 768; t += 256) {
    int c = t >> 8, j = t & 255;
    int n = (np << 8) + j;
    int oy = n >> 5, ox = n & 31;
    int si = ((oy * S) >> 5) * S + ((ox * S) >> 5);
    float2 v = yu[ybase + c * S * S + si];
    y2s[t] = pA[c] * v.x + pB[c] + pP2v * v.y;
  }
  __syncthreads();
  for (int t = threadIdx.x; t < 768; t += 256) {
    int o = t >> 8, j = t & 255;
    qs[t] = qb[o] + qw[o * 3] * y2s[j] + qw[o * 3 + 1] * y2s[256 + j] +
            qw[o * 3 + 2] * y2s[512 + j];
  }
  __syncthreads();
  int m = (mc << 8) + threadIdx.x;
  int oy = m >> 5, ox = m & 31;
  int si = ((oy * S) >> 5) * S + ((ox * S) >> 5);
  float ym[3];
  #pragma unroll
  for (int c = 0; c < 3; ++c) {
    float2 v = yu[ybase + c * S * S + si];
    ym[c] = pA[c] * v.x + pB[c] + pP2v * v.y;
  }
  float k0 = (kb[0] + kw[0] * ym[0] + kw[1] * ym[1] + kw[2] * ym[2]) * LOG2E;
  float k1 = (kb[1] + kw[3] * ym[0] + kw[4] * ym[1] + kw[5] * ym[2]) * LOG2E;
  float k2 = (kb[2] + kw[6] * ym[0] + kw[7] * ym[1] + kw[8] * ym[2]) * LOG2E;
  float mr = -1e30f;
  for (int j = 0; j < 256; ++j) {
    float s = k0 * qs[j] + k1 * qs[256 + j] + k2 * qs[512 + j];
    mr = fmaxf(mr, s);
  }
  float l = 0.f;
  for (int j = 0; j < 256; ++j) {
    float s = k0 * qs[j] + k1 * qs[256 + j] + k2 * qs[512 + j];
    l += exp2f(s - mr);
  }
  int idx = (b * 4 + np) * 1024 + m;
  Mp[idx] = mr;
  Lp[idx] = l;
}

// ---- attention HW=1024, pass 2: partial buffers, NO atomics ----
__global__ __launch_bounds__(256) void attn_out_f(
    const float2* __restrict__ yu, const float* __restrict__ sums,
    const float* __restrict__ inp, const float* __restrict__ lnp,
    const float* __restrict__ bnp, const float* __restrict__ bnw,
    const float* __restrict__ bnb, const float* __restrict__ p1p,
    const float* __restrict__ p2p,
    const float* __restrict__ qw, const float* __restrict__ qb,
    const float* __restrict__ kw, const float* __restrict__ kb,
    const float* __restrict__ vw, const float* __restrict__ vb,
    const float* __restrict__ Mp, const float* __restrict__ Lp,
    float* __restrict__ aout, int S) {
  __shared__ float pA[3], pB[3], pP2v;
  __shared__ float ym[768], ks[768], vs[768], Ms[256], Ls[256];
  int bid = blockIdx.x;
  int mp = bid & 3; bid >>= 2;
  int nc = bid & 3;
  int b = bid >> 2;
  compute_AB(sums, b, 32, 1024.f, inp, lnp, bnp, bnw, bnb, p1p, p2p, pA, pB, &pP2v);
  size_t ybase = (size_t)b * 3 * S * S;
  for (int t = threadIdx.x; t < 768; t += 256) {
    int c = t >> 8, j = t & 255;
    int m = (mp << 8) + j;
    int oy = m >> 5, ox = m & 31;
    int si = ((oy * S) >> 5) * S + ((ox * S) >> 5);
    float2 v = yu[ybase + c * S * S + si];
    ym[t] = pA[c] * v.x + pB[c] + pP2v * v.y;
  }
  __syncthreads();
  for (int t = threadIdx.x; t < 768; t += 256) {
    int o = t >> 8, j = t & 255;
    float y0 = ym[j], y1 = ym[256 + j], y2v = ym[512 + j];
    ks[t] = (kb[o] + kw[o * 3] * y0 + kw[o * 3 + 1] * y1 + kw[o * 3 + 2] * y2v) * LOG2E;
    vs[t] = vb[o] + vw[o * 3] * y0 + vw[o * 3 + 1] * y1 + vw[o * 3 + 2] * y2v;
  }
  {
    int t = threadIdx.x;
    int m = (mp << 8) + t;
    float M0 = Mp[(b * 4 + 0) * 1024 + m], M1 = Mp[(b * 4 + 1) * 1024 + m];
    float M2 = Mp[(b * 4 + 2) * 1024 + m], M3 = Mp[(b * 4 + 3) * 1024 + m];
    float L0 = Lp[(b * 4 + 0) * 1024 + m], L1 = Lp[(b * 4 + 1) * 1024 + m];
    float L2 = Lp[(b * 4 + 2) * 1024 + m], L3 = Lp[(b * 4 + 3) * 1024 + m];
    float MM = fmaxf(fmaxf(M0, M1), fmaxf(M2, M3));
    float LL = L0 * exp2f(M0 - MM) + L1 * exp2f(M1 - MM) +
               L2 * exp2f(M2 - MM) + L3 * exp2f(M3 - MM);
    Ms[t] = MM;
    Ls[t] = 1.0f / LL;
  }
  __syncthreads();
  int n = (nc << 8) + threadIdx.x;
  int oy = n >> 5, ox = n & 31;
  int si = ((oy * S) >> 5) * S + ((ox * S) >> 5);
  float yn[3];
  #pragma unroll
  for (int c = 0; c < 3; ++c) {
    float2 v = yu[ybase + c * S * S + si];
    yn[c] = pA[c] * v.x + pB[c] + pP2v * v.y;
  }
  float q0 = qb[0] + qw[0] * yn[0] + qw[1] * yn[1] + qw[2] * yn[2];
  float q1 = qb[1] + qw[3] * yn[0] + qw[4] * yn[1] + qw[5] * yn[2];
  float q2 = qb[2] + qw[6] * yn[0] + qw[7] * yn[1] + qw[8] * yn[2];
  float a0 = 0.f, a1 = 0.f, a2 = 0.f;
  for (int j = 0; j < 256; ++j) {
    float s = ks[j] * q0 + ks[256 + j] * q1 + ks[512 + j] * q2;
    float w = exp2f(s - Ms[j]) * Ls[j];
    a0 = fmaf(vs[j], w, a0);
    a1 = fmaf(vs[256 + j], w, a1);
    a2 = fmaf(vs[512 + j], w, a2);
  }
  if (mp == 0) { a0 += yn[0]; a1 += yn[1]; a2 += yn[2]; }
  size_t o0 = (size_t)mp * 98304 + (size_t)b * 3072 + n;
  aout[o0] = a0;
  aout[o0 + 1024] = a1;
  aout[o0 + 2048] = a2;
}

// ---- attention HW=256 + following conv, 1024 threads, 4-way split loops ----
__global__ __launch_bounds__(1024) void attn256_conv(
    const float2* __restrict__ yu, const float* __restrict__ sums,
    const float* __restrict__ inp, const float* __restrict__ lnp,
    const float* __restrict__ bnp, const float* __restrict__ bnw,
    const float* __restrict__ bnb, const float* __restrict__ p1p,
    const float* __restrict__ p2p,
    const float* __restrict__ qw, const float* __restrict__ qb,
    const float* __restrict__ kw, const float* __restrict__ kb,
    const float* __restrict__ vw, const float* __restrict__ vb,
    const float* __restrict__ cw1, const float* __restrict__ cb1,
    const float* __restrict__ cw2, const float* __restrict__ cb2,
    float2* __restrict__ yu_out, float* __restrict__ sums_out, int S, int r) {
  __shared__ float pA[3], pB[3], pP2v;
  __shared__ float y2s[768], qs[768], ks[768], vs[768];
  __shared__ float Ms[256], Ls[256];
  __shared__ float Mq[1024], Lq[1024];
  __shared__ float Oq[3072];
  __shared__ float redS[16][3], redQ[16][3];
  int tid = threadIdx.x;
  int quarter = tid >> 8;
  int lane256 = tid & 255;
  int b = blockIdx.x;
  compute_AB(sums, b, 32, 256.f, inp, lnp, bnp, bnw, bnb, p1p, p2p, pA, pB, &pP2v);
  size_t ybase = (size_t)b * 3 * S * S;
  if (tid < 768) {
    int c = tid >> 8, p = tid & 255;
    int oy = p >> 4, ox = p & 15;
    int si = ((oy * S) >> 4) * S + ((ox * S) >> 4);
    float2 v = yu[ybase + c * S * S + si];
    y2s[tid] = pA[c] * v.x + pB[c] + pP2v * v.y;
  }
  __syncthreads();
  if (tid < 768) {
    int o = tid >> 8, p = tid & 255;
    float y0 = y2s[p], y1 = y2s[256 + p], y2v = y2s[512 + p];
    qs[tid] = qb[o] + qw[o * 3] * y0 + qw[o * 3 + 1] * y1 + qw[o * 3 + 2] * y2v;
    ks[tid] = (kb[o] + kw[o * 3] * y0 + kw[o * 3 + 1] * y1 + kw[o * 3 + 2] * y2v) * LOG2E;
    vs[tid] = vb[o] + vw[o * 3] * y0 + vw[o * 3 + 1] * y1 + vw[o * 3 + 2] * y2v;
  }
  __syncthreads();
  // row stats: thread (quarter, m) over n-quarter
  {
    int m = lane256;
    float kx = ks[m], ky = ks[256 + m], kz = ks[512 + m];
    int n0 = quarter << 6;
    float mr = -1e30f;
    #pragma unroll 4
    for (int j = 0; j < 64; ++j) {
      int n = n0 + j;
      float s = kx * qs[n] + ky * qs[256 + n] + kz * qs[512 + n];
      mr = fmaxf(mr, s);
    }
    float l = 0.f;
    #pragma unroll 4
    for (int j = 0; j < 64; ++j) {
      int n = n0 + j;
      float s = kx * qs[n] + ky * qs[256 + n] + kz * qs[512 + n];
      l += exp2f(s - mr);
    }
    Mq[tid] = mr;
    Lq[tid] = l;
  }
  __syncthreads();
  if (tid < 256) {
    float M0 = Mq[tid], M1 = Mq[256 + tid], M2 = Mq[512 + tid], M3 = Mq[768 + tid];
    float L0 = Lq[tid], L1 = Lq[256 + tid], L2 = Lq[512 + tid], L3 = Lq[768 + tid];
    float MM = fmaxf(fmaxf(M0, M1), fmaxf(M2, M3));
    float LL = L0 * exp2f(M0 - MM) + L1 * exp2f(M1 - MM) +
               L2 * exp2f(M2 - MM) + L3 * exp2f(M3 - MM);
    Ms[tid] = MM;
    Ls[tid] = 1.0f / LL;
  }
  __syncthreads();
  // output: thread (quarter, n) partial over m-quarter
  {
    int n = lane256;
    float q0 = qs[n], q1 = qs[256 + n], q2 = qs[512 + n];
    int m0 = quarter << 6;
    float a0 = 0.f, a1 = 0.f, a2 = 0.f;
    #pragma unroll 4
    for (int j = 0; j < 64; ++j) {
      int m = m0 + j;
      float s = ks[m] * q0 + ks[256 + m] * q1 + ks[512 + m] * q2;
      float w = exp2f(s - Ms[m]) * Ls[m];
      a0 = fmaf(vs[m], w, a0);
      a1 = fmaf(vs[256 + m], w, a1);
      a2 = fmaf(vs[512 + m], w, a2);
    }
    Oq[tid] = a0;
    Oq[1024 + tid] = a1;
    Oq[2048 + tid] = a2;
  }
  __syncthreads();
  if (tid < 768) {
    int c = tid >> 8, n = tid & 255;
    int cb_ = c << 10;
    y2s[tid] += Oq[cb_ + n] + Oq[cb_ + 256 + n] + Oq[cb_ + 512 + n] + Oq[cb_ + 768 + n];
  }
  __syncthreads();
  // ---- conv 5x5 valid on the 16x16 image in y2s -> 12x12 grid ----
  float sc[3] = {0.f, 0.f, 0.f}, sq[3] = {0.f, 0.f, 0.f};
  int p = tid;
  if (p < 144) {
    int py = p / 12, px = p - py * 12;
    float a1[3], a2[3];
    #pragma unroll
    for (int c = 0; c < 3; ++c) { a1[c] = cb1[c]; a2[c] = cb2[c]; }
    #pragma unroll
    for (int ci = 0; ci < 3; ++ci) {
      #pragma unroll
      for (int ky = 0; ky < 5; ++ky) {
        const float* row = &y2s[ci * 256 + (py + ky) * 16 + px];
        #pragma unroll
        for (int c = 0; c < 3; ++c) {
          #pragma unroll
          for (int kx = 0; kx < 5; ++kx) {
            a1[c] = fmaf(row[kx], cw1[c * 75 + ci * 25 + ky * 5 + kx], a1[c]);
            a2[c] = fmaf(row[kx], cw2[c * 75 + ci * 25 + ky * 5 + kx], a2[c]);
          }
        }
      }
    }
    float wy = (float)(((py + 1) * r + 11) / 12 - (py * r + 11) / 12);
    float wx = (float)(((px + 1) * r + 11) / 12 - (px * r + 11) / 12);
    float wgt = wy * wx;
    #pragma unroll
    for (int c = 0; c < 3; ++c) {
      yu_out[(size_t)(b * 3 + c) * 144 + p] = make_float2(a1[c], a2[c]);
      sc[c] += a1[c] * wgt;
      sq[c] += a1[c] * a1[c] * wgt;
    }
  }
  // 16-wave stats reduce
  #pragma unroll
  for (int off = 32; off; off >>= 1) {
    #pragma unroll
    for (int c = 0; c < 3; ++c) {
      sc[c] += __shfl_down(sc[c], off);
      sq[c] += __shfl_down(sq[c], off);
    }
  }
  int wid = tid >> 6, lane = tid & 63;
  if (lane == 0) {
    #pragma unroll
    for (int c = 0; c < 3; ++c) { redS[wid][c] = sc[c]; redQ[wid][c] = sq[c]; }
  }
  __syncthreads();
  if (tid < 3) {
    int c = tid;
    float s1 = 0.f, s2 = 0.f;
    #pragma unroll
    for (int w = 0; w < 16; ++w) { s1 += redS[w][c]; s2 += redQ[w][c]; }
    atomicAdd(&sums_out[2 * (b * 3 + c)], s1);
    atomicAdd(&sums_out[2 * (b * 3 + c) + 1], s2);
  }
}

// ---- final: affine + p2*u2 + tanh -> out ----
__global__ __launch_bounds__(256) void elem_final(
    const float2* __restrict__ yu, const float* __restrict__ sums,
    const float* __restrict__ inp, const float* __restrict__ lnp,
    const float* __restrict__ bnp, const float* __restrict__ bnw,
    const float* __restrict__ bnb, const float* __restrict__ p1p,
    const float* __restrict__ p2p, float* __restrict__ out, int S) {
  __shared__ float pA[3], pB[3], pP2v;
  int n = blockIdx.x >> 8;
  int p = ((blockIdx.x & 255) << 8) + threadIdx.x;
  compute_AB(sums, n, 32, 65536.f, inp, lnp, bnp, bnw, bnb, p1p, p2p, pA, pB, &pP2v);
  int oy = p >> 8, ox = p & 255;
  int si = ((oy * S) >> 8) * S + ((ox * S) >> 8);
  size_t ybase = (size_t)n * 3 * S * S;
  #pragma unroll
  for (int c = 0; c < 3; ++c) {
    float2 v = yu[ybase + c * S * S + si];
    out[((size_t)(n * 3 + c) << 16) + p] = tanhf(pA[c] * v.x + pB[c] + pP2v * v.y);
  }
}

#define NPX nullptr, nullptr, nullptr, nullptr, nullptr, nullptr, nullptr, \
            nullptr, nullptr, 0, 0, 0

extern "C" void kernel_launch(void* const* d_in, const int* in_sizes, int n_in,
                              void* d_out, int out_size, void* d_ws, size_t ws_size,
                              hipStream_t stream) {
  const float* x       = (const float*)d_in[0];
  const float* noise_z = (const float*)d_in[1];
  const float* lin_w   = (const float*)d_in[2];
  const float* lin_b   = (const float*)d_in[3];
  const float* conv_w  = (const float*)d_in[4];
  const float* conv_b  = (const float*)d_in[5];
  const float* conv2_w = (const float*)d_in[6];
  const float* conv2_b = (const float*)d_in[7];
  const float* q_w     = (const float*)d_in[8];
  const float* q_b     = (const float*)d_in[9];
  const float* k_w     = (const float*)d_in[10];
  const float* k_b     = (const float*)d_in[11];
  const float* v_w     = (const float*)d_in[12];
  const float* v_b     = (const float*)d_in[13];
  const float* in_p    = (const float*)d_in[14];
  const float* ln_p    = (const float*)d_in[15];
  const float* bn_p    = (const float*)d_in[16];
  const float* bn_w    = (const float*)d_in[17];
  const float* bn_b    = (const float*)d_in[18];
  const float* p1      = (const float*)d_in[19];
  const float* p2      = (const float*)d_in[20];
  float* out = (float*)d_out;

  float* ws = (float*)d_ws;
  size_t off = 0;
  auto alloc = [&](size_t nf) { float* p = ws + off; off += nf; return p; };
  float* SUMS = alloc(2304);
  float* P45  = alloc(393216);   // attn5 partials (4 x 32 x 3072)
  float* P48  = alloc(393216);   // attn8 partials
  float2* YU2 = (float2*)alloc(12192768);  // 252^2 * 96 * 2
  float2* PA  = (float2*)alloc(3145728);
  float2* PB  = (float2*)alloc(3145728);
  float* Mp   = alloc(131072);
  float* Lp   = alloc(131072);
  float* NB0  = alloc(12288);
  float* LIN  = alloc(768);

  hipMemsetAsync(SUMS, 0, 2304 * sizeof(float), stream);

  const float* nul = nullptr;
  const float2* nul2 = nullptr;

  // noise path: parallel linear, then small conv pipeline (blocks 0,1) -> NB0
  linear_wave<<<192, 256, 0, stream>>>(noise_z, lin_w, lin_b, LIN);
  noise_rest<<<1, 256, 0, stream>>>(LIN, conv_w, conv_b, conv2_w, conv2_b,
      in_p, ln_p, bn_p, bn_w, bn_b, p1, p2, NB0);

  // conv2: x -> YU2 (S=252, r=256), async global->LDS staging
  conv_up_t<false, false><<<2048, 256, 0, stream>>>(x, nul2, YU2, conv_w + 450,
      conv_b + 6, conv2_w + 450, conv2_b + 6, SUMS + 384, 256, 252, 256, 4, 16,
      NPX);
  // conv3: fused(b2) YU2 -> PA (S=128); prev Sp=252, logrp=8 (true gather)
  conv_dn_t<true, false, false><<<2048, 256, 0, stream>>>(nul, YU2, PA,
      conv_w + 675, conv_b + 9, conv2_w + 675, conv2_b + 9, SUMS + 576,
      256, 128, 252, 7, 4, 16,
      SUMS + 384, in_p + 6, ln_p + 6, bn_p + 6, bn_w + 6, bn_b + 6, p1 + 2,
      p2 + 2, nul, 32, 252, 8);
  // conv4: fused(b3) PA -> PB (S=64); prev identity
  conv_dn_t<true, true, false><<<512, 256, 0, stream>>>(nul, PA, PB,
      conv_w + 900, conv_b + 12, conv2_w + 900, conv2_b + 12, SUMS + 768,
      128, 64, 124, 6, 2, 8,
      SUMS + 576, in_p + 9, ln_p + 9, bn_p + 9, bn_w + 9, bn_b + 9, p1 + 3,
      p2 + 3, nul, 32, 128, 7);
  // conv5: fused(b4)+noise PB -> PA (S=32); prev identity
  conv_dn_t<true, true, false><<<128, 256, 0, stream>>>(nul, PB, PA,
      conv_w + 1125, conv_b + 15, conv2_w + 1125, conv2_b + 15, SUMS + 960,
      64, 32, 60, 5, 1, 4,
      SUMS + 768, in_p + 12, ln_p + 12, bn_p + 12, bn_w + 12, bn_b + 12, p1 + 4,
      p2 + 4, NB0, 32, 64, 6);
  // attn5 (HW=1024) on PA (S=32) -> partials P45
  attn_rows_f<<<512, 256, 0, stream>>>(PA, SUMS + 960, in_p + 15, ln_p + 15,
      bn_p + 15, bn_w + 15, bn_b + 15, p1 + 5, p2 + 5,
      q_w + 45, q_b + 15, k_w + 45, k_b + 15, Mp, Lp, 32);
  attn_out_f<<<512, 256, 0, stream>>>(PA, SUMS + 960, in_p + 15, ln_p + 15,
      bn_p + 15, bn_w + 15, bn_b + 15, p1 + 5, p2 + 5,
      q_w + 45, q_b + 15, k_w + 45, k_b + 15, v_w + 45, v_b + 15, Mp, Lp, P45, 32);
  // conv6: SUM4 staging from P45 -> PB (S=16)
  conv_dn_t<false, false, true><<<64, 256, 0, stream>>>(P45, nul2, PB,
      conv_w + 1350, conv_b + 18, conv2_w + 1350, conv2_b + 18, SUMS + 1152,
      32, 16, 28, 4, 1, 2, NPX);
  // attn6 (HW=256) on PB (S=16) + conv7 (r=16) -> PA (S=12)
  attn256_conv<<<32, 1024, 0, stream>>>(PB, SUMS + 1152, in_p + 18, ln_p + 18,
      bn_p + 18, bn_w + 18, bn_b + 18, p1 + 6, p2 + 6,
      q_w + 54, q_b + 18, k_w + 54, k_b + 18, v_w + 54, v_b + 18,
      conv_w + 1575, conv_b + 21, conv2_w + 1575, conv2_b + 21,
      PA, SUMS + 1344, 16, 16);
  // attn7 (HW=256) on PA (S=12) + conv8 (r=32) -> PB (S=12)
  attn256_conv<<<32, 1024, 0, stream>>>(PA, SUMS + 1344, in_p + 21, ln_p + 21,
      bn_p + 21, bn_w + 21, bn_b + 21, p1 + 7, p2 + 7,
      q_w + 63, q_b + 21, k_w + 63, k_b + 21, v_w + 63, v_b + 21,
      conv_w + 1800, conv_b + 24, conv2_w + 1800, conv2_b + 24,
      PB, SUMS + 1536, 12, 32);
  // attn8 (HW=1024) on PB (S=12) -> partials P48
  attn_rows_f<<<512, 256, 0, stream>>>(PB, SUMS + 1536, in_p + 24, ln_p + 24,
      bn_p + 24, bn_w + 24, bn_b + 24, p1 + 8, p2 + 8,
      q_w + 72, q_b + 24, k_w + 72, k_b + 24, Mp, Lp, 12);
  attn_out_f<<<512, 256, 0, stream>>>(PB, SUMS + 1536, in_p + 24, ln_p + 24,
      bn_p + 24, bn_w + 24, bn_b + 24, p1 + 8, p2 + 8,
      q_w + 72, q_b + 24, k_w + 72, k_b + 24, v_w + 72, v_b + 24, Mp, Lp, P48, 12);
  // conv9: SUM4 staging from P48 -> PA (S=28, r=64)
  conv_up_t<false, true><<<64, 256, 0, stream>>>(P48, nul2, PA, conv_w + 2025,
      conv_b + 27, conv2_w + 2025, conv2_b + 27, SUMS + 1728, 32, 28, 64, 1, 2,
      NPX);
  // conv10: fused(b9) PA -> PB (S=60); prev Sp=28, logrp=6
  conv_up_t<true, false><<<128, 256, 0, stream>>>(nul, PA, PB, conv_w + 2250,
      conv_b + 30, conv2_w + 2250, conv2_b + 30, SUMS + 1920, 64, 60, 128, 1, 4,
      SUMS + 1728, in_p + 27, ln_p + 27, bn_p + 27, bn_w + 27, bn_b + 27,
      p1 + 9, p2 + 9, nul, 32, 28, 6);
  // conv11: fused(b10) PB -> YU2 (S=124); prev Sp=60, logrp=7
  conv_up_t<true, false><<<512, 256, 0, stream>>>(nul, PB, YU2, conv_w + 2475,
      conv_b + 33, conv2_w + 2475, conv2_b + 33, SUMS + 2112, 128, 124, 256, 2, 8,
      SUMS + 1920, in_p + 30, ln_p + 30, bn_p + 30, bn_w + 30, bn_b + 30,
      p1 + 10, p2 + 10, nul, 32, 60, 7);
  // final: tanh -> out
  elem_final<<<8192, 256, 0, stream>>>(YU2, SUMS + 2112, in_p + 33, ln_p + 33,
      bn_p + 33, bn_w + 33, bn_b + 33, p1 + 11, p2 + 11, out, 124);
}

// Round 11
// 492.032 us; speedup vs baseline: 1.7927x; 1.0217x over previous
//
#include <hip/hip_runtime.h>
#include <math.h>

#define EPS 1e-5f
#define LOG2E 1.44269504088896340736f

#define AS_GLOBAL __attribute__((address_space(1)))
#define AS_LDS    __attribute__((address_space(3)))

// ---- shared affine-fold helper: A,B from sums (instance+batch norm + p1) ----
__device__ __forceinline__ float2 ab_from(float s1, float s2, float bs, float bs2,
    float hw, float Nf, float si_, float sb, float bnw_c, float bnb_c, float p1v) {
  float inv = 1.0f / hw;
  float mi = s1 * inv, vi = s2 * inv - mi * mi;
  float ri = rsqrtf(vi + EPS);
  float invb = 1.0f / (Nf * hw);
  float mb = bs * invb, vb = bs2 * invb - mb * mb;
  float rb = rsqrtf(vb + EPS);
  float A = 1.0f + si_ * ri + sb * rb * bnw_c;
  float B = -(si_ * ri * mi + sb * rb * bnw_c * mb) + sb * bnb_c;
  return make_float2(A * p1v, B * p1v);
}

__device__ __forceinline__ void compute_AB(
    const float* __restrict__ sums, int n, int N, float hw,
    const float* __restrict__ inp, const float* __restrict__ lnp,
    const float* __restrict__ bnp, const float* __restrict__ bnw,
    const float* __restrict__ bnb, const float* __restrict__ p1p,
    const float* __restrict__ p2p, float* pA, float* pB, float* pP2) {
  if (threadIdx.x == 0) *pP2 = p2p[0];
  if (threadIdx.x < 3) {
    int c = threadIdx.x;
    float si_ = inp[0] + inp[1] + inp[2] + lnp[0] + lnp[1] + lnp[2];
    float sb = bnp[0] + bnp[1] + bnp[2];
    float s1 = sums[2 * (n * 3 + c)], s2 = sums[2 * (n * 3 + c) + 1];
    float bs = 0.f, bs2 = 0.f;
    for (int nn = 0; nn < N; ++nn) {
      bs += sums[2 * (nn * 3 + c)];
      bs2 += sums[2 * (nn * 3 + c) + 1];
    }
    float2 ab = ab_from(s1, s2, bs, bs2, hw, (float)N, si_, sb, bnw[c], bnb[c], p1p[0]);
    pA[c] = ab.x;
    pB[c] = ab.y;
  }
  __syncthreads();
}

// stats block-reduce (256 threads, all must participate)
#define STATS_REDUCE_ATOMIC(scv, sqv, sumsp, nvar)                            \
  {                                                                           \
    _Pragma("unroll")                                                         \
    for (int off = 32; off; off >>= 1) {                                      \
      _Pragma("unroll")                                                       \
      for (int c = 0; c < 3; ++c) {                                           \
        scv[c] += __shfl_down(scv[c], off);                                   \
        sqv[c] += __shfl_down(sqv[c], off);                                   \
      }                                                                       \
    }                                                                         \
    __shared__ float redS[4][3], redQ[4][3];                                  \
    int wid = threadIdx.x >> 6, lane = threadIdx.x & 63;                      \
    if (lane == 0) {                                                          \
      _Pragma("unroll")                                                       \
      for (int c = 0; c < 3; ++c) { redS[wid][c] = scv[c]; redQ[wid][c] = sqv[c]; } \
    }                                                                         \
    __syncthreads();                                                          \
    if (threadIdx.x < 3) {                                                    \
      int c = threadIdx.x;                                                    \
      atomicAdd(&sumsp[2 * ((nvar) * 3 + c)],                                 \
                redS[0][c] + redS[1][c] + redS[2][c] + redS[3][c]);           \
      atomicAdd(&sumsp[2 * ((nvar) * 3 + c) + 1],                             \
                redQ[0][c] + redQ[1][c] + redQ[2][c] + redQ[3][c]);           \
    }                                                                         \
  }

// ---- division-free 2D staging of a 3 x 20 x 68 tile ----
// FUSED: gather float2 from pyu at prev grid + affine (+noise)
// SUM4:  sum 4 partial buffers from `in` (n-offset included by caller in inb)
// DIRECT: plain load from inb
// col = tid&63 (wave-coherent), r4 = tid>>6; tail cols 64..67 via 240 threads.
template <int MODE, bool IDENT>  // MODE: 0=direct, 1=fused, 2=sum4
__device__ __forceinline__ void stage_tile(
    float* __restrict__ lin, const float* __restrict__ inb, size_t ps,
    const float2* __restrict__ pyu, size_t pbase,
    int Hin, int sy0, int sx0, int Sp, int logrp,
    const float* pA, const float* pB, float pP2v,
    const float* __restrict__ pnoise) {
  const int IW = 68, IH = 20;
  int colt = threadIdx.x & 63;
  int r4 = threadIdx.x >> 6;
  int gx = sx0 + colt; gx = gx < Hin ? gx : Hin - 1;
  int gxs = (MODE == 1) ? (IDENT ? gx : ((gx * Sp) >> logrp)) : 0;
  #pragma unroll
  for (int cc = 0; cc < 3; ++cc) {
    #pragma unroll
    for (int rb = 0; rb < 5; ++rb) {
      int rr = r4 + (rb << 2);
      int gy = sy0 + rr; gy = gy < Hin ? gy : Hin - 1;
      float val;
      if (MODE == 1) {
        int rbase = IDENT ? gy * Sp : ((gy * Sp) >> logrp) * Sp;
        float2 v = pyu[pbase + (size_t)cc * Sp * Sp + rbase + gxs];
        val = pA[cc] * v.x + pB[cc] + pP2v * v.y;
        if (pnoise) val += pnoise[((size_t)cc * Hin + gy) * Hin + gx];
      } else if (MODE == 2) {
        size_t idx = ((size_t)cc * Hin + gy) * Hin + gx;
        val = inb[idx] + inb[idx + ps] + inb[idx + 2 * ps] + inb[idx + 3 * ps];
      } else {
        val = inb[((size_t)cc * Hin + gy) * Hin + gx];
      }
      lin[(cc * IH + rr) * IW + colt] = val;
    }
  }
  if (threadIdx.x < 240) {
    int col2 = 64 + (threadIdx.x & 3);
    int rowlin = threadIdx.x >> 2;        // 0..59
    int cc = rowlin / 20, rr = rowlin - cc * 20;
    int gx2 = sx0 + col2; gx2 = gx2 < Hin ? gx2 : Hin - 1;
    int gy = sy0 + rr; gy = gy < Hin ? gy : Hin - 1;
    float val;
    if (MODE == 1) {
      int gxs2 = IDENT ? gx2 : ((gx2 * Sp) >> logrp);
      int rbase = IDENT ? gy * Sp : ((gy * Sp) >> logrp) * Sp;
      float2 v = pyu[pbase + (size_t)cc * Sp * Sp + rbase + gxs2];
      val = pA[cc] * v.x + pB[cc] + pP2v * v.y;
      if (pnoise) val += pnoise[((size_t)cc * Hin + gy) * Hin + gx2];
    } else if (MODE == 2) {
      size_t idx = ((size_t)cc * Hin + gy) * Hin + gx2;
      val = inb[idx] + inb[idx + ps] + inb[idx + 2 * ps] + inb[idx + 3 * ps];
    } else {
      val = inb[((size_t)cc * Hin + gy) * Hin + gx2];
    }
    lin[(cc * IH + rr) * IW + col2] = val;
  }
}

// ---- LDS-tiled upsample conv (S==hc): 64x16 tile, TX=4, float2 out ----
template <bool FUSED, bool SUM4>
__global__ __launch_bounds__(256) void conv_up_t(
    const float* __restrict__ in, const float2* __restrict__ pyu,
    float2* __restrict__ yu,
    const float* __restrict__ w1, const float* __restrict__ b1,
    const float* __restrict__ w2, const float* __restrict__ b2,
    float* __restrict__ sums, int Hin, int S, int r, int tilesX, int tilesY,
    const float* __restrict__ psums,
    const float* __restrict__ pinp, const float* __restrict__ plnp,
    const float* __restrict__ pbnp, const float* __restrict__ pbnw,
    const float* __restrict__ pbnb, const float* __restrict__ pp1,
    const float* __restrict__ pp2, const float* __restrict__ pnoise,
    int pN, int Sp, int logrp) {
  const int TW = 64, TH = 16, IW = 68, IH = 20;
  __shared__ float lin[3 * IH * IW];
  __shared__ float pA[3], pB[3], pP2v;
  int tpi = tilesX * tilesY;
  int n = blockIdx.x / tpi;
  int trem = blockIdx.x - n * tpi;
  int tyB = trem / tilesX, txB = trem - tyB * tilesX;
  int px0 = txB * TW, py0 = tyB * TH;
  const float* inb = in + (size_t)n * 3 * Hin * Hin;
  if (FUSED) {
    compute_AB(psums, n, pN, (float)(Hin * Hin), pinp, plnp, pbnp, pbnw, pbnb,
               pp1, pp2, pA, pB, &pP2v);
    size_t pbase = (size_t)n * 3 * Sp * Sp;
    stage_tile<1, false>(lin, nullptr, 0, pyu, pbase, Hin, py0, px0, Sp, logrp,
                         pA, pB, pP2v, pnoise);
  } else if (SUM4) {
    size_t ps = (size_t)96 * Hin * Hin;
    stage_tile<2, false>(lin, inb, ps, nullptr, 0, Hin, py0, px0, 0, 0,
                         nullptr, nullptr, 0.f, nullptr);
  } else {
    if (px0 + IW <= Hin && py0 + IH <= Hin) {
      for (int t4 = threadIdx.x; t4 < 3 * IH * 17; t4 += 256) {
        int cc = t4 / (IH * 17);
        int rem = t4 - cc * (IH * 17);
        int rr = rem / 17, j = rem - rr * 17;
        const float* src = inb + ((size_t)cc * Hin + py0 + rr) * Hin + px0 + 4 * j;
        int base = t4 - (threadIdx.x & 63);  // wave-uniform float4 index
        __builtin_amdgcn_global_load_lds(
            (const AS_GLOBAL void*)src,
            (AS_LDS void*)(lin + 4 * base), 16, 0, 0);
      }
    } else {
      stage_tile<0, false>(lin, inb, 0, nullptr, 0, Hin, py0, px0, 0, 0,
                           nullptr, nullptr, 0.f, nullptr);
    }
  }
  __syncthreads();
  int tx = threadIdx.x & 15, ty = threadIdx.x >> 4;
  int lx0 = tx * 4;
  int px = px0 + lx0, py = py0 + ty;
  float a1[3][4], a2[3][4];
  #pragma unroll
  for (int c = 0; c < 3; ++c) {
    float bb1 = b1[c], bb2 = b2[c];
    #pragma unroll
    for (int x = 0; x < 4; ++x) { a1[c][x] = bb1; a2[c][x] = bb2; }
  }
  #pragma unroll 1
  for (int ci = 0; ci < 3; ++ci) {
    const float* lrow = lin + ci * IH * IW + ty * IW + lx0;
    const float* wp1 = w1 + ci * 25;
    const float* wp2 = w2 + ci * 25;
    #pragma unroll
    for (int ky = 0; ky < 5; ++ky) {
      float v[8];
      #pragma unroll
      for (int j = 0; j < 8; ++j) v[j] = lrow[ky * IW + j];
      #pragma unroll
      for (int c = 0; c < 3; ++c) {
        #pragma unroll
        for (int kx = 0; kx < 5; ++kx) {
          float wa = wp1[c * 75 + ky * 5 + kx];
          float wb = wp2[c * 75 + ky * 5 + kx];
          #pragma unroll
          for (int x = 0; x < 4; ++x) {
            a1[c][x] = fmaf(v[kx + x], wa, a1[c][x]);
            a2[c][x] = fmaf(v[kx + x], wb, a2[c][x]);
          }
        }
      }
    }
  }
  float sc[3] = {0.f, 0.f, 0.f}, sq[3] = {0.f, 0.f, 0.f};
  bool valid = (py < S) && (px < S);
  if (valid) {
    int hc = S;
    float wy = (float)(((py + 1) * r + hc - 1) / hc - (py * r + hc - 1) / hc);
    float wx[4];
    #pragma unroll
    for (int x = 0; x < 4; ++x) {
      int pxx = px + x;
      wx[x] = (float)(((pxx + 1) * r + hc - 1) / hc - (pxx * r + hc - 1) / hc);
    }
    #pragma unroll
    for (int c = 0; c < 3; ++c) {
      size_t idx = ((size_t)(n * 3 + c) * S + py) * S + px;
      float2* yp = yu + idx;
      *reinterpret_cast<float4*>(yp) =
          make_float4(a1[c][0], a2[c][0], a1[c][1], a2[c][1]);
      *reinterpret_cast<float4*>(yp + 2) =
          make_float4(a1[c][2], a2[c][2], a1[c][3], a2[c][3]);
      #pragma unroll
      for (int x = 0; x < 4; ++x) {
        float wgt = wy * wx[x];
        sc[c] += a1[c][x] * wgt;
        sq[c] += a1[c][x] * a1[c][x] * wgt;
      }
    }
  }
  STATS_REDUCE_ATOMIC(sc, sq, sums, n)
}

// ---- LDS-tiled downsample conv (ratio<2.05): 32x8 tile, float2 out ----
template <bool FUSED, bool IDENT, bool SUM4>
__global__ __launch_bounds__(256) void conv_dn_t(
    const float* __restrict__ in, const float2* __restrict__ pyu,
    float2* __restrict__ yu,
    const float* __restrict__ w1, const float* __restrict__ b1,
    const float* __restrict__ w2, const float* __restrict__ b2,
    float* __restrict__ sums, int Hin, int S, int hc, int logr,
    int tilesX, int tilesY,
    const float* __restrict__ psums,
    const float* __restrict__ pinp, const float* __restrict__ plnp,
    const float* __restrict__ pbnp, const float* __restrict__ pbnw,
    const float* __restrict__ pbnb, const float* __restrict__ pp1,
    const float* __restrict__ pp2, const float* __restrict__ pnoise,
    int pN, int Sp, int logrp) {
  const int TW = 32, TH = 8, IW = 68, IH = 20;
  __shared__ float lin[3 * IH * IW];
  __shared__ float pA[3], pB[3], pP2v;
  int tpi = tilesX * tilesY;
  int n = blockIdx.x / tpi;
  int trem = blockIdx.x - n * tpi;
  int tyB = trem / tilesX, txB = trem - tyB * tilesX;
  int px0 = txB * TW, py0 = tyB * TH;
  int sy0 = (py0 * hc) >> logr, sx0 = (px0 * hc) >> logr;
  const float* inb = in + (size_t)n * 3 * Hin * Hin;
  if (FUSED) {
    compute_AB(psums, n, pN, (float)(Hin * Hin), pinp, plnp, pbnp, pbnw, pbnb,
               pp1, pp2, pA, pB, &pP2v);
    size_t pbase = (size_t)n * 3 * Sp * Sp;
    stage_tile<1, IDENT>(lin, nullptr, 0, pyu, pbase, Hin, sy0, sx0, Sp, logrp,
                         pA, pB, pP2v, pnoise);
  } else if (SUM4) {
    size_t ps = (size_t)96 * Hin * Hin;
    stage_tile<2, false>(lin, inb, ps, nullptr, 0, Hin, sy0, sx0, 0, 0,
                         nullptr, nullptr, 0.f, nullptr);
  } else {
    stage_tile<0, false>(lin, inb, 0, nullptr, 0, Hin, sy0, sx0, 0, 0,
                         nullptr, nullptr, 0.f, nullptr);
  }
  __syncthreads();
  int tx = threadIdx.x & 31, ty = threadIdx.x >> 5;
  int px = px0 + tx, py = py0 + ty;
  int sxl = ((px * hc) >> logr) - sx0;
  int syl = ((py * hc) >> logr) - sy0;
  float a1[3], a2[3];
  #pragma unroll
  for (int c = 0; c < 3; ++c) { a1[c] = b1[c]; a2[c] = b2[c]; }
  #pragma unroll
  for (int ci = 0; ci < 3; ++ci) {
    const float* lrow = lin + ci * IH * IW + syl * IW + sxl;
    const float* wp1 = w1 + ci * 25;
    const float* wp2 = w2 + ci * 25;
    #pragma unroll
    for (int ky = 0; ky < 5; ++ky) {
      float v[5];
      #pragma unroll
      for (int j = 0; j < 5; ++j) v[j] = lrow[ky * IW + j];
      #pragma unroll
      for (int c = 0; c < 3; ++c) {
        #pragma unroll
        for (int kx = 0; kx < 5; ++kx) {
          a1[c] = fmaf(v[kx], wp1[c * 75 + ky * 5 + kx], a1[c]);
          a2[c] = fmaf(v[kx], wp2[c * 75 + ky * 5 + kx], a2[c]);
        }
      }
    }
  }
  float sc[3] = {0.f, 0.f, 0.f}, sq[3] = {0.f, 0.f, 0.f};
  bool valid = (py < S) && (px < S);
  if (valid) {
    #pragma unroll
    for (int c = 0; c < 3; ++c) {
      size_t idx = ((size_t)(n * 3 + c) * S + py) * S + px;
      yu[idx] = make_float2(a1[c], a2[c]);
      sc[c] += a1[c];
      sq[c] += a1[c] * a1[c];
    }
  }
  STATS_REDUCE_ATOMIC(sc, sq, sums, n)
}

// ---- Linear 512->768: one wave per output row, coalesced float4 ----
__global__ __launch_bounds__(256) void linear_wave(
    const float* __restrict__ z, const float* __restrict__ w,
    const float* __restrict__ b, float* __restrict__ out) {
  int row = (blockIdx.x << 2) + (threadIdx.x >> 6);
  int lane = threadIdx.x & 63;
  const float4* wr = reinterpret_cast<const float4*>(w + (size_t)row * 512);
  const float4* zz = reinterpret_cast<const float4*>(z);
  float acc = 0.f;
  #pragma unroll
  for (int i = 0; i < 2; ++i) {
    float4 wv = wr[lane + 64 * i];
    float4 zv = zz[lane + 64 * i];
    acc += wv.x * zv.x + wv.y * zv.y + wv.z * zv.z + wv.w * zv.w;
  }
  #pragma unroll
  for (int off = 32; off; off >>= 1) acc += __shfl_down(acc, off);
  if (lane == 0) out[row] = acc + b[row];
}

// ---- noise conv path (blocks 0,1) in one block, L0 from global ----
__global__ __launch_bounds__(256) void noise_rest(
    const float* __restrict__ L0g,
    const float* __restrict__ cw, const float* __restrict__ cb,
    const float* __restrict__ c2w, const float* __restrict__ c2b,
    const float* __restrict__ inp, const float* __restrict__ lnp,
    const float* __restrict__ bnp, const float* __restrict__ bnw,
    const float* __restrict__ bnb, const float* __restrict__ p1p,
    const float* __restrict__ p2p, float* __restrict__ nb0) {
  __shared__ float L0[768];
  __shared__ float ys0[432], u20[432];
  __shared__ float buf1[3072];
  __shared__ float ys1[2352], u21[2352];
  __shared__ float redS[4][3], redQ[4][3];
  __shared__ float AB[6];
  int tid = threadIdx.x;
  for (int t = tid; t < 768; t += 256) L0[t] = L0g[t];
  __syncthreads();
  // ---- conv0: (3,16,16) -> S=12, r=32 ----
  {
    float sc[3] = {0, 0, 0}, sq[3] = {0, 0, 0};
    for (int p = tid; p < 144; p += 256) {
      int py = p / 12, px = p - py * 12;
      float a1[3], a2[3];
      #pragma unroll
      for (int c = 0; c < 3; ++c) { a1[c] = cb[c]; a2[c] = c2b[c]; }
      for (int ci = 0; ci < 3; ++ci)
        #pragma unroll
        for (int ky = 0; ky < 5; ++ky) {
          const float* row = &L0[ci * 256 + (py + ky) * 16 + px];
          #pragma unroll
          for (int c = 0; c < 3; ++c)
            #pragma unroll
            for (int kx = 0; kx < 5; ++kx) {
              a1[c] = fmaf(row[kx], cw[c * 75 + ci * 25 + ky * 5 + kx], a1[c]);
              a2[c] = fmaf(row[kx], c2w[c * 75 + ci * 25 + ky * 5 + kx], a2[c]);
            }
        }
      int wy = ((py + 1) * 32 + 11) / 12 - (py * 32 + 11) / 12;
      int wx = ((px + 1) * 32 + 11) / 12 - (px * 32 + 11) / 12;
      float wgt = (float)(wy * wx);
      #pragma unroll
      for (int c = 0; c < 3; ++c) {
        ys0[c * 144 + p] = a1[c];
        u20[c * 144 + p] = a2[c];
        sc[c] += a1[c] * wgt;
        sq[c] += a1[c] * a1[c] * wgt;
      }
    }
    #pragma unroll
    for (int off = 32; off; off >>= 1)
      #pragma unroll
      for (int c = 0; c < 3; ++c) {
        sc[c] += __shfl_down(sc[c], off);
        sq[c] += __shfl_down(sq[c], off);
      }
    int wid = tid >> 6, lane = tid & 63;
    if (lane == 0)
      #pragma unroll
      for (int c = 0; c < 3; ++c) { redS[wid][c] = sc[c]; redQ[wid][c] = sq[c]; }
    __syncthreads();
    if (tid < 3) {
      int c = tid;
      float s1 = redS[0][c] + redS[1][c] + redS[2][c] + redS[3][c];
      float s2 = redQ[0][c] + redQ[1][c] + redQ[2][c] + redQ[3][c];
      float si_ = inp[0] + inp[1] + inp[2] + lnp[0] + lnp[1] + lnp[2];
      float sb = bnp[0] + bnp[1] + bnp[2];
      float2 ab = ab_from(s1, s2, s1, s2, 1024.f, 1.f, si_, sb, bnw[c], bnb[c], p1p[0]);
      AB[c] = ab.x; AB[3 + c] = ab.y;
    }
    __syncthreads();
  }
  {
    float P2a = p2p[0];
    for (int t = tid; t < 3072; t += 256) {
      int c = t >> 10, p = t & 1023;
      int oy = p >> 5, ox = p & 31;
      int si = ((oy * 12) >> 5) * 12 + ((ox * 12) >> 5);
      buf1[t] = AB[c] * ys0[c * 144 + si] + AB[3 + c] + P2a * u20[c * 144 + si];
    }
  }
  __syncthreads();
  // ---- conv1: (3,32,32) -> S=28, r=64 ----
  {
    const float* w1 = cw + 225;
    const float* w2 = c2w + 225;
    float sc[3] = {0, 0, 0}, sq[3] = {0, 0, 0};
    for (int p = tid; p < 784; p += 256) {
      int py = p / 28, px = p - py * 28;
      float a1[3], a2[3];
      #pragma unroll
      for (int c = 0; c < 3; ++c) { a1[c] = cb[3 + c]; a2[c] = c2b[3 + c]; }
      for (int ci = 0; ci < 3; ++ci)
        #pragma unroll
        for (int ky = 0; ky < 5; ++ky) {
          const float* row = &buf1[ci * 1024 + (py + ky) * 32 + px];
          #pragma unroll
          for (int c = 0; c < 3; ++c)
            #pragma unroll
            for (int kx = 0; kx < 5; ++kx) {
              a1[c] = fmaf(row[kx], w1[c * 75 + ci * 25 + ky * 5 + kx], a1[c]);
              a2[c] = fmaf(row[kx], w2[c * 75 + ci * 25 + ky * 5 + kx], a2[c]);
            }
        }
      int wy = ((py + 1) * 64 + 27) / 28 - (py * 64 + 27) / 28;
      int wx = ((px + 1) * 64 + 27) / 28 - (px * 64 + 27) / 28;
      float wgt = (float)(wy * wx);
      #pragma unroll
      for (int c = 0; c < 3; ++c) {
        ys1[c * 784 + p] = a1[c];
        u21[c * 784 + p] = a2[c];
        sc[c] += a1[c] * wgt;
        sq[c] += a1[c] * a1[c] * wgt;
      }
    }
    #pragma unroll
    for (int off = 32; off; off >>= 1)
      #pragma unroll
      for (int c = 0; c < 3; ++c) {
        sc[c] += __shfl_down(sc[c], off);
        sq[c] += __shfl_down(sq[c], off);
      }
    int wid = tid >> 6, lane = tid & 63;
    __syncthreads();  // protect redS reuse
    if (lane == 0)
      #pragma unroll
      for (int c = 0; c < 3; ++c) { redS[wid][c] = sc[c]; redQ[wid][c] = sq[c]; }
    __syncthreads();
    if (tid < 3) {
      int c = tid;
      float s1 = redS[0][c] + redS[1][c] + redS[2][c] + redS[3][c];
      float s2 = redQ[0][c] + redQ[1][c] + redQ[2][c] + redQ[3][c];
      float si_ = inp[3] + inp[4] + inp[5] + lnp[3] + lnp[4] + lnp[5];
      float sb = bnp[3] + bnp[4] + bnp[5];
      float2 ab = ab_from(s1, s2, s1, s2, 4096.f, 1.f, si_, sb, bnw[3 + c], bnb[3 + c], p1p[1]);
      AB[c] = ab.x; AB[3 + c] = ab.y;
    }
    __syncthreads();
  }
  {
    float P2b = p2p[1];
    for (int t = tid; t < 12288; t += 256) {
      int c = t >> 12, p = t & 4095;
      int oy = p >> 6, ox = p & 63;
      int si = ((oy * 28) >> 6) * 28 + ((ox * 28) >> 6);
      nb0[t] = AB[c] * ys1[c * 784 + si] + AB[3 + c] + P2b * u21[c * 784 + si];
    }
  }
}

// ---- attention HW=1024, pass 1 (fused y2+QKV recompute) ----
__global__ __launch_bounds__(256) void attn_rows_f(
    const float2* __restrict__ yu, const float* __restrict__ sums,
    const float* __restrict__ inp, const float* __restrict__ lnp,
    const float* __restrict__ bnp, const float* __restrict__ bnw,
    const float* __restrict__ bnb, const float* __restrict__ p1p,
    const float* __restrict__ p2p,
    const float* __restrict__ qw, const float* __restrict__ qb,
    const float* __restrict__ kw, const float* __restrict__ kb,
    float* __restrict__ Mp, float* __restrict__ Lp, int S) {
  __shared__ float pA[3], pB[3], pP2v;
  __shared__ float y2s[768], qs[768];
  int bid = blockIdx.x;
  int np = bid & 3; bid >>= 2;
  int mc = bid & 3;
  int b = bid >> 2;
  compute_AB(sums, b, 32, 1024.f, inp, lnp, bnp, bnw, bnb, p1p, p2p, pA, pB, &pP2v);
  size_t ybase = (size_t)b * 3 * S * S;
  for (int t = threadIdx.x; t < 768; t += 256) {
    int c = t >> 8, j = t & 255;
    int n = (np << 8) + j;
    int oy = n >> 5, ox = n & 31;
    int si = ((oy * S) >> 5) * S + ((ox * S) >> 5);
    float2 v = yu[ybase + c * S * S + si];
    y2s[t] = pA[c] * v.x + pB[c] + pP2v * v.y;
  }
  __syncthreads();
  for (int t = threadIdx.x; t < 768; t += 256) {
    int o = t >> 8, j = t & 255;
    qs[t] = qb[o] + qw[o * 3] * y2s[j] + qw[o * 3 + 1] * y2s[256 + j] +
            qw[o * 3 + 2] * y2s[512 + j];
  }
  __syncthreads();
  int m = (mc << 8) + threadIdx.x;
  int oy = m >> 5, ox = m & 31;
  int si = ((oy * S) >> 5) * S + ((ox * S) >> 5);
  float ym[3];
  #pragma unroll
  for (int c = 0; c < 3; ++c) {
    float2 v = yu[ybase + c * S * S + si];
    ym[c] = pA[c] * v.x + pB[c] + pP2v * v.y;
  }
  float k0 = (kb[0] + kw[0] * ym[0] + kw[1] * ym[1] + kw[2] * ym[2]) * LOG2E;
  float k1 = (kb[1] + kw[3] * ym[0] + kw[4] * ym[1] + kw[5] * ym[2]) * LOG2E;
  float k2 = (kb[2] + kw[6] * ym[0] + kw[7] * ym[1] + kw[8] * ym[2]) * LOG2E;
  float mr = -1e30f;
  for (int j = 0; j < 256; ++j) {
    float s = k0 * qs[j] + k1 * qs[256 + j] + k2 * qs[512 + j];
    mr = fmaxf(mr, s);
  }
  float l = 0.f;
  for (int j = 0; j < 256; ++j) {
    float s = k0 * qs[j] + k1 * qs[256 + j] + k2 * qs[512 + j];
    l += exp2f(s - mr);
  }
  int idx = (b * 4 + np) * 1024 + m;
  Mp[idx] = mr;
  Lp[idx] = l;
}

// ---- attention HW=1024, pass 2: partial buffers, NO atomics ----
__global__ __launch_bounds__(256) void attn_out_f(
    const float2* __restrict__ yu, const float* __restrict__ sums,
    const float* __restrict__ inp, const float* __restrict__ lnp,
    const float* __restrict__ bnp, const float* __restrict__ bnw,
    const float* __restrict__ bnb, const float* __restrict__ p1p,
    const float* __restrict__ p2p,
    const float* __restrict__ qw, const float* __restrict__ qb,
    const float* __restrict__ kw, const float* __restrict__ kb,
    const float* __restrict__ vw, const float* __restrict__ vb,
    const float* __restrict__ Mp, const float* __restrict__ Lp,
    float* __restrict__ aout, int S) {
  __shared__ float pA[3], pB[3], pP2v;
  __shared__ float ym[768], ks[768], vs[768], Ms[256], Ls[256];
  int bid = blockIdx.x;
  int mp = bid & 3; bid >>= 2;
  int nc = bid & 3;
  int b = bid >> 2;
  compute_AB(sums, b, 32, 1024.f, inp, lnp, bnp, bnw, bnb, p1p, p2p, pA, pB, &pP2v);
  size_t ybase = (size_t)b * 3 * S * S;
  for (int t = threadIdx.x; t < 768; t += 256) {
    int c = t >> 8, j = t & 255;
    int m = (mp << 8) + j;
    int oy = m >> 5, ox = m & 31;
    int si = ((oy * S) >> 5) * S + ((ox * S) >> 5);
    float2 v = yu[ybase + c * S * S + si];
    ym[t] = pA[c] * v.x + pB[c] + pP2v * v.y;
  }
  __syncthreads();
  for (int t = threadIdx.x; t < 768; t += 256) {
    int o = t >> 8, j = t & 255;
    float y0 = ym[j], y1 = ym[256 + j], y2v = ym[512 + j];
    ks[t] = (kb[o] + kw[o * 3] * y0 + kw[o * 3 + 1] * y1 + kw[o * 3 + 2] * y2v) * LOG2E;
    vs[t] = vb[o] + vw[o * 3] * y0 + vw[o * 3 + 1] * y1 + vw[o * 3 + 2] * y2v;
  }
  {
    int t = threadIdx.x;
    int m = (mp << 8) + t;
    float M0 = Mp[(b * 4 + 0) * 1024 + m], M1 = Mp[(b * 4 + 1) * 1024 + m];
    float M2 = Mp[(b * 4 + 2) * 1024 + m], M3 = Mp[(b * 4 + 3) * 1024 + m];
    float L0 = Lp[(b * 4 + 0) * 1024 + m], L1 = Lp[(b * 4 + 1) * 1024 + m];
    float L2 = Lp[(b * 4 + 2) * 1024 + m], L3 = Lp[(b * 4 + 3) * 1024 + m];
    float MM = fmaxf(fmaxf(M0, M1), fmaxf(M2, M3));
    float LL = L0 * exp2f(M0 - MM) + L1 * exp2f(M1 - MM) +
               L2 * exp2f(M2 - MM) + L3 * exp2f(M3 - MM);
    Ms[t] = MM;
    Ls[t] = 1.0f / LL;
  }
  __syncthreads();
  int n = (nc << 8) + threadIdx.x;
  int oy = n >> 5, ox = n & 31;
  int si = ((oy * S) >> 5) * S + ((ox * S) >> 5);
  float yn[3];
  #pragma unroll
  for (int c = 0; c < 3; ++c) {
    float2 v = yu[ybase + c * S * S + si];
    yn[c] = pA[c] * v.x + pB[c] + pP2v * v.y;
  }
  float q0 = qb[0] + qw[0] * yn[0] + qw[1] * yn[1] + qw[2] * yn[2];
  float q1 = qb[1] + qw[3] * yn[0] + qw[4] * yn[1] + qw[5] * yn[2];
  float q2 = qb[2] + qw[6] * yn[0] + qw[7] * yn[1] + qw[8] * yn[2];
  float a0 = 0.f, a1 = 0.f, a2 = 0.f;
  for (int j = 0; j < 256; ++j) {
    float s = ks[j] * q0 + ks[256 + j] * q1 + ks[512 + j] * q2;
    float w = exp2f(s - Ms[j]) * Ls[j];
    a0 = fmaf(vs[j], w, a0);
    a1 = fmaf(vs[256 + j], w, a1);
    a2 = fmaf(vs[512 + j], w, a2);
  }
  if (mp == 0) { a0 += yn[0]; a1 += yn[1]; a2 += yn[2]; }
  size_t o0 = (size_t)mp * 98304 + (size_t)b * 3072 + n;
  aout[o0] = a0;
  aout[o0 + 1024] = a1;
  aout[o0 + 2048] = a2;
}

// ---- attention HW=256 + following conv, 1024 threads, 4-way split loops ----
__global__ __launch_bounds__(1024) void attn256_conv(
    const float2* __restrict__ yu, const float* __restrict__ sums,
    const float* __restrict__ inp, const float* __restrict__ lnp,
    const float* __restrict__ bnp, const float* __restrict__ bnw,
    const float* __restrict__ bnb, const float* __restrict__ p1p,
    const float* __restrict__ p2p,
    const float* __restrict__ qw, const float* __restrict__ qb,
    const float* __restrict__ kw, const float* __restrict__ kb,
    const float* __restrict__ vw, const float* __restrict__ vb,
    const float* __restrict__ cw1, const float* __restrict__ cb1,
    const float* __restrict__ cw2, const float* __restrict__ cb2,
    float2* __restrict__ yu_out, float* __restrict__ sums_out, int S, int r) {
  __shared__ float pA[3], pB[3], pP2v;
  __shared__ float y2s[768], qs[768], ks[768], vs[768];
  __shared__ float Ms[256], Ls[256];
  __shared__ float Mq[1024], Lq[1024];
  __shared__ float Oq[3072];
  __shared__ float redS[16][3], redQ[16][3];
  int tid = threadIdx.x;
  int quarter = tid >> 8;
  int lane256 = tid & 255;
  int b = blockIdx.x;
  compute_AB(sums, b, 32, 256.f, inp, lnp, bnp, bnw, bnb, p1p, p2p, pA, pB, &pP2v);
  size_t ybase = (size_t)b * 3 * S * S;
  if (tid < 768) {
    int c = tid >> 8, p = tid & 255;
    int oy = p >> 4, ox = p & 15;
    int si = ((oy * S) >> 4) * S + ((ox * S) >> 4);
    float2 v = yu[ybase + c * S * S + si];
    y2s[tid] = pA[c] * v.x + pB[c] + pP2v * v.y;
  }
  __syncthreads();
  if (tid < 768) {
    int o = tid >> 8, p = tid & 255;
    float y0 = y2s[p], y1 = y2s[256 + p], y2v = y2s[512 + p];
    qs[tid] = qb[o] + qw[o * 3] * y0 + qw[o * 3 + 1] * y1 + qw[o * 3 + 2] * y2v;
    ks[tid] = (kb[o] + kw[o * 3] * y0 + kw[o * 3 + 1] * y1 + kw[o * 3 + 2] * y2v) * LOG2E;
    vs[tid] = vb[o] + vw[o * 3] * y0 + vw[o * 3 + 1] * y1 + vw[o * 3 + 2] * y2v;
  }
  __syncthreads();
  {
    int m = lane256;
    float kx = ks[m], ky = ks[256 + m], kz = ks[512 + m];
    int n0 = quarter << 6;
    float mr = -1e30f;
    #pragma unroll 4
    for (int j = 0; j < 64; ++j) {
      int n = n0 + j;
      float s = kx * qs[n] + ky * qs[256 + n] + kz * qs[512 + n];
      mr = fmaxf(mr, s);
    }
    float l = 0.f;
    #pragma unroll 4
    for (int j = 0; j < 64; ++j) {
      int n = n0 + j;
      float s = kx * qs[n] + ky * qs[256 + n] + kz * qs[512 + n];
      l += exp2f(s - mr);
    }
    Mq[tid] = mr;
    Lq[tid] = l;
  }
  __syncthreads();
  if (tid < 256) {
    float M0 = Mq[tid], M1 = Mq[256 + tid], M2 = Mq[512 + tid], M3 = Mq[768 + tid];
    float L0 = Lq[tid], L1 = Lq[256 + tid], L2 = Lq[512 + tid], L3 = Lq[768 + tid];
    float MM = fmaxf(fmaxf(M0, M1), fmaxf(M2, M3));
    float LL = L0 * exp2f(M0 - MM) + L1 * exp2f(M1 - MM) +
               L2 * exp2f(M2 - MM) + L3 * exp2f(M3 - MM);
    Ms[tid] = MM;
    Ls[tid] = 1.0f / LL;
  }
  __syncthreads();
  {
    int n = lane256;
    float q0 = qs[n], q1 = qs[256 + n], q2 = qs[512 + n];
    int m0 = quarter << 6;
    float a0 = 0.f, a1 = 0.f, a2 = 0.f;
    #pragma unroll 4
    for (int j = 0; j < 64; ++j) {
      int m = m0 + j;
      float s = ks[m] * q0 + ks[256 + m] * q1 + ks[512 + m] * q2;
      float w = exp2f(s - Ms[m]) * Ls[m];
      a0 = fmaf(vs[m], w, a0);
      a1 = fmaf(vs[256 + m], w, a1);
      a2 = fmaf(vs[512 + m], w, a2);
    }
    Oq[tid] = a0;
    Oq[1024 + tid] = a1;
    Oq[2048 + tid] = a2;
  }
  __syncthreads();
  if (tid < 768) {
    int c = tid >> 8, n = tid & 255;
    int cb_ = c << 10;
    y2s[tid] += Oq[cb_ + n] + Oq[cb_ + 256 + n] + Oq[cb_ + 512 + n] + Oq[cb_ + 768 + n];
  }
  __syncthreads();
  float sc[3] = {0.f, 0.f, 0.f}, sq[3] = {0.f, 0.f, 0.f};
  int p = tid;
  if (p < 144) {
    int py = p / 12, px = p - py * 12;
    float a1[3], a2[3];
    #pragma unroll
    for (int c = 0; c < 3; ++c) { a1[c] = cb1[c]; a2[c] = cb2[c]; }
    #pragma unroll
    for (int ci = 0; ci < 3; ++ci) {
      #pragma unroll
      for (int ky = 0; ky < 5; ++ky) {
        const float* row = &y2s[ci * 256 + (py + ky) * 16 + px];
        #pragma unroll
        for (int c = 0; c < 3; ++c) {
          #pragma unroll
          for (int kx = 0; kx < 5; ++kx) {
            a1[c] = fmaf(row[kx], cw1[c * 75 + ci * 25 + ky * 5 + kx], a1[c]);
            a2[c] = fmaf(row[kx], cw2[c * 75 + ci * 25 + ky * 5 + kx], a2[c]);
          }
        }
      }
    }
    float wy = (float)(((py + 1) * r + 11) / 12 - (py * r + 11) / 12);
    float wx = (float)(((px + 1) * r + 11) / 12 - (px * r + 11) / 12);
    float wgt = wy * wx;
    #pragma unroll
    for (int c = 0; c < 3; ++c) {
      yu_out[(size_t)(b * 3 + c) * 144 + p] = make_float2(a1[c], a2[c]);
      sc[c] += a1[c] * wgt;
      sq[c] += a1[c] * a1[c] * wgt;
    }
  }
  #pragma unroll
  for (int off = 32; off; off >>= 1) {
    #pragma unroll
    for (int c = 0; c < 3; ++c) {
      sc[c] += __shfl_down(sc[c], off);
      sq[c] += __shfl_down(sq[c], off);
    }
  }
  int wid = tid >> 6, lane = tid & 63;
  if (lane == 0) {
    #pragma unroll
    for (int c = 0; c < 3; ++c) { redS[wid][c] = sc[c]; redQ[wid][c] = sq[c]; }
  }
  __syncthreads();
  if (tid < 3) {
    int c = tid;
    float s1 = 0.f, s2 = 0.f;
    #pragma unroll
    for (int w = 0; w < 16; ++w) { s1 += redS[w][c]; s2 += redQ[w][c]; }
    atomicAdd(&sums_out[2 * (b * 3 + c)], s1);
    atomicAdd(&sums_out[2 * (b * 3 + c) + 1], s2);
  }
}

// ---- final: affine + p2*u2 + tanh -> out ----
__global__ __launch_bounds__(256) void elem_final(
    const float2* __restrict__ yu, const float* __restrict__ sums,
    const float* __restrict__ inp, const float* __restrict__ lnp,
    const float* __restrict__ bnp, const float* __restrict__ bnw,
    const float* __restrict__ bnb, const float* __restrict__ p1p,
    const float* __restrict__ p2p, float* __restrict__ out, int S) {
  __shared__ float pA[3], pB[3], pP2v;
  int n = blockIdx.x >> 8;
  int p = ((blockIdx.x & 255) << 8) + threadIdx.x;
  compute_AB(sums, n, 32, 65536.f, inp, lnp, bnp, bnw, bnb, p1p, p2p, pA, pB, &pP2v);
  int oy = p >> 8, ox = p & 255;
  int si = ((oy * S) >> 8) * S + ((ox * S) >> 8);
  size_t ybase = (size_t)n * 3 * S * S;
  #pragma unroll
  for (int c = 0; c < 3; ++c) {
    float2 v = yu[ybase + c * S * S + si];
    out[((size_t)(n * 3 + c) << 16) + p] = tanhf(pA[c] * v.x + pB[c] + pP2v * v.y);
  }
}

#define NPX nullptr, nullptr, nullptr, nullptr, nullptr, nullptr, nullptr, \
            nullptr, nullptr, 0, 0, 0

extern "C" void kernel_launch(void* const* d_in, const int* in_sizes, int n_in,
                              void* d_out, int out_size, void* d_ws, size_t ws_size,
                              hipStream_t stream) {
  const float* x       = (const float*)d_in[0];
  const float* noise_z = (const float*)d_in[1];
  const float* lin_w   = (const float*)d_in[2];
  const float* lin_b   = (const float*)d_in[3];
  const float* conv_w  = (const float*)d_in[4];
  const float* conv_b  = (const float*)d_in[5];
  const float* conv2_w = (const float*)d_in[6];
  const float* conv2_b = (const float*)d_in[7];
  const float* q_w     = (const float*)d_in[8];
  const float* q_b     = (const float*)d_in[9];
  const float* k_w     = (const float*)d_in[10];
  const float* k_b     = (const float*)d_in[11];
  const float* v_w     = (const float*)d_in[12];
  const float* v_b     = (const float*)d_in[13];
  const float* in_p    = (const float*)d_in[14];
  const float* ln_p    = (const float*)d_in[15];
  const float* bn_p    = (const float*)d_in[16];
  const float* bn_w    = (const float*)d_in[17];
  const float* bn_b    = (const float*)d_in[18];
  const float* p1      = (const float*)d_in[19];
  const float* p2      = (const float*)d_in[20];
  float* out = (float*)d_out;

  float* ws = (float*)d_ws;
  size_t off = 0;
  auto alloc = [&](size_t nf) { float* p = ws + off; off += nf; return p; };
  float* SUMS = alloc(2304);
  float* P45  = alloc(393216);
  float* P48  = alloc(393216);
  float2* YU2 = (float2*)alloc(12192768);
  float2* PA  = (float2*)alloc(3145728);
  float2* PB  = (float2*)alloc(3145728);
  float* Mp   = alloc(131072);
  float* Lp   = alloc(131072);
  float* NB0  = alloc(12288);
  float* LIN  = alloc(768);

  hipMemsetAsync(SUMS, 0, 2304 * sizeof(float), stream);

  const float* nul = nullptr;
  const float2* nul2 = nullptr;

  linear_wave<<<192, 256, 0, stream>>>(noise_z, lin_w, lin_b, LIN);
  noise_rest<<<1, 256, 0, stream>>>(LIN, conv_w, conv_b, conv2_w, conv2_b,
      in_p, ln_p, bn_p, bn_w, bn_b, p1, p2, NB0);

  // conv2: x -> YU2 (S=252, r=256), async global->LDS staging
  conv_up_t<false, false><<<2048, 256, 0, stream>>>(x, nul2, YU2, conv_w + 450,
      conv_b + 6, conv2_w + 450, conv2_b + 6, SUMS + 384, 256, 252, 256, 4, 16,
      NPX);
  // conv3: fused(b2) YU2 -> PA (S=128); prev Sp=252, logrp=8 (true gather)
  conv_dn_t<true, false, false><<<2048, 256, 0, stream>>>(nul, YU2, PA,
      conv_w + 675, conv_b + 9, conv2_w + 675, conv2_b + 9, SUMS + 576,
      256, 128, 252, 7, 4, 16,
      SUMS + 384, in_p + 6, ln_p + 6, bn_p + 6, bn_w + 6, bn_b + 6, p1 + 2,
      p2 + 2, nul, 32, 252, 8);
  // conv4: fused(b3) PA -> PB (S=64); prev identity
  conv_dn_t<true, true, false><<<512, 256, 0, stream>>>(nul, PA, PB,
      conv_w + 900, conv_b + 12, conv2_w + 900, conv2_b + 12, SUMS + 768,
      128, 64, 124, 6, 2, 8,
      SUMS + 576, in_p + 9, ln_p + 9, bn_p + 9, bn_w + 9, bn_b + 9, p1 + 3,
      p2 + 3, nul, 32, 128, 7);
  // conv5: fused(b4)+noise PB -> PA (S=32); prev identity
  conv_dn_t<true, true, false><<<128, 256, 0, stream>>>(nul, PB, PA,
      conv_w + 1125, conv_b + 15, conv2_w + 1125, conv2_b + 15, SUMS + 960,
      64, 32, 60, 5, 1, 4,
      SUMS + 768, in_p + 12, ln_p + 12, bn_p + 12, bn_w + 12, bn_b + 12, p1 + 4,
      p2 + 4, NB0, 32, 64, 6);
  // attn5 (HW=1024) on PA (S=32) -> partials P45
  attn_rows_f<<<512, 256, 0, stream>>>(PA, SUMS + 960, in_p + 15, ln_p + 15,
      bn_p + 15, bn_w + 15, bn_b + 15, p1 + 5, p2 + 5,
      q_w + 45, q_b + 15, k_w + 45, k_b + 15, Mp, Lp, 32);
  attn_out_f<<<512, 256, 0, stream>>>(PA, SUMS + 960, in_p + 15, ln_p + 15,
      bn_p + 15, bn_w + 15, bn_b + 15, p1 + 5, p2 + 5,
      q_w + 45, q_b + 15, k_w + 45, k_b + 15, v_w + 45, v_b + 15, Mp, Lp, P45, 32);
  // conv6: SUM4 staging from P45 -> PB (S=16)
  conv_dn_t<false, false, true><<<64, 256, 0, stream>>>(P45, nul2, PB,
      conv_w + 1350, conv_b + 18, conv2_w + 1350, conv2_b + 18, SUMS + 1152,
      32, 16, 28, 4, 1, 2, NPX);
  // attn6 (HW=256) on PB (S=16) + conv7 (r=16) -> PA (S=12)
  attn256_conv<<<32, 1024, 0, stream>>>(PB, SUMS + 1152, in_p + 18, ln_p + 18,
      bn_p + 18, bn_w + 18, bn_b + 18, p1 + 6, p2 + 6,
      q_w + 54, q_b + 18, k_w + 54, k_b + 18, v_w + 54, v_b + 18,
      conv_w + 1575, conv_b + 21, conv2_w + 1575, conv2_b + 21,
      PA, SUMS + 1344, 16, 16);
  // attn7 (HW=256) on PA (S=12) + conv8 (r=32) -> PB (S=12)
  attn256_conv<<<32, 1024, 0, stream>>>(PA, SUMS + 1344, in_p + 21, ln_p + 21,
      bn_p + 21, bn_w + 21, bn_b + 21, p1 + 7, p2 + 7,
      q_w + 63, q_b + 21, k_w + 63, k_b + 21, v_w + 63, v_b + 21,
      conv_w + 1800, conv_b + 24, conv2_w + 1800, conv2_b + 24,
      PB, SUMS + 1536, 12, 32);
  // attn8 (HW=1024) on PB (S=12) -> partials P48
  attn_rows_f<<<512, 256, 0, stream>>>(PB, SUMS + 1536, in_p + 24, ln_p + 24,
      bn_p + 24, bn_w + 24, bn_b + 24, p1 + 8, p2 + 8,
      q_w + 72, q_b + 24, k_w + 72, k_b + 24, Mp, Lp, 12);
  attn_out_f<<<512, 256, 0, stream>>>(PB, SUMS + 1536, in_p + 24, ln_p + 24,
      bn_p + 24, bn_w + 24, bn_b + 24, p1 + 8, p2 + 8,
      q_w + 72, q_b + 24, k_w + 72, k_b + 24, v_w + 72, v_b + 24, Mp, Lp, P48, 12);
  // conv9: SUM4 staging from P48 -> PA (S=28, r=64)
  conv_up_t<false, true><<<64, 256, 0, stream>>>(P48, nul2, PA, conv_w + 2025,
      conv_b + 27, conv2_w + 2025, conv2_b + 27, SUMS + 1728, 32, 28, 64, 1, 2,
      NPX);
  // conv10: fused(b9) PA -> PB (S=60); prev Sp=28, logrp=6
  conv_up_t<true, false><<<128, 256, 0, stream>>>(nul, PA, PB, conv_w + 2250,
      conv_b + 30, conv2_w + 2250, conv2_b + 30, SUMS + 1920, 64, 60, 128, 1, 4,
      SUMS + 1728, in_p + 27, ln_p + 27, bn_p + 27, bn_w + 27, bn_b + 27,
      p1 + 9, p2 + 9, nul, 32, 28, 6);
  // conv11: fused(b10) PB -> YU2 (S=124); prev Sp=60, logrp=7
  conv_up_t<true, false><<<512, 256, 0, stream>>>(nul, PB, YU2, conv_w + 2475,
      conv_b + 33, conv2_w + 2475, conv2_b + 33, SUMS + 2112, 128, 124, 256, 2, 8,
      SUMS + 1920, in_p + 30, ln_p + 30, bn_p + 30, bn_w + 30, bn_b + 30,
      p1 + 10, p2 + 10, nul, 32, 60, 7);
  // final: tanh -> out
  elem_final<<<8192, 256, 0, stream>>>(YU2, SUMS + 2112, in_p + 33, ln_p + 33,
      bn_p + 33, bn_w + 33, bn_b + 33, p1 + 11, p2 + 11, out, 124);
}